// Round 1
// baseline (839.337 us; speedup 1.0000x reference)
//
#include <hip/hip_runtime.h>
#include <cstdint>
#include <cstddef>

#define NEG_SLOPE 0.2f
#define F_IN 128
#define C1 256      // HEADS*HID layer-1 width
#define HID 64
#define HEADS 4

__device__ __forceinline__ float wave_reduce_sum(float v) {
#pragma unroll
  for (int off = 32; off > 0; off >>= 1) v += __shfl_down(v, off);
  return v;
}

// ---------------- GEMM fp32: C[M,N] = A[M,K] @ B[K,N] ----------------
// 64x64 tile, BK=16, 256 threads, 4x4 micro-tile. N,K multiples of 16/64.
__global__ __launch_bounds__(256) void gemm_f32(const float* __restrict__ A,
                                                const float* __restrict__ B,
                                                float* __restrict__ C,
                                                int M, int K, int N) {
  __shared__ float As[64][17];
  __shared__ float Bs[16][65];
  const int tid = threadIdx.x;
  const int m0 = blockIdx.y * 64, n0 = blockIdx.x * 64;
  const int tx = tid & 15, ty = tid >> 4;
  float acc[4][4] = {};
  for (int kt = 0; kt < K; kt += 16) {
#pragma unroll
    for (int i = 0; i < 4; i++) {
      int idx = tid + i * 256;
      int r = idx >> 4, c = idx & 15;
      int gr = m0 + r;
      As[r][c] = (gr < M) ? A[(size_t)gr * K + kt + c] : 0.f;
    }
#pragma unroll
    for (int i = 0; i < 4; i++) {
      int idx = tid + i * 256;
      int r = idx >> 6, c = idx & 63;
      Bs[r][c] = B[(size_t)(kt + r) * N + n0 + c];
    }
    __syncthreads();
#pragma unroll
    for (int k = 0; k < 16; k++) {
      float a[4], b[4];
#pragma unroll
      for (int i = 0; i < 4; i++) a[i] = As[ty * 4 + i][k];
#pragma unroll
      for (int j = 0; j < 4; j++) b[j] = Bs[k][tx * 4 + j];
#pragma unroll
      for (int i = 0; i < 4; i++)
#pragma unroll
        for (int j = 0; j < 4; j++) acc[i][j] += a[i] * b[j];
    }
    __syncthreads();
  }
#pragma unroll
  for (int i = 0; i < 4; i++) {
    int gr = m0 + ty * 4 + i;
    if (gr < M) {
#pragma unroll
      for (int j = 0; j < 4; j++) C[(size_t)gr * N + n0 + tx * 4 + j] = acc[i][j];
    }
  }
}

// ---------------- layer-1 alpha dots: one wave per node ----------------
__global__ __launch_bounds__(256) void alphas1_kernel(const float* __restrict__ h,
                                                      const float* __restrict__ att_s,
                                                      const float* __restrict__ att_d,
                                                      float* __restrict__ as_,
                                                      float* __restrict__ ad_, int n) {
  int node = blockIdx.x * 4 + (threadIdx.x >> 6);
  if (node >= n) return;
  int l = threadIdx.x & 63;
  const float* row = h + (size_t)node * C1;
#pragma unroll
  for (int hh = 0; hh < HEADS; hh++) {
    float v = row[hh * HID + l];
    float s = v * att_s[hh * HID + l];
    float d = v * att_d[hh * HID + l];
    s = wave_reduce_sum(s);
    d = wave_reduce_sum(d);
    if (l == 0) { as_[node * HEADS + hh] = s; ad_[node * HEADS + hh] = d; }
  }
}

// ---------------- layer-2 alpha dots (1 head) ----------------
__global__ __launch_bounds__(256) void alphas2_kernel(const float* __restrict__ h,
                                                      const float* __restrict__ att_s,
                                                      const float* __restrict__ att_d,
                                                      float* __restrict__ as_,
                                                      float* __restrict__ ad_, int n) {
  int node = blockIdx.x * 4 + (threadIdx.x >> 6);
  if (node >= n) return;
  int l = threadIdx.x & 63;
  float v = h[(size_t)node * HID + l];
  float s = wave_reduce_sum(v * att_s[l]);
  float d = wave_reduce_sum(v * att_d[l]);
  if (l == 0) { as_[node] = s; ad_[node] = d; }
}

// ---------------- CSR build ----------------
__global__ __launch_bounds__(256) void hist_kernel(const int* __restrict__ edge_dst,
                                                   int* __restrict__ deg, int E, int Etot) {
  int e = blockIdx.x * blockDim.x + threadIdx.x;
  if (e >= Etot) return;
  int d = (e < E) ? edge_dst[e] : (e - E);
  atomicAdd(&deg[d], 1);
}

__global__ __launch_bounds__(1024) void scan_kernel(const int* __restrict__ deg,
                                                    int* __restrict__ row_ptr, int n) {
  __shared__ int part[1024];
  const int tid = threadIdx.x;
  const int chunk = (n + 1023) / 1024;
  int start = tid * chunk, end = min(start + chunk, n);
  int s = 0;
  for (int i = start; i < end; i++) s += deg[i];
  part[tid] = s;
  __syncthreads();
  for (int off = 1; off < 1024; off <<= 1) {
    int v = (tid >= off) ? part[tid - off] : 0;
    __syncthreads();
    part[tid] += v;
    __syncthreads();
  }
  int run = (tid == 0) ? 0 : part[tid - 1];
  for (int i = start; i < end; i++) { row_ptr[i] = run; run += deg[i]; }
  if (tid == 0) row_ptr[n] = part[1023];
}

__global__ __launch_bounds__(256) void scatter_kernel(const int* __restrict__ edge_src,
                                                      const int* __restrict__ edge_dst,
                                                      const int* __restrict__ row_ptr,
                                                      int* __restrict__ cursor,
                                                      int* __restrict__ csr_src,
                                                      int E, int Etot) {
  int e = blockIdx.x * blockDim.x + threadIdx.x;
  if (e >= Etot) return;
  int s = (e < E) ? edge_src[e] : (e - E);
  int d = (e < E) ? edge_dst[e] : (e - E);
  int pos = atomicAdd(&cursor[d], 1);
  csr_src[row_ptr[d] + pos] = s;
}

// ---------------- layer-1 aggregate: one wave per dst node ----------------
// lane l covers channels 4l..4l+3 (head = l>>4); softmax denom tracked per head.
__global__ __launch_bounds__(256) void agg1_kernel(const float* __restrict__ h,
                                                   const float* __restrict__ as_,
                                                   const float* __restrict__ ad_,
                                                   const int* __restrict__ row_ptr,
                                                   const int* __restrict__ csr_src,
                                                   const float* __restrict__ b1,
                                                   float* __restrict__ out, int n) {
  int d = blockIdx.x * 4 + (threadIdx.x >> 6);
  if (d >= n) return;
  int l = threadIdx.x & 63;
  int hh = l >> 4;
  float ad = ad_[d * HEADS + hh];
  int e0 = row_ptr[d], e1 = row_ptr[d + 1];
  float4 acc = {0.f, 0.f, 0.f, 0.f};
  float denom = 0.f;
  for (int e = e0; e < e1; e++) {
    int s = csr_src[e];
    float sc = as_[s * HEADS + hh] + ad;
    sc = sc > 0.f ? sc : NEG_SLOPE * sc;
    float w = __expf(sc);
    denom += w;
    const float4 hv = *(const float4*)(h + (size_t)s * C1 + l * 4);
    acc.x += w * hv.x; acc.y += w * hv.y; acc.z += w * hv.z; acc.w += w * hv.w;
  }
  float inv = 1.f / (denom + 1e-16f);
  float4 bb = *(const float4*)(b1 + l * 4);
  float4 o;
  o.x = acc.x * inv + bb.x;
  o.y = acc.y * inv + bb.y;
  o.z = acc.z * inv + bb.z;
  o.w = acc.w * inv + bb.w;
  o.x = o.x > 0.f ? o.x : (__expf(o.x) - 1.f);
  o.y = o.y > 0.f ? o.y : (__expf(o.y) - 1.f);
  o.z = o.z > 0.f ? o.z : (__expf(o.z) - 1.f);
  o.w = o.w > 0.f ? o.w : (__expf(o.w) - 1.f);
  *(float4*)(out + (size_t)d * C1 + l * 4) = o;
}

// ---------------- layer-2 aggregate: one wave per dst node, 64 ch, 1 head ----
__global__ __launch_bounds__(256) void agg2_kernel(const float* __restrict__ h,
                                                   const float* __restrict__ as_,
                                                   const float* __restrict__ ad_,
                                                   const int* __restrict__ row_ptr,
                                                   const int* __restrict__ csr_src,
                                                   const float* __restrict__ b2,
                                                   float* __restrict__ out, int n) {
  int d = blockIdx.x * 4 + (threadIdx.x >> 6);
  if (d >= n) return;
  int l = threadIdx.x & 63;
  float ad = ad_[d];
  int e0 = row_ptr[d], e1 = row_ptr[d + 1];
  float acc = 0.f, denom = 0.f;
  for (int e = e0; e < e1; e++) {
    int s = csr_src[e];
    float sc = as_[s] + ad;
    sc = sc > 0.f ? sc : NEG_SLOPE * sc;
    float w = __expf(sc);
    denom += w;
    acc += w * h[(size_t)s * HID + l];
  }
  float o = acc / (denom + 1e-16f) + b2[l];
  o = o > 0.f ? o : (__expf(o) - 1.f);
  out[(size_t)d * HID + l] = o;
}

// ---------------- mean pool ----------------
__global__ __launch_bounds__(256) void pool_partial(const float* __restrict__ h,
                                                    float* __restrict__ pooled, int n) {
  int c = threadIdx.x & 63, rg = threadIdx.x >> 6;
  float acc = 0.f;
  for (int r = blockIdx.x * 4 + rg; r < n; r += gridDim.x * 4)
    acc += h[(size_t)r * HID + c];
  __shared__ float lds[256];
  lds[threadIdx.x] = acc;
  __syncthreads();
  if (rg == 0) {
    float v = lds[c] + lds[64 + c] + lds[128 + c] + lds[192 + c];
    atomicAdd(&pooled[c], v);
  }
}

__global__ __launch_bounds__(64) void head_kernel(const float* __restrict__ pooled,
                                                  const float* __restrict__ Wc,
                                                  const float* __restrict__ bc,
                                                  float* __restrict__ out, float inv_n) {
  int l = threadIdx.x;
  float p = pooled[l] * inv_n;
  float o0 = wave_reduce_sum(p * Wc[l * 2 + 0]);
  float o1 = wave_reduce_sum(p * Wc[l * 2 + 1]);
  if (l == 0) { out[0] = o0 + bc[0]; out[1] = o1 + bc[1]; }
}

// ---------------- host ----------------
static inline size_t align256(size_t x) { return (x + 255) & ~(size_t)255; }

extern "C" void kernel_launch(void* const* d_in, const int* in_sizes, int n_in,
                              void* d_out, int out_size, void* d_ws, size_t ws_size,
                              hipStream_t stream) {
  const float* x        = (const float*)d_in[0];
  const int*   ei       = (const int*)d_in[1];
  const float* W1       = (const float*)d_in[2];
  const float* att_src1 = (const float*)d_in[3];
  const float* att_dst1 = (const float*)d_in[4];
  const float* b1       = (const float*)d_in[5];
  const float* W2       = (const float*)d_in[6];
  const float* att_src2 = (const float*)d_in[7];
  const float* att_dst2 = (const float*)d_in[8];
  const float* b2       = (const float*)d_in[9];
  const float* Wc       = (const float*)d_in[10];
  const float* bc       = (const float*)d_in[11];
  float* out = (float*)d_out;

  const int N = in_sizes[0] / F_IN;          // 50000
  const int E = in_sizes[1] / 2;             // 1,600,000
  const int Etot = E + N;                    // + self loops
  const int* ei_src = ei;
  const int* ei_dst = ei + E;

  // workspace layout
  char* w = (char*)d_ws;
  size_t off = 0;
  float* h1pre = (float*)(w + off); off += align256((size_t)N * C1 * 4);   // 51.2MB
  float* h1act = (float*)(w + off); off += align256((size_t)N * C1 * 4);   // 51.2MB
  float* as1   = (float*)(w + off); off += align256((size_t)N * HEADS * 4);
  float* ad1   = (float*)(w + off); off += align256((size_t)N * HEADS * 4);
  int* deg     = (int*)(w + off);   off += align256((size_t)N * 4);
  int* cursor  = (int*)(w + off);   off += align256((size_t)N * 4);
  int* row_ptr = (int*)(w + off);   off += align256((size_t)(N + 1) * 4);
  int* csr_src = (int*)(w + off);   off += align256((size_t)Etot * 4);
  // phase-2 buffers alias the (dead after agg1) h1pre region
  char* w2 = (char*)h1pre;
  size_t off2 = 0;
  float* h2pre = (float*)(w2 + off2); off2 += align256((size_t)N * HID * 4);
  float* h2act = (float*)(w2 + off2); off2 += align256((size_t)N * HID * 4);
  float* as2   = (float*)(w2 + off2); off2 += align256((size_t)N * 4);
  float* ad2   = (float*)(w2 + off2); off2 += align256((size_t)N * 4);
  float* pooled= (float*)(w2 + off2); off2 += align256(64 * 4);

  // CSR build (independent of GEMM1)
  hipMemsetAsync(deg, 0, (size_t)N * 4, stream);
  hipMemsetAsync(cursor, 0, (size_t)N * 4, stream);
  int eb = (Etot + 255) / 256;
  hist_kernel<<<eb, 256, 0, stream>>>(ei_dst, deg, E, Etot);
  scan_kernel<<<1, 1024, 0, stream>>>(deg, row_ptr, N);
  scatter_kernel<<<eb, 256, 0, stream>>>(ei_src, ei_dst, row_ptr, cursor, csr_src, E, Etot);

  // layer 1
  dim3 g1(C1 / 64, (N + 63) / 64);
  gemm_f32<<<g1, 256, 0, stream>>>(x, W1, h1pre, N, F_IN, C1);
  int nb4 = (N + 3) / 4;
  alphas1_kernel<<<nb4, 256, 0, stream>>>(h1pre, att_src1, att_dst1, as1, ad1, N);
  agg1_kernel<<<nb4, 256, 0, stream>>>(h1pre, as1, ad1, row_ptr, csr_src, b1, h1act, N);

  // layer 2
  dim3 g2(HID / 64 > 0 ? HID / 64 : 1, (N + 63) / 64);
  gemm_f32<<<g2, 256, 0, stream>>>(h1act, W2, h2pre, N, C1, HID);
  alphas2_kernel<<<nb4, 256, 0, stream>>>(h2pre, att_src2, att_dst2, as2, ad2, N);
  agg2_kernel<<<nb4, 256, 0, stream>>>(h2pre, as2, ad2, row_ptr, csr_src, b2, h2act, N);

  // pool + head
  hipMemsetAsync(pooled, 0, 64 * 4, stream);
  pool_partial<<<256, 256, 0, stream>>>(h2act, pooled, N);
  head_kernel<<<1, 64, 0, stream>>>(pooled, Wc, bc, out, 1.0f / (float)N);
}

// Round 2
// 561.614 us; speedup vs baseline: 1.4945x; 1.4945x over previous
//
#include <hip/hip_runtime.h>
#include <cstdint>
#include <cstddef>

#define NEG_SLOPE 0.2f
#define F_IN 128
#define C1 256      // HEADS*HID layer-1 width
#define HID 64
#define HEADS 4

__device__ __forceinline__ float wave_reduce_sum(float v) {
#pragma unroll
  for (int off = 32; off > 0; off >>= 1) v += __shfl_down(v, off);
  return v;
}

__device__ __forceinline__ unsigned short f2bf(float f) {
  union { float f; unsigned int u; } v; v.f = f;
  unsigned int u = v.u;
  unsigned int r = (u + 0x7fffu + ((u >> 16) & 1u)) >> 16;  // round-nearest-even
  return (unsigned short)r;
}
__device__ __forceinline__ float bf_lo(unsigned int u) { return __uint_as_float(u << 16); }
__device__ __forceinline__ float bf_hi(unsigned int u) { return __uint_as_float(u & 0xffff0000u); }

// ---------------- fused GEMM + alpha-dot epilogue + bf16 store ----------------
// C[M,N] = A[M,K] @ B[K,N], 64x64 tile, BK=16, 256 thr, 4x4 micro-tile.
// Each 64-col block tile == one attention head (N = 64*gridDim.x).
// Epilogue: Hb (bf16) = C; as_out/ad_out[node*nheads+head] = C_row . att.
__global__ __launch_bounds__(256) void gemm_fused(const float* __restrict__ A,
                                                  const float* __restrict__ B,
                                                  unsigned short* __restrict__ Hb,
                                                  float* __restrict__ as_out,
                                                  float* __restrict__ ad_out,
                                                  const float* __restrict__ att_s,
                                                  const float* __restrict__ att_d,
                                                  int M, int K, int N) {
  __shared__ float As[16][68];   // k-major so fragment reads are contiguous
  __shared__ float Bs[16][68];
  const int tid = threadIdx.x;
  const int m0 = blockIdx.y * 64, n0 = blockIdx.x * 64;
  const int head = blockIdx.x, nheads = gridDim.x;
  const int tx = tid & 15, ty = tid >> 4;
  float acc[4][4] = {};
  for (int kt = 0; kt < K; kt += 16) {
    {  // A tile: 64 rows x 16 k, one float4 per thread
      int r = tid >> 2, c4 = (tid & 3) * 4;
      int gr = m0 + r;
      float4 av = make_float4(0.f, 0.f, 0.f, 0.f);
      if (gr < M) av = *(const float4*)(A + (size_t)gr * K + kt + c4);
      As[c4 + 0][r] = av.x; As[c4 + 1][r] = av.y;
      As[c4 + 2][r] = av.z; As[c4 + 3][r] = av.w;
    }
    {  // B tile: 16 k x 64 cols, one float4 per thread
      int r = tid >> 4, c4 = (tid & 15) * 4;
      float4 bv = *(const float4*)(B + (size_t)(kt + r) * N + n0 + c4);
      *(float4*)&Bs[r][c4] = bv;
    }
    __syncthreads();
#pragma unroll
    for (int k = 0; k < 16; k++) {
      float a[4], b[4];
#pragma unroll
      for (int i = 0; i < 4; i++) a[i] = As[k][ty * 4 + i];
#pragma unroll
      for (int j = 0; j < 4; j++) b[j] = Bs[k][tx * 4 + j];
#pragma unroll
      for (int i = 0; i < 4; i++)
#pragma unroll
        for (int j = 0; j < 4; j++) acc[i][j] += a[i] * b[j];
    }
    __syncthreads();
  }
  // epilogue: bf16 store + per-head alpha dots
  float a_s[4], a_d[4];
#pragma unroll
  for (int j = 0; j < 4; j++) {
    a_s[j] = att_s[head * 64 + tx * 4 + j];
    a_d[j] = att_d[head * 64 + tx * 4 + j];
  }
#pragma unroll
  for (int i = 0; i < 4; i++) {
    int gr = m0 + ty * 4 + i;
    float ps = 0.f, pd = 0.f;
#pragma unroll
    for (int j = 0; j < 4; j++) { ps += acc[i][j] * a_s[j]; pd += acc[i][j] * a_d[j]; }
#pragma unroll
    for (int m = 1; m < 16; m <<= 1) { ps += __shfl_xor(ps, m); pd += __shfl_xor(pd, m); }
    if (gr < M) {
      unsigned int lo = (unsigned int)f2bf(acc[i][0]) | ((unsigned int)f2bf(acc[i][1]) << 16);
      unsigned int hi = (unsigned int)f2bf(acc[i][2]) | ((unsigned int)f2bf(acc[i][3]) << 16);
      uint2 pk; pk.x = lo; pk.y = hi;
      *(uint2*)(Hb + (size_t)gr * N + n0 + tx * 4) = pk;
      if (tx == 0) {
        as_out[(size_t)gr * nheads + head] = ps;
        ad_out[(size_t)gr * nheads + head] = pd;
      }
    }
  }
}

// ---------------- CSR build ----------------
__global__ __launch_bounds__(256) void init_kernel(int* __restrict__ deg,
                                                   int* __restrict__ cursor,
                                                   float* __restrict__ pooled, int n) {
  int i = blockIdx.x * blockDim.x + threadIdx.x;
  if (i < n) { deg[i] = 0; cursor[i] = 0; }
  if (i < 64) pooled[i] = 0.f;
}

__global__ __launch_bounds__(256) void hist_kernel(const int* __restrict__ edge_dst,
                                                   int* __restrict__ deg, int E, int Etot) {
  int e = blockIdx.x * blockDim.x + threadIdx.x;
  if (e >= Etot) return;
  int d = (e < E) ? edge_dst[e] : (e - E);
  atomicAdd(&deg[d], 1);
}

__global__ __launch_bounds__(1024) void scan_kernel(const int* __restrict__ deg,
                                                    int* __restrict__ row_ptr, int n) {
  __shared__ int part[1024];
  const int tid = threadIdx.x;
  const int chunk = (n + 1023) / 1024;
  int start = tid * chunk, end = min(start + chunk, n);
  int s = 0;
  for (int i = start; i < end; i++) s += deg[i];
  part[tid] = s;
  __syncthreads();
  for (int off = 1; off < 1024; off <<= 1) {
    int v = (tid >= off) ? part[tid - off] : 0;
    __syncthreads();
    part[tid] += v;
    __syncthreads();
  }
  int run = (tid == 0) ? 0 : part[tid - 1];
  for (int i = start; i < end; i++) { row_ptr[i] = run; run += deg[i]; }
  if (tid == 0) row_ptr[n] = part[1023];
}

__global__ __launch_bounds__(256) void scatter_kernel(const int* __restrict__ edge_src,
                                                      const int* __restrict__ edge_dst,
                                                      const int* __restrict__ row_ptr,
                                                      int* __restrict__ cursor,
                                                      int* __restrict__ csr_src,
                                                      int E, int Etot) {
  int e = blockIdx.x * blockDim.x + threadIdx.x;
  if (e >= Etot) return;
  int s = (e < E) ? edge_src[e] : (e - E);
  int d = (e < E) ? edge_dst[e] : (e - E);
  int pos = atomicAdd(&cursor[d], 1);
  csr_src[row_ptr[d] + pos] = s;
}

// ---------------- layer-1 aggregate: one wave per dst, bf16 gather ----------------
// lane l covers channels 4l..4l+3 (head = l>>4); 8B gather per lane per edge.
__global__ __launch_bounds__(256) void agg1_kernel(const unsigned short* __restrict__ Hb,
                                                   const float* __restrict__ as_,
                                                   const float* __restrict__ ad_,
                                                   const int* __restrict__ row_ptr,
                                                   const int* __restrict__ csr_src,
                                                   const float* __restrict__ b1,
                                                   float* __restrict__ out, int n) {
  int d = blockIdx.x * 4 + (threadIdx.x >> 6);
  if (d >= n) return;
  int l = threadIdx.x & 63;
  int hh = l >> 4;
  float ad = ad_[d * HEADS + hh];
  int e0 = row_ptr[d], e1 = row_ptr[d + 1];
  float4 acc = {0.f, 0.f, 0.f, 0.f};
  float denom = 0.f;
  int e = e0;
  for (; e + 3 < e1; e += 4) {
    int s0 = csr_src[e], s1 = csr_src[e + 1], s2 = csr_src[e + 2], s3 = csr_src[e + 3];
    float sc0 = as_[s0 * HEADS + hh] + ad;
    float sc1 = as_[s1 * HEADS + hh] + ad;
    float sc2 = as_[s2 * HEADS + hh] + ad;
    float sc3 = as_[s3 * HEADS + hh] + ad;
    uint2 p0 = *(const uint2*)(Hb + (size_t)s0 * C1 + l * 4);
    uint2 p1 = *(const uint2*)(Hb + (size_t)s1 * C1 + l * 4);
    uint2 p2 = *(const uint2*)(Hb + (size_t)s2 * C1 + l * 4);
    uint2 p3 = *(const uint2*)(Hb + (size_t)s3 * C1 + l * 4);
    float w0 = __expf(sc0 > 0.f ? sc0 : NEG_SLOPE * sc0);
    float w1 = __expf(sc1 > 0.f ? sc1 : NEG_SLOPE * sc1);
    float w2 = __expf(sc2 > 0.f ? sc2 : NEG_SLOPE * sc2);
    float w3 = __expf(sc3 > 0.f ? sc3 : NEG_SLOPE * sc3);
    denom += (w0 + w1) + (w2 + w3);
    acc.x += w0 * bf_lo(p0.x); acc.y += w0 * bf_hi(p0.x); acc.z += w0 * bf_lo(p0.y); acc.w += w0 * bf_hi(p0.y);
    acc.x += w1 * bf_lo(p1.x); acc.y += w1 * bf_hi(p1.x); acc.z += w1 * bf_lo(p1.y); acc.w += w1 * bf_hi(p1.y);
    acc.x += w2 * bf_lo(p2.x); acc.y += w2 * bf_hi(p2.x); acc.z += w2 * bf_lo(p2.y); acc.w += w2 * bf_hi(p2.y);
    acc.x += w3 * bf_lo(p3.x); acc.y += w3 * bf_hi(p3.x); acc.z += w3 * bf_lo(p3.y); acc.w += w3 * bf_hi(p3.y);
  }
  for (; e < e1; e++) {
    int s = csr_src[e];
    float sc = as_[s * HEADS + hh] + ad;
    float w = __expf(sc > 0.f ? sc : NEG_SLOPE * sc);
    denom += w;
    uint2 p = *(const uint2*)(Hb + (size_t)s * C1 + l * 4);
    acc.x += w * bf_lo(p.x); acc.y += w * bf_hi(p.x); acc.z += w * bf_lo(p.y); acc.w += w * bf_hi(p.y);
  }
  float inv = 1.f / (denom + 1e-16f);
  float4 bb = *(const float4*)(b1 + l * 4);
  float4 o;
  o.x = acc.x * inv + bb.x; o.y = acc.y * inv + bb.y;
  o.z = acc.z * inv + bb.z; o.w = acc.w * inv + bb.w;
  o.x = o.x > 0.f ? o.x : (__expf(o.x) - 1.f);
  o.y = o.y > 0.f ? o.y : (__expf(o.y) - 1.f);
  o.z = o.z > 0.f ? o.z : (__expf(o.z) - 1.f);
  o.w = o.w > 0.f ? o.w : (__expf(o.w) - 1.f);
  *(float4*)(out + (size_t)d * C1 + l * 4) = o;
}

// ---------------- layer-2 aggregate: one wave per dst, 2 edges/iter ----------------
// half-wave h handles edge e0+half, e0+half+2, ...; lane li covers ch {2li, 2li+1}.
__global__ __launch_bounds__(256) void agg2_kernel(const unsigned short* __restrict__ Hb,
                                                   const float* __restrict__ as_,
                                                   const float* __restrict__ ad_,
                                                   const int* __restrict__ row_ptr,
                                                   const int* __restrict__ csr_src,
                                                   const float* __restrict__ b2,
                                                   float* __restrict__ out, int n) {
  int d = blockIdx.x * 4 + (threadIdx.x >> 6);
  if (d >= n) return;
  int l = threadIdx.x & 63;
  int half = l >> 5, li = l & 31;
  float ad = ad_[d];
  int e0 = row_ptr[d], e1 = row_ptr[d + 1];
  float acc0 = 0.f, acc1 = 0.f, denom = 0.f;
  for (int e = e0 + half; e < e1; e += 2) {
    int s = csr_src[e];
    float sc = as_[s] + ad;
    sc = sc > 0.f ? sc : NEG_SLOPE * sc;
    float w = __expf(sc);
    denom += w;
    unsigned int p = *(const unsigned int*)(Hb + (size_t)s * HID + li * 2);
    acc0 += w * bf_lo(p);
    acc1 += w * bf_hi(p);
  }
  acc0 += __shfl_xor(acc0, 32);
  acc1 += __shfl_xor(acc1, 32);
  denom += __shfl_xor(denom, 32);
  if (half == 0) {
    float inv = 1.f / (denom + 1e-16f);
    float o0 = acc0 * inv + b2[li * 2];
    float o1 = acc1 * inv + b2[li * 2 + 1];
    o0 = o0 > 0.f ? o0 : (__expf(o0) - 1.f);
    o1 = o1 > 0.f ? o1 : (__expf(o1) - 1.f);
    float2 ov; ov.x = o0; ov.y = o1;
    *(float2*)(out + (size_t)d * HID + li * 2) = ov;
  }
}

// ---------------- mean pool + head ----------------
__global__ __launch_bounds__(256) void pool_partial(const float* __restrict__ h,
                                                    float* __restrict__ pooled, int n) {
  int c = threadIdx.x & 63, rg = threadIdx.x >> 6;
  float acc = 0.f;
  for (int r = blockIdx.x * 4 + rg; r < n; r += gridDim.x * 4)
    acc += h[(size_t)r * HID + c];
  __shared__ float lds[256];
  lds[threadIdx.x] = acc;
  __syncthreads();
  if (rg == 0) {
    float v = lds[c] + lds[64 + c] + lds[128 + c] + lds[192 + c];
    atomicAdd(&pooled[c], v);
  }
}

__global__ __launch_bounds__(64) void head_kernel(const float* __restrict__ pooled,
                                                  const float* __restrict__ Wc,
                                                  const float* __restrict__ bc,
                                                  float* __restrict__ out, float inv_n) {
  int l = threadIdx.x;
  float p = pooled[l] * inv_n;
  float o0 = wave_reduce_sum(p * Wc[l * 2 + 0]);
  float o1 = wave_reduce_sum(p * Wc[l * 2 + 1]);
  if (l == 0) { out[0] = o0 + bc[0]; out[1] = o1 + bc[1]; }
}

// ---------------- host ----------------
static inline size_t align256(size_t x) { return (x + 255) & ~(size_t)255; }

extern "C" void kernel_launch(void* const* d_in, const int* in_sizes, int n_in,
                              void* d_out, int out_size, void* d_ws, size_t ws_size,
                              hipStream_t stream) {
  const float* x        = (const float*)d_in[0];
  const int*   ei       = (const int*)d_in[1];
  const float* W1       = (const float*)d_in[2];
  const float* att_src1 = (const float*)d_in[3];
  const float* att_dst1 = (const float*)d_in[4];
  const float* b1       = (const float*)d_in[5];
  const float* W2       = (const float*)d_in[6];
  const float* att_src2 = (const float*)d_in[7];
  const float* att_dst2 = (const float*)d_in[8];
  const float* b2       = (const float*)d_in[9];
  const float* Wc       = (const float*)d_in[10];
  const float* bc       = (const float*)d_in[11];
  float* out = (float*)d_out;

  const int N = in_sizes[0] / F_IN;          // 50000
  const int E = in_sizes[1] / 2;             // 1,600,000
  const int Etot = E + N;                    // + self loops
  const int* ei_src = ei;
  const int* ei_dst = ei + E;

  // workspace layout (~105 MB)
  char* w = (char*)d_ws;
  size_t off = 0;
  unsigned short* h1b  = (unsigned short*)(w + off); off += align256((size_t)N * C1 * 2);  // 25.6MB
  float* h1act = (float*)(w + off); off += align256((size_t)N * C1 * 4);                   // 51.2MB
  unsigned short* h2b  = (unsigned short*)(w + off); off += align256((size_t)N * HID * 2); // 6.4MB
  float* h2act = (float*)(w + off); off += align256((size_t)N * HID * 4);                  // 12.8MB
  float* as1   = (float*)(w + off); off += align256((size_t)N * HEADS * 4);
  float* ad1   = (float*)(w + off); off += align256((size_t)N * HEADS * 4);
  float* as2   = (float*)(w + off); off += align256((size_t)N * 4);
  float* ad2   = (float*)(w + off); off += align256((size_t)N * 4);
  int* deg     = (int*)(w + off);   off += align256((size_t)N * 4);
  int* cursor  = (int*)(w + off);   off += align256((size_t)N * 4);
  int* row_ptr = (int*)(w + off);   off += align256((size_t)(N + 1) * 4);
  float* pooled= (float*)(w + off); off += align256(64 * 4);
  int* csr_src = (int*)(w + off);   off += align256((size_t)Etot * 4);

  // CSR build
  init_kernel<<<(N + 255) / 256, 256, 0, stream>>>(deg, cursor, pooled, N);
  int eb = (Etot + 255) / 256;
  hist_kernel<<<eb, 256, 0, stream>>>(ei_dst, deg, E, Etot);
  scan_kernel<<<1, 1024, 0, stream>>>(deg, row_ptr, N);
  scatter_kernel<<<eb, 256, 0, stream>>>(ei_src, ei_dst, row_ptr, cursor, csr_src, E, Etot);

  int nb4 = (N + 3) / 4;

  // layer 1: GEMM (+bf16 store, +alpha dots) then gather/softmax/aggregate
  dim3 g1(C1 / 64, (N + 63) / 64);
  gemm_fused<<<g1, 256, 0, stream>>>(x, W1, h1b, as1, ad1, att_src1, att_dst1, N, F_IN, C1);
  agg1_kernel<<<nb4, 256, 0, stream>>>(h1b, as1, ad1, row_ptr, csr_src, b1, h1act, N);

  // layer 2
  dim3 g2(HID / 64, (N + 63) / 64);
  gemm_fused<<<g2, 256, 0, stream>>>(h1act, W2, h2b, as2, ad2, att_src2, att_dst2, N, C1, HID);
  agg2_kernel<<<nb4, 256, 0, stream>>>(h2b, as2, ad2, row_ptr, csr_src, b2, h2act, N);

  // pool + head
  pool_partial<<<256, 256, 0, stream>>>(h2act, pooled, N);
  head_kernel<<<1, 64, 0, stream>>>(pooled, Wc, bc, out, 1.0f / (float)N);
}

// Round 3
// 524.028 us; speedup vs baseline: 1.6017x; 1.0717x over previous
//
#include <hip/hip_runtime.h>
#include <cstdint>
#include <cstddef>

#define NEG_SLOPE 0.2f
#define F_IN 128
#define C1 256      // HEADS*HID layer-1 width
#define HID 64
#define HEADS 4

typedef __attribute__((ext_vector_type(8))) short bf16x8;
typedef __attribute__((ext_vector_type(4))) float f32x4;

__device__ __forceinline__ float wave_reduce_sum(float v) {
#pragma unroll
  for (int off = 32; off > 0; off >>= 1) v += __shfl_down(v, off);
  return v;
}

__device__ __forceinline__ unsigned short f2bf(float f) {
  union { float f; unsigned int u; } v; v.f = f;
  unsigned int u = v.u;
  unsigned int r = (u + 0x7fffu + ((u >> 16) & 1u)) >> 16;  // round-nearest-even
  return (unsigned short)r;
}
__device__ __forceinline__ float bf_lo(unsigned int u) { return __uint_as_float(u << 16); }
__device__ __forceinline__ float bf_hi(unsigned int u) { return __uint_as_float(u & 0xffff0000u); }

// ---------------- weight pre-pack into MFMA fragment order ----------------
// W1b[head][ks][nt][lane][8]; W2b[ks][nt][lane][8]
__global__ __launch_bounds__(256) void pack_w(const float* __restrict__ W1,
                                              const float* __restrict__ W2,
                                              unsigned short* __restrict__ W1b,
                                              unsigned short* __restrict__ W2b) {
  for (int idx = threadIdx.x + blockIdx.x * 256; idx < 32768 + 16384;
       idx += 256 * gridDim.x) {
    if (idx < 32768) {
      int head = idx >> 13, ks = (idx >> 11) & 3, nt = (idx >> 9) & 3;
      int lane = (idx >> 3) & 63, j = idx & 7;
      int k = ks * 32 + (lane >> 4) * 8 + j;
      int c = head * 64 + nt * 16 + (lane & 15);
      W1b[idx] = f2bf(W1[k * 256 + c]);
    } else {
      int o = idx - 32768;
      int ks = o >> 11, nt = (o >> 9) & 3, lane = (o >> 3) & 63, j = o & 7;
      int k = ks * 32 + (lane >> 4) * 8 + j;
      int c = nt * 16 + (lane & 15);
      W2b[o] = f2bf(W2[k * 64 + c]);
    }
  }
}

// ---------------- MFMA GEMM + alpha-dot epilogue + bf16 store ----------------
// block = 256 thr (4 waves), each wave = 16 rows; blockIdx.x = head, .y = row-block.
// A: [M][K] (fp32 or bf16); Wb packed fragment order; out Hb bf16 [M][NH*64].
template <int KSTEPS, bool A_BF16, int NH>
__global__ __launch_bounds__(256) void gemm_mfma(const void* __restrict__ Av,
                                                 const unsigned short* __restrict__ Wb,
                                                 unsigned short* __restrict__ Hb,
                                                 float* __restrict__ as_out,
                                                 float* __restrict__ ad_out,
                                                 const float* __restrict__ att_s,
                                                 const float* __restrict__ att_d,
                                                 int M) {
  constexpr int K = KSTEPS * 32;
  constexpr int N = NH * 64;
  const int lane = threadIdx.x & 63, wid = threadIdx.x >> 6;
  const int head = blockIdx.x;
  const int rowbase = blockIdx.y * 64 + wid * 16;
  const int g = lane >> 4, li = lane & 15;
  int r_a = rowbase + li;
  if (r_a > M - 1) r_a = M - 1;
  const int n0 = head * 64;

  f32x4 acc[4];
#pragma unroll
  for (int nt = 0; nt < 4; nt++) { acc[nt][0] = 0.f; acc[nt][1] = 0.f; acc[nt][2] = 0.f; acc[nt][3] = 0.f; }

#pragma unroll
  for (int ks = 0; ks < KSTEPS; ks++) {
    bf16x8 a;
    if constexpr (A_BF16) {
      const unsigned short* Ab = (const unsigned short*)Av;
      a = *(const bf16x8*)(Ab + (size_t)r_a * K + ks * 32 + g * 8);
    } else {
      const float* Af = (const float*)Av;
      const float* p = Af + (size_t)r_a * K + ks * 32 + g * 8;
      float4 v0 = *(const float4*)p, v1 = *(const float4*)(p + 4);
      a[0] = (short)f2bf(v0.x); a[1] = (short)f2bf(v0.y);
      a[2] = (short)f2bf(v0.z); a[3] = (short)f2bf(v0.w);
      a[4] = (short)f2bf(v1.x); a[5] = (short)f2bf(v1.y);
      a[6] = (short)f2bf(v1.z); a[7] = (short)f2bf(v1.w);
    }
#pragma unroll
    for (int nt = 0; nt < 4; nt++) {
      bf16x8 b = *(const bf16x8*)(Wb + ((size_t)((head * KSTEPS + ks) * 4 + nt) * 64 + lane) * 8);
      acc[nt] = __builtin_amdgcn_mfma_f32_16x16x32_bf16(a, b, acc[nt], 0, 0, 0);
    }
  }

  // epilogue: alpha dots (fp32 accs) + bf16 store
  float asum[4] = {0.f, 0.f, 0.f, 0.f}, dsum[4] = {0.f, 0.f, 0.f, 0.f};
#pragma unroll
  for (int nt = 0; nt < 4; nt++) {
    float ws = att_s[n0 + nt * 16 + li];
    float wd = att_d[n0 + nt * 16 + li];
#pragma unroll
    for (int r = 0; r < 4; r++) { asum[r] += acc[nt][r] * ws; dsum[r] += acc[nt][r] * wd; }
  }
#pragma unroll
  for (int r = 0; r < 4; r++) {
#pragma unroll
    for (int m = 1; m < 16; m <<= 1) {
      asum[r] += __shfl_xor(asum[r], m);
      dsum[r] += __shfl_xor(dsum[r], m);
    }
  }
#pragma unroll
  for (int r = 0; r < 4; r++) {
    int gr = rowbase + g * 4 + r;
    if (gr < M) {
#pragma unroll
      for (int nt = 0; nt < 4; nt++)
        Hb[(size_t)gr * N + n0 + nt * 16 + li] = f2bf(acc[nt][r]);
      if (li == 0) {
        as_out[(size_t)gr * NH + head] = asum[r];
        ad_out[(size_t)gr * NH + head] = dsum[r];
      }
    }
  }
}

// ---------------- CSR build ----------------
__global__ __launch_bounds__(256) void init_kernel(int* __restrict__ deg,
                                                   int* __restrict__ cursor,
                                                   float* __restrict__ pooled, int n) {
  int i = blockIdx.x * blockDim.x + threadIdx.x;
  if (i < n) { deg[i] = 0; cursor[i] = 0; }
  if (i < 64) pooled[i] = 0.f;
}

__global__ __launch_bounds__(256) void hist_kernel(const int* __restrict__ edge_dst,
                                                   int* __restrict__ deg, int E, int Etot) {
  int e = blockIdx.x * blockDim.x + threadIdx.x;
  if (e >= Etot) return;
  int d = (e < E) ? edge_dst[e] : (e - E);
  atomicAdd(&deg[d], 1);
}

__global__ __launch_bounds__(1024) void scan_kernel(const int* __restrict__ deg,
                                                    int* __restrict__ row_ptr, int n) {
  __shared__ int part[1024];
  const int tid = threadIdx.x;
  const int chunk = (n + 1023) / 1024;
  int start = tid * chunk, end = min(start + chunk, n);
  int s = 0;
  for (int i = start; i < end; i++) s += deg[i];
  part[tid] = s;
  __syncthreads();
  for (int off = 1; off < 1024; off <<= 1) {
    int v = (tid >= off) ? part[tid - off] : 0;
    __syncthreads();
    part[tid] += v;
    __syncthreads();
  }
  int run = (tid == 0) ? 0 : part[tid - 1];
  for (int i = start; i < end; i++) { row_ptr[i] = run; run += deg[i]; }
  if (tid == 0) row_ptr[n] = part[1023];
}

__global__ __launch_bounds__(256) void scatter_kernel(const int* __restrict__ edge_src,
                                                      const int* __restrict__ edge_dst,
                                                      const int* __restrict__ row_ptr,
                                                      int* __restrict__ cursor,
                                                      int* __restrict__ csr_src,
                                                      int E, int Etot) {
  int e = blockIdx.x * blockDim.x + threadIdx.x;
  if (e >= Etot) return;
  int s = (e < E) ? edge_src[e] : (e - E);
  int d = (e < E) ? edge_dst[e] : (e - E);
  int pos = atomicAdd(&cursor[d], 1);
  csr_src[row_ptr[d] + pos] = s;
}

// ---------------- layer-1 aggregate: one wave per dst, bf16 gather ----------------
__global__ __launch_bounds__(256) void agg1_kernel(const unsigned short* __restrict__ Hb,
                                                   const float* __restrict__ as_,
                                                   const float* __restrict__ ad_,
                                                   const int* __restrict__ row_ptr,
                                                   const int* __restrict__ csr_src,
                                                   const float* __restrict__ b1,
                                                   unsigned short* __restrict__ outb, int n) {
  int d = blockIdx.x * 4 + (threadIdx.x >> 6);
  if (d >= n) return;
  int l = threadIdx.x & 63;
  int hh = l >> 4;
  float ad = ad_[d * HEADS + hh];
  int e0 = row_ptr[d], e1 = row_ptr[d + 1];
  float4 acc = {0.f, 0.f, 0.f, 0.f};
  float denom = 0.f;
  int e = e0;
  for (; e + 3 < e1; e += 4) {
    int s0 = csr_src[e], s1 = csr_src[e + 1], s2 = csr_src[e + 2], s3 = csr_src[e + 3];
    float sc0 = as_[s0 * HEADS + hh] + ad;
    float sc1 = as_[s1 * HEADS + hh] + ad;
    float sc2 = as_[s2 * HEADS + hh] + ad;
    float sc3 = as_[s3 * HEADS + hh] + ad;
    uint2 p0 = *(const uint2*)(Hb + (size_t)s0 * C1 + l * 4);
    uint2 p1 = *(const uint2*)(Hb + (size_t)s1 * C1 + l * 4);
    uint2 p2 = *(const uint2*)(Hb + (size_t)s2 * C1 + l * 4);
    uint2 p3 = *(const uint2*)(Hb + (size_t)s3 * C1 + l * 4);
    float w0 = __expf(sc0 > 0.f ? sc0 : NEG_SLOPE * sc0);
    float w1 = __expf(sc1 > 0.f ? sc1 : NEG_SLOPE * sc1);
    float w2 = __expf(sc2 > 0.f ? sc2 : NEG_SLOPE * sc2);
    float w3 = __expf(sc3 > 0.f ? sc3 : NEG_SLOPE * sc3);
    denom += (w0 + w1) + (w2 + w3);
    acc.x += w0 * bf_lo(p0.x); acc.y += w0 * bf_hi(p0.x); acc.z += w0 * bf_lo(p0.y); acc.w += w0 * bf_hi(p0.y);
    acc.x += w1 * bf_lo(p1.x); acc.y += w1 * bf_hi(p1.x); acc.z += w1 * bf_lo(p1.y); acc.w += w1 * bf_hi(p1.y);
    acc.x += w2 * bf_lo(p2.x); acc.y += w2 * bf_hi(p2.x); acc.z += w2 * bf_lo(p2.y); acc.w += w2 * bf_hi(p2.y);
    acc.x += w3 * bf_lo(p3.x); acc.y += w3 * bf_hi(p3.x); acc.z += w3 * bf_lo(p3.y); acc.w += w3 * bf_hi(p3.y);
  }
  for (; e < e1; e++) {
    int s = csr_src[e];
    float sc = as_[s * HEADS + hh] + ad;
    float w = __expf(sc > 0.f ? sc : NEG_SLOPE * sc);
    denom += w;
    uint2 p = *(const uint2*)(Hb + (size_t)s * C1 + l * 4);
    acc.x += w * bf_lo(p.x); acc.y += w * bf_hi(p.x); acc.z += w * bf_lo(p.y); acc.w += w * bf_hi(p.y);
  }
  float inv = 1.f / (denom + 1e-16f);
  float4 bb = *(const float4*)(b1 + l * 4);
  float4 o;
  o.x = acc.x * inv + bb.x; o.y = acc.y * inv + bb.y;
  o.z = acc.z * inv + bb.z; o.w = acc.w * inv + bb.w;
  o.x = o.x > 0.f ? o.x : (__expf(o.x) - 1.f);
  o.y = o.y > 0.f ? o.y : (__expf(o.y) - 1.f);
  o.z = o.z > 0.f ? o.z : (__expf(o.z) - 1.f);
  o.w = o.w > 0.f ? o.w : (__expf(o.w) - 1.f);
  uint2 pk;
  pk.x = (unsigned int)f2bf(o.x) | ((unsigned int)f2bf(o.y) << 16);
  pk.y = (unsigned int)f2bf(o.z) | ((unsigned int)f2bf(o.w) << 16);
  *(uint2*)(outb + (size_t)d * C1 + l * 4) = pk;
}

// ---------------- layer-2 aggregate ----------------
__global__ __launch_bounds__(256) void agg2_kernel(const unsigned short* __restrict__ Hb,
                                                   const float* __restrict__ as_,
                                                   const float* __restrict__ ad_,
                                                   const int* __restrict__ row_ptr,
                                                   const int* __restrict__ csr_src,
                                                   const float* __restrict__ b2,
                                                   float* __restrict__ out, int n) {
  int d = blockIdx.x * 4 + (threadIdx.x >> 6);
  if (d >= n) return;
  int l = threadIdx.x & 63;
  int half = l >> 5, li = l & 31;
  float ad = ad_[d];
  int e0 = row_ptr[d], e1 = row_ptr[d + 1];
  float acc0 = 0.f, acc1 = 0.f, denom = 0.f;
  for (int e = e0 + half; e < e1; e += 2) {
    int s = csr_src[e];
    float sc = as_[s] + ad;
    sc = sc > 0.f ? sc : NEG_SLOPE * sc;
    float w = __expf(sc);
    denom += w;
    unsigned int p = *(const unsigned int*)(Hb + (size_t)s * HID + li * 2);
    acc0 += w * bf_lo(p);
    acc1 += w * bf_hi(p);
  }
  acc0 += __shfl_xor(acc0, 32);
  acc1 += __shfl_xor(acc1, 32);
  denom += __shfl_xor(denom, 32);
  if (half == 0) {
    float inv = 1.f / (denom + 1e-16f);
    float o0 = acc0 * inv + b2[li * 2];
    float o1 = acc1 * inv + b2[li * 2 + 1];
    o0 = o0 > 0.f ? o0 : (__expf(o0) - 1.f);
    o1 = o1 > 0.f ? o1 : (__expf(o1) - 1.f);
    float2 ov; ov.x = o0; ov.y = o1;
    *(float2*)(out + (size_t)d * HID + li * 2) = ov;
  }
}

// ---------------- mean pool + head ----------------
__global__ __launch_bounds__(256) void pool_partial(const float* __restrict__ h,
                                                    float* __restrict__ pooled, int n) {
  int c = threadIdx.x & 63, rg = threadIdx.x >> 6;
  float acc = 0.f;
  for (int r = blockIdx.x * 4 + rg; r < n; r += gridDim.x * 4)
    acc += h[(size_t)r * HID + c];
  __shared__ float lds[256];
  lds[threadIdx.x] = acc;
  __syncthreads();
  if (rg == 0) {
    float v = lds[c] + lds[64 + c] + lds[128 + c] + lds[192 + c];
    atomicAdd(&pooled[c], v);
  }
}

__global__ __launch_bounds__(64) void head_kernel(const float* __restrict__ pooled,
                                                  const float* __restrict__ Wc,
                                                  const float* __restrict__ bc,
                                                  float* __restrict__ out, float inv_n) {
  int l = threadIdx.x;
  float p = pooled[l] * inv_n;
  float o0 = wave_reduce_sum(p * Wc[l * 2 + 0]);
  float o1 = wave_reduce_sum(p * Wc[l * 2 + 1]);
  if (l == 0) { out[0] = o0 + bc[0]; out[1] = o1 + bc[1]; }
}

// ---------------- host ----------------
static inline size_t align256(size_t x) { return (x + 255) & ~(size_t)255; }

extern "C" void kernel_launch(void* const* d_in, const int* in_sizes, int n_in,
                              void* d_out, int out_size, void* d_ws, size_t ws_size,
                              hipStream_t stream) {
  const float* x        = (const float*)d_in[0];
  const int*   ei       = (const int*)d_in[1];
  const float* W1       = (const float*)d_in[2];
  const float* att_src1 = (const float*)d_in[3];
  const float* att_dst1 = (const float*)d_in[4];
  const float* b1       = (const float*)d_in[5];
  const float* W2       = (const float*)d_in[6];
  const float* att_src2 = (const float*)d_in[7];
  const float* att_dst2 = (const float*)d_in[8];
  const float* b2       = (const float*)d_in[9];
  const float* Wc       = (const float*)d_in[10];
  const float* bc       = (const float*)d_in[11];
  float* out = (float*)d_out;

  const int N = in_sizes[0] / F_IN;          // 50000
  const int E = in_sizes[1] / 2;             // 1,600,000
  const int Etot = E + N;                    // + self loops
  const int* ei_src = ei;
  const int* ei_dst = ei + E;

  // workspace layout (~78 MB)
  char* w = (char*)d_ws;
  size_t off = 0;
  unsigned short* h1b    = (unsigned short*)(w + off); off += align256((size_t)N * C1 * 2);
  unsigned short* h1actb = (unsigned short*)(w + off); off += align256((size_t)N * C1 * 2);
  unsigned short* h2b    = (unsigned short*)(w + off); off += align256((size_t)N * HID * 2);
  float* h2act = (float*)(w + off); off += align256((size_t)N * HID * 4);
  float* as1   = (float*)(w + off); off += align256((size_t)N * HEADS * 4);
  float* ad1   = (float*)(w + off); off += align256((size_t)N * HEADS * 4);
  float* as2   = (float*)(w + off); off += align256((size_t)N * 4);
  float* ad2   = (float*)(w + off); off += align256((size_t)N * 4);
  int* deg     = (int*)(w + off);   off += align256((size_t)N * 4);
  int* cursor  = (int*)(w + off);   off += align256((size_t)N * 4);
  int* row_ptr = (int*)(w + off);   off += align256((size_t)(N + 1) * 4);
  float* pooled= (float*)(w + off); off += align256(64 * 4);
  unsigned short* W1b = (unsigned short*)(w + off); off += align256(32768 * 2);
  unsigned short* W2b = (unsigned short*)(w + off); off += align256(16384 * 2);
  int* csr_src = (int*)(w + off);   off += align256((size_t)Etot * 4);

  // CSR build + weight pack
  init_kernel<<<(N + 255) / 256, 256, 0, stream>>>(deg, cursor, pooled, N);
  int eb = (Etot + 255) / 256;
  hist_kernel<<<eb, 256, 0, stream>>>(ei_dst, deg, E, Etot);
  pack_w<<<64, 256, 0, stream>>>(W1, W2, W1b, W2b);
  scan_kernel<<<1, 1024, 0, stream>>>(deg, row_ptr, N);
  scatter_kernel<<<eb, 256, 0, stream>>>(ei_src, ei_dst, row_ptr, cursor, csr_src, E, Etot);

  int nb4 = (N + 3) / 4;
  int rowblocks = (N + 63) / 64;

  // layer 1
  dim3 g1(HEADS, rowblocks);
  gemm_mfma<4, false, HEADS><<<g1, 256, 0, stream>>>(x, W1b, h1b, as1, ad1,
                                                     att_src1, att_dst1, N);
  agg1_kernel<<<nb4, 256, 0, stream>>>(h1b, as1, ad1, row_ptr, csr_src, b1, h1actb, N);

  // layer 2
  dim3 g2(1, rowblocks);
  gemm_mfma<8, true, 1><<<g2, 256, 0, stream>>>(h1actb, W2b, h2b, as2, ad2,
                                                att_src2, att_dst2, N);
  agg2_kernel<<<nb4, 256, 0, stream>>>(h2b, as2, ad2, row_ptr, csr_src, b2, h2act, N);

  // pool + head
  pool_partial<<<256, 256, 0, stream>>>(h2act, pooled, N);
  head_kernel<<<1, 64, 0, stream>>>(pooled, Wc, bc, out, 1.0f / (float)N);
}

// Round 4
// 466.521 us; speedup vs baseline: 1.7991x; 1.1233x over previous
//
#include <hip/hip_runtime.h>
#include <cstdint>
#include <cstddef>

#define NEG_SLOPE 0.2f
#define F_IN 128
#define C1 256      // HEADS*HID layer-1 width
#define HID 64
#define HEADS 4
#define LOG2E 1.4426950408889634f

typedef __attribute__((ext_vector_type(8))) short bf16x8;
typedef __attribute__((ext_vector_type(4))) float f32x4;

__device__ __forceinline__ float wave_reduce_sum(float v) {
#pragma unroll
  for (int off = 32; off > 0; off >>= 1) v += __shfl_down(v, off);
  return v;
}

__device__ __forceinline__ unsigned short f2bf(float f) {
  union { float f; unsigned int u; } v; v.f = f;
  unsigned int u = v.u;
  unsigned int r = (u + 0x7fffu + ((u >> 16) & 1u)) >> 16;  // RNE
  return (unsigned short)r;
}
__device__ __forceinline__ float bf_lo(unsigned int u) { return __uint_as_float(u << 16); }
__device__ __forceinline__ float bf_hi(unsigned int u) { return __uint_as_float(u & 0xffff0000u); }

// ---------------- weight pre-pack into MFMA fragment order ----------------
__global__ __launch_bounds__(256) void pack_w(const float* __restrict__ W1,
                                              const float* __restrict__ W2,
                                              unsigned short* __restrict__ W1b,
                                              unsigned short* __restrict__ W2b) {
  for (int idx = threadIdx.x + blockIdx.x * 256; idx < 32768 + 16384;
       idx += 256 * gridDim.x) {
    if (idx < 32768) {
      int head = idx >> 13, ks = (idx >> 11) & 3, nt = (idx >> 9) & 3;
      int lane = (idx >> 3) & 63, j = idx & 7;
      int k = ks * 32 + (lane >> 4) * 8 + j;
      int c = head * 64 + nt * 16 + (lane & 15);
      W1b[idx] = f2bf(W1[k * 256 + c]);
    } else {
      int o = idx - 32768;
      int ks = o >> 11, nt = (o >> 9) & 3, lane = (o >> 3) & 63, j = o & 7;
      int k = ks * 32 + (lane >> 4) * 8 + j;
      int c = nt * 16 + (lane & 15);
      W2b[o] = f2bf(W2[k * 64 + c]);
    }
  }
}

// ---------------- MFMA GEMM, all heads per block ----------------
// block = 256 thr (4 waves), each wave = 16 rows x (NH*64) cols; grid = rowblocks.
// Epilogue: Hb bf16; as/ad = (C_row . att) * LOG2E  (pre-scaled for exp2).
template <int KSTEPS, bool A_BF16, int NH>
__global__ __launch_bounds__(256) void gemm_mfma(const void* __restrict__ Av,
                                                 const unsigned short* __restrict__ Wb,
                                                 unsigned short* __restrict__ Hb,
                                                 float* __restrict__ as_out,
                                                 float* __restrict__ ad_out,
                                                 const float* __restrict__ att_s,
                                                 const float* __restrict__ att_d,
                                                 int M) {
  constexpr int K = KSTEPS * 32;
  constexpr int N = NH * 64;
  const int lane = threadIdx.x & 63, wid = threadIdx.x >> 6;
  const int rowbase = blockIdx.x * 64 + wid * 16;
  const int g = lane >> 4, li = lane & 15;
  int r_a = rowbase + li;
  if (r_a > M - 1) r_a = M - 1;

  f32x4 acc[NH][4];
#pragma unroll
  for (int h = 0; h < NH; h++)
#pragma unroll
    for (int nt = 0; nt < 4; nt++) {
      acc[h][nt][0] = 0.f; acc[h][nt][1] = 0.f; acc[h][nt][2] = 0.f; acc[h][nt][3] = 0.f;
    }

#pragma unroll
  for (int ks = 0; ks < KSTEPS; ks++) {
    bf16x8 a;
    if constexpr (A_BF16) {
      const unsigned short* Ab = (const unsigned short*)Av;
      a = *(const bf16x8*)(Ab + (size_t)r_a * K + ks * 32 + g * 8);
    } else {
      const float* Af = (const float*)Av;
      const float* p = Af + (size_t)r_a * K + ks * 32 + g * 8;
      float4 v0 = *(const float4*)p, v1 = *(const float4*)(p + 4);
      a[0] = (short)f2bf(v0.x); a[1] = (short)f2bf(v0.y);
      a[2] = (short)f2bf(v0.z); a[3] = (short)f2bf(v0.w);
      a[4] = (short)f2bf(v1.x); a[5] = (short)f2bf(v1.y);
      a[6] = (short)f2bf(v1.z); a[7] = (short)f2bf(v1.w);
    }
#pragma unroll
    for (int h = 0; h < NH; h++)
#pragma unroll
      for (int nt = 0; nt < 4; nt++) {
        bf16x8 b = *(const bf16x8*)(Wb + ((size_t)((h * KSTEPS + ks) * 4 + nt) * 64 + lane) * 8);
        acc[h][nt] = __builtin_amdgcn_mfma_f32_16x16x32_bf16(a, b, acc[h][nt], 0, 0, 0);
      }
  }

#pragma unroll
  for (int h = 0; h < NH; h++) {
    float asum[4] = {0.f, 0.f, 0.f, 0.f}, dsum[4] = {0.f, 0.f, 0.f, 0.f};
#pragma unroll
    for (int nt = 0; nt < 4; nt++) {
      float ws = att_s[h * 64 + nt * 16 + li];
      float wd = att_d[h * 64 + nt * 16 + li];
#pragma unroll
      for (int r = 0; r < 4; r++) { asum[r] += acc[h][nt][r] * ws; dsum[r] += acc[h][nt][r] * wd; }
    }
#pragma unroll
    for (int r = 0; r < 4; r++) {
#pragma unroll
      for (int m = 1; m < 16; m <<= 1) {
        asum[r] += __shfl_xor(asum[r], m);
        dsum[r] += __shfl_xor(dsum[r], m);
      }
    }
#pragma unroll
    for (int r = 0; r < 4; r++) {
      int gr = rowbase + g * 4 + r;
      if (gr < M) {
#pragma unroll
        for (int nt = 0; nt < 4; nt++)
          Hb[(size_t)gr * N + h * 64 + nt * 16 + li] = f2bf(acc[h][nt][r]);
        if (li == 0) {
          as_out[(size_t)gr * NH + h] = asum[r] * LOG2E;
          ad_out[(size_t)gr * NH + h] = dsum[r] * LOG2E;
        }
      }
    }
  }
}

// ---------------- CSR build ----------------
__global__ __launch_bounds__(256) void init_kernel(int* __restrict__ deg,
                                                   float* __restrict__ poolrep, int n) {
  int i = blockIdx.x * blockDim.x + threadIdx.x;
  if (i < n) deg[i] = 0;
  if (i < 64 * 64) poolrep[i] = 0.f;
}

__global__ __launch_bounds__(256) void hist_kernel(const int* __restrict__ edge_dst,
                                                   int* __restrict__ deg, int E, int Etot) {
  int e = blockIdx.x * blockDim.x + threadIdx.x;
  if (e >= Etot) return;
  int d = (e < E) ? edge_dst[e] : (e - E);
  atomicAdd(&deg[d], 1);
}

__global__ __launch_bounds__(1024) void scan_kernel(const int* __restrict__ deg,
                                                    int* __restrict__ row_ptr,
                                                    int* __restrict__ cursor, int n) {
  __shared__ int part[1024];
  const int tid = threadIdx.x;
  const int chunk = (n + 1023) / 1024;
  int start = tid * chunk, end = min(start + chunk, n);
  int s = 0;
  for (int i = start; i < end; i++) s += deg[i];
  part[tid] = s;
  __syncthreads();
  for (int off = 1; off < 1024; off <<= 1) {
    int v = (tid >= off) ? part[tid - off] : 0;
    __syncthreads();
    part[tid] += v;
    __syncthreads();
  }
  int run = (tid == 0) ? 0 : part[tid - 1];
  for (int i = start; i < end; i++) { row_ptr[i] = run; cursor[i] = run; run += deg[i]; }
  if (tid == 0) row_ptr[n] = part[1023];
}

// scatter + layer-1 edge weights fused: record = {src, w0|w1, w2|w3, 0} (w bf16)
__global__ __launch_bounds__(256) void scatter_rec(const int* __restrict__ esrc,
                                                   const int* __restrict__ edst,
                                                   int* __restrict__ cursor,
                                                   const float4* __restrict__ as1,
                                                   const float4* __restrict__ ad1,
                                                   int4* __restrict__ recs,
                                                   int E, int Etot) {
  int e = blockIdx.x * blockDim.x + threadIdx.x;
  if (e >= Etot) return;
  int s = (e < E) ? esrc[e] : (e - E);
  int d = (e < E) ? edst[e] : (e - E);
  int pos = atomicAdd(&cursor[d], 1);
  float4 a = as1[s], b = ad1[d];
  float s0 = a.x + b.x, s1 = a.y + b.y, s2 = a.z + b.z, s3 = a.w + b.w;
  float w0 = exp2f(fmaxf(s0, NEG_SLOPE * s0));
  float w1 = exp2f(fmaxf(s1, NEG_SLOPE * s1));
  float w2 = exp2f(fmaxf(s2, NEG_SLOPE * s2));
  float w3 = exp2f(fmaxf(s3, NEG_SLOPE * s3));
  int4 r;
  r.x = s;
  r.y = (int)((unsigned)f2bf(w0) | ((unsigned)f2bf(w1) << 16));
  r.z = (int)((unsigned)f2bf(w2) | ((unsigned)f2bf(w3) << 16));
  r.w = 0;
  recs[pos] = r;
}

// ---------------- layer-1 aggregate: one wave per dst, record-driven ----------------
__global__ __launch_bounds__(256) void agg1_kernel(const unsigned short* __restrict__ Hb,
                                                   const int4* __restrict__ recs,
                                                   const int* __restrict__ row_ptr,
                                                   const float* __restrict__ b1,
                                                   unsigned short* __restrict__ outb, int n) {
  int d = blockIdx.x * 4 + (threadIdx.x >> 6);
  int l = threadIdx.x & 63;
  int hh = l >> 4;
  int e0 = __builtin_amdgcn_readfirstlane(row_ptr[d]);
  int e1 = __builtin_amdgcn_readfirstlane(row_ptr[d + 1]);
  const int shamt = (hh & 1) ? 0 : 16;
  const bool lowpair = hh < 2;
  float4 acc = {0.f, 0.f, 0.f, 0.f};
  float denom = 0.f;
  int e = e0;
#define WSEL(r) __uint_as_float(((unsigned)((lowpair) ? (r).y : (r).z) << shamt) & 0xffff0000u)
  for (; e + 3 < e1; e += 4) {
    int4 r0 = recs[e], r1 = recs[e + 1], r2 = recs[e + 2], r3 = recs[e + 3];
    float w0 = WSEL(r0), w1 = WSEL(r1), w2 = WSEL(r2), w3 = WSEL(r3);
    uint2 p0 = *(const uint2*)(Hb + (size_t)r0.x * C1 + l * 4);
    uint2 p1 = *(const uint2*)(Hb + (size_t)r1.x * C1 + l * 4);
    uint2 p2 = *(const uint2*)(Hb + (size_t)r2.x * C1 + l * 4);
    uint2 p3 = *(const uint2*)(Hb + (size_t)r3.x * C1 + l * 4);
    denom += (w0 + w1) + (w2 + w3);
    acc.x += w0 * bf_lo(p0.x); acc.y += w0 * bf_hi(p0.x); acc.z += w0 * bf_lo(p0.y); acc.w += w0 * bf_hi(p0.y);
    acc.x += w1 * bf_lo(p1.x); acc.y += w1 * bf_hi(p1.x); acc.z += w1 * bf_lo(p1.y); acc.w += w1 * bf_hi(p1.y);
    acc.x += w2 * bf_lo(p2.x); acc.y += w2 * bf_hi(p2.x); acc.z += w2 * bf_lo(p2.y); acc.w += w2 * bf_hi(p2.y);
    acc.x += w3 * bf_lo(p3.x); acc.y += w3 * bf_hi(p3.x); acc.z += w3 * bf_lo(p3.y); acc.w += w3 * bf_hi(p3.y);
  }
  for (; e < e1; e++) {
    int4 r0 = recs[e];
    float w = WSEL(r0);
    denom += w;
    uint2 p = *(const uint2*)(Hb + (size_t)r0.x * C1 + l * 4);
    acc.x += w * bf_lo(p.x); acc.y += w * bf_hi(p.x); acc.z += w * bf_lo(p.y); acc.w += w * bf_hi(p.y);
  }
#undef WSEL
  float inv = 1.f / (denom + 1e-16f);
  float4 bb = *(const float4*)(b1 + l * 4);
  float4 o;
  o.x = acc.x * inv + bb.x; o.y = acc.y * inv + bb.y;
  o.z = acc.z * inv + bb.z; o.w = acc.w * inv + bb.w;
  o.x = o.x > 0.f ? o.x : (__expf(o.x) - 1.f);
  o.y = o.y > 0.f ? o.y : (__expf(o.y) - 1.f);
  o.z = o.z > 0.f ? o.z : (__expf(o.z) - 1.f);
  o.w = o.w > 0.f ? o.w : (__expf(o.w) - 1.f);
  uint2 pk;
  pk.x = (unsigned int)f2bf(o.x) | ((unsigned int)f2bf(o.y) << 16);
  pk.y = (unsigned int)f2bf(o.z) | ((unsigned int)f2bf(o.w) << 16);
  *(uint2*)(outb + (size_t)d * C1 + l * 4) = pk;
}

// ---------------- layer-2 aggregate + fused mean pool ----------------
// 16 lanes per edge (4 edges in flight); lane li covers ch 4li..4li+3.
__global__ __launch_bounds__(256) void agg2_pool(const unsigned short* __restrict__ Hb,
                                                 const float* __restrict__ as_,
                                                 const float* __restrict__ ad_,
                                                 const int* __restrict__ row_ptr,
                                                 const int4* __restrict__ recs,
                                                 const float* __restrict__ b2,
                                                 float* __restrict__ poolrep, int n) {
  __shared__ float lds[4][64];
  int wid = threadIdx.x >> 6;
  int d = blockIdx.x * 4 + wid;
  int l = threadIdx.x & 63, q = l >> 4, li = l & 15;
  float ad = ad_[d];
  int e0 = row_ptr[d], e1 = row_ptr[d + 1];
  float4 acc = {0.f, 0.f, 0.f, 0.f};
  float denom = 0.f;
  for (int e = e0 + q; e < e1; e += 4) {
    int s = ((const int*)recs)[(size_t)e * 4];
    float sc = as_[s] + ad;
    float w = exp2f(fmaxf(sc, NEG_SLOPE * sc));
    denom += w;
    uint2 p = *(const uint2*)(Hb + (size_t)s * HID + li * 4);
    acc.x += w * bf_lo(p.x); acc.y += w * bf_hi(p.x);
    acc.z += w * bf_lo(p.y); acc.w += w * bf_hi(p.y);
  }
#pragma unroll
  for (int m = 16; m <= 32; m <<= 1) {
    acc.x += __shfl_xor(acc.x, m); acc.y += __shfl_xor(acc.y, m);
    acc.z += __shfl_xor(acc.z, m); acc.w += __shfl_xor(acc.w, m);
    denom += __shfl_xor(denom, m);
  }
  if (q == 0) {
    float inv = 1.f / (denom + 1e-16f);
    float o[4] = {acc.x * inv + b2[li * 4], acc.y * inv + b2[li * 4 + 1],
                  acc.z * inv + b2[li * 4 + 2], acc.w * inv + b2[li * 4 + 3]};
#pragma unroll
    for (int j = 0; j < 4; j++) {
      float v = o[j];
      lds[wid][li * 4 + j] = v > 0.f ? v : (__expf(v) - 1.f);
    }
  }
  __syncthreads();
  if (threadIdx.x < 64) {
    int c = threadIdx.x;
    float v = lds[0][c] + lds[1][c] + lds[2][c] + lds[3][c];
    atomicAdd(&poolrep[(blockIdx.x & 63) * 64 + c], v);
  }
}

__global__ __launch_bounds__(64) void head_kernel(const float* __restrict__ poolrep,
                                                  const float* __restrict__ Wc,
                                                  const float* __restrict__ bc,
                                                  float* __restrict__ out, float inv_n) {
  int l = threadIdx.x;
  float p = 0.f;
  for (int k = 0; k < 64; k++) p += poolrep[k * 64 + l];
  p *= inv_n;
  float o0 = wave_reduce_sum(p * Wc[l * 2 + 0]);
  float o1 = wave_reduce_sum(p * Wc[l * 2 + 1]);
  if (l == 0) { out[0] = o0 + bc[0]; out[1] = o1 + bc[1]; }
}

// ---------------- host ----------------
static inline size_t align256(size_t x) { return (x + 255) & ~(size_t)255; }

extern "C" void kernel_launch(void* const* d_in, const int* in_sizes, int n_in,
                              void* d_out, int out_size, void* d_ws, size_t ws_size,
                              hipStream_t stream) {
  const float* x        = (const float*)d_in[0];
  const int*   ei       = (const int*)d_in[1];
  const float* W1       = (const float*)d_in[2];
  const float* att_src1 = (const float*)d_in[3];
  const float* att_dst1 = (const float*)d_in[4];
  const float* b1       = (const float*)d_in[5];
  const float* W2       = (const float*)d_in[6];
  const float* att_src2 = (const float*)d_in[7];
  const float* att_dst2 = (const float*)d_in[8];
  const float* b2       = (const float*)d_in[9];
  const float* Wc       = (const float*)d_in[10];
  const float* bc       = (const float*)d_in[11];
  float* out = (float*)d_out;

  const int N = in_sizes[0] / F_IN;          // 50000
  const int E = in_sizes[1] / 2;             // 1,600,000
  const int Etot = E + N;                    // + self loops
  const int* ei_src = ei;
  const int* ei_dst = ei + E;

  // workspace layout (~86 MB)
  char* w = (char*)d_ws;
  size_t off = 0;
  unsigned short* h1b    = (unsigned short*)(w + off); off += align256((size_t)N * C1 * 2);
  unsigned short* h1actb = (unsigned short*)(w + off); off += align256((size_t)N * C1 * 2);
  unsigned short* h2b    = (unsigned short*)(w + off); off += align256((size_t)N * HID * 2);
  float* as1   = (float*)(w + off); off += align256((size_t)N * HEADS * 4);
  float* ad1   = (float*)(w + off); off += align256((size_t)N * HEADS * 4);
  float* as2   = (float*)(w + off); off += align256((size_t)N * 4);
  float* ad2   = (float*)(w + off); off += align256((size_t)N * 4);
  int* deg     = (int*)(w + off);   off += align256((size_t)N * 4);
  int* cursor  = (int*)(w + off);   off += align256((size_t)N * 4);
  int* row_ptr = (int*)(w + off);   off += align256((size_t)(N + 1) * 4);
  float* poolrep = (float*)(w + off); off += align256(64 * 64 * 4);
  unsigned short* W1b = (unsigned short*)(w + off); off += align256(32768 * 2);
  unsigned short* W2b = (unsigned short*)(w + off); off += align256(16384 * 2);
  int4* recs   = (int4*)(w + off);  off += align256((size_t)Etot * 16);

  int eb = (Etot + 255) / 256;
  int nb4 = (N + 3) / 4;
  int rowblocks = (N + 63) / 64;

  init_kernel<<<(N + 255) / 256, 256, 0, stream>>>(deg, poolrep, N);
  hist_kernel<<<eb, 256, 0, stream>>>(ei_dst, deg, E, Etot);
  scan_kernel<<<1, 1024, 0, stream>>>(deg, row_ptr, cursor, N);
  pack_w<<<64, 256, 0, stream>>>(W1, W2, W1b, W2b);

  // layer 1 GEMM (all heads per block), then edge-weight scatter, then aggregate
  gemm_mfma<4, false, HEADS><<<rowblocks, 256, 0, stream>>>(x, W1b, h1b, as1, ad1,
                                                            att_src1, att_dst1, N);
  scatter_rec<<<eb, 256, 0, stream>>>(ei_src, ei_dst, cursor,
                                      (const float4*)as1, (const float4*)ad1,
                                      recs, E, Etot);
  agg1_kernel<<<nb4, 256, 0, stream>>>(h1b, recs, row_ptr, b1, h1actb, N);

  // layer 2
  gemm_mfma<8, true, 1><<<rowblocks, 256, 0, stream>>>(h1actb, W2b, h2b, as2, ad2,
                                                       att_src2, att_dst2, N);
  agg2_pool<<<nb4, 256, 0, stream>>>(h2b, as2, ad2, row_ptr, recs, b2, poolrep, N);

  head_kernel<<<1, 64, 0, stream>>>(poolrep, Wc, bc, out, 1.0f / (float)N);
}

// Round 5
// 370.537 us; speedup vs baseline: 2.2652x; 1.2590x over previous
//
#include <hip/hip_runtime.h>
#include <cstdint>
#include <cstddef>

#define NEG_SLOPE 0.2f
#define F_IN 128
#define C1 256      // HEADS*HID layer-1 width
#define HID 64
#define HEADS 4
#define LOG2E 1.4426950408889634f

typedef __attribute__((ext_vector_type(8))) short bf16x8;
typedef __attribute__((ext_vector_type(4))) float f32x4;

__device__ __forceinline__ float wave_reduce_sum(float v) {
#pragma unroll
  for (int off = 32; off > 0; off >>= 1) v += __shfl_down(v, off);
  return v;
}

__device__ __forceinline__ int wave_reduce_sum_i(int v) {
#pragma unroll
  for (int off = 32; off > 0; off >>= 1) v += __shfl_down(v, off);
  return v;
}

__device__ __forceinline__ unsigned short f2bf(float f) {
  union { float f; unsigned int u; } v; v.f = f;
  unsigned int u = v.u;
  unsigned int r = (u + 0x7fffu + ((u >> 16) & 1u)) >> 16;  // RNE
  return (unsigned short)r;
}
__device__ __forceinline__ float bf_lo(unsigned int u) { return __uint_as_float(u << 16); }
__device__ __forceinline__ float bf_hi(unsigned int u) { return __uint_as_float(u & 0xffff0000u); }

// ---------------- weight pre-pack into MFMA fragment order ----------------
__global__ __launch_bounds__(256) void pack_w(const float* __restrict__ W1,
                                              const float* __restrict__ W2,
                                              unsigned short* __restrict__ W1b,
                                              unsigned short* __restrict__ W2b) {
  for (int idx = threadIdx.x + blockIdx.x * 256; idx < 32768 + 16384;
       idx += 256 * gridDim.x) {
    if (idx < 32768) {
      int head = idx >> 13, ks = (idx >> 11) & 3, nt = (idx >> 9) & 3;
      int lane = (idx >> 3) & 63, j = idx & 7;
      int k = ks * 32 + (lane >> 4) * 8 + j;
      int c = head * 64 + nt * 16 + (lane & 15);
      W1b[idx] = f2bf(W1[k * 256 + c]);
    } else {
      int o = idx - 32768;
      int ks = o >> 11, nt = (o >> 9) & 3, lane = (o >> 3) & 63, j = o & 7;
      int k = ks * 32 + (lane >> 4) * 8 + j;
      int c = nt * 16 + (lane & 15);
      W2b[o] = f2bf(W2[k * 64 + c]);
    }
  }
}

// ---------------- MFMA GEMM, all heads per block ----------------
template <int KSTEPS, bool A_BF16, int NH>
__global__ __launch_bounds__(256) void gemm_mfma(const void* __restrict__ Av,
                                                 const unsigned short* __restrict__ Wb,
                                                 unsigned short* __restrict__ Hb,
                                                 float* __restrict__ as_out,
                                                 float* __restrict__ ad_out,
                                                 const float* __restrict__ att_s,
                                                 const float* __restrict__ att_d,
                                                 int M) {
  constexpr int K = KSTEPS * 32;
  constexpr int N = NH * 64;
  const int lane = threadIdx.x & 63, wid = threadIdx.x >> 6;
  const int rowbase = blockIdx.x * 64 + wid * 16;
  const int g = lane >> 4, li = lane & 15;
  int r_a = rowbase + li;
  if (r_a > M - 1) r_a = M - 1;

  f32x4 acc[NH][4];
#pragma unroll
  for (int h = 0; h < NH; h++)
#pragma unroll
    for (int nt = 0; nt < 4; nt++) {
      acc[h][nt][0] = 0.f; acc[h][nt][1] = 0.f; acc[h][nt][2] = 0.f; acc[h][nt][3] = 0.f;
    }

#pragma unroll
  for (int ks = 0; ks < KSTEPS; ks++) {
    bf16x8 a;
    if constexpr (A_BF16) {
      const unsigned short* Ab = (const unsigned short*)Av;
      a = *(const bf16x8*)(Ab + (size_t)r_a * K + ks * 32 + g * 8);
    } else {
      const float* Af = (const float*)Av;
      const float* p = Af + (size_t)r_a * K + ks * 32 + g * 8;
      float4 v0 = *(const float4*)p, v1 = *(const float4*)(p + 4);
      a[0] = (short)f2bf(v0.x); a[1] = (short)f2bf(v0.y);
      a[2] = (short)f2bf(v0.z); a[3] = (short)f2bf(v0.w);
      a[4] = (short)f2bf(v1.x); a[5] = (short)f2bf(v1.y);
      a[6] = (short)f2bf(v1.z); a[7] = (short)f2bf(v1.w);
    }
#pragma unroll
    for (int h = 0; h < NH; h++)
#pragma unroll
      for (int nt = 0; nt < 4; nt++) {
        bf16x8 b = *(const bf16x8*)(Wb + ((size_t)((h * KSTEPS + ks) * 4 + nt) * 64 + lane) * 8);
        acc[h][nt] = __builtin_amdgcn_mfma_f32_16x16x32_bf16(a, b, acc[h][nt], 0, 0, 0);
      }
  }

#pragma unroll
  for (int h = 0; h < NH; h++) {
    float asum[4] = {0.f, 0.f, 0.f, 0.f}, dsum[4] = {0.f, 0.f, 0.f, 0.f};
#pragma unroll
    for (int nt = 0; nt < 4; nt++) {
      float ws = att_s[h * 64 + nt * 16 + li];
      float wd = att_d[h * 64 + nt * 16 + li];
#pragma unroll
      for (int r = 0; r < 4; r++) { asum[r] += acc[h][nt][r] * ws; dsum[r] += acc[h][nt][r] * wd; }
    }
#pragma unroll
    for (int r = 0; r < 4; r++) {
#pragma unroll
      for (int m = 1; m < 16; m <<= 1) {
        asum[r] += __shfl_xor(asum[r], m);
        dsum[r] += __shfl_xor(dsum[r], m);
      }
    }
#pragma unroll
    for (int r = 0; r < 4; r++) {
      int gr = rowbase + g * 4 + r;
      if (gr < M) {
#pragma unroll
        for (int nt = 0; nt < 4; nt++)
          Hb[(size_t)gr * N + h * 64 + nt * 16 + li] = f2bf(acc[h][nt][r]);
        if (li == 0) {
          as_out[(size_t)gr * NH + h] = asum[r] * LOG2E;
          ad_out[(size_t)gr * NH + h] = dsum[r] * LOG2E;
        }
      }
    }
  }
}

// ---------------- CSR build ----------------
__global__ __launch_bounds__(256) void init_kernel(int* __restrict__ deg,
                                                   float* __restrict__ poolrep, int n) {
  int i = blockIdx.x * blockDim.x + threadIdx.x;
  if (i < n) deg[i] = 0;
  if (i < 64 * 64) poolrep[i] = 0.f;
}

__global__ __launch_bounds__(256) void hist_kernel(const int* __restrict__ edge_dst,
                                                   int* __restrict__ deg, int E, int Etot) {
  int e = blockIdx.x * blockDim.x + threadIdx.x;
  if (e >= Etot) return;
  int d = (e < E) ? edge_dst[e] : (e - E);
  atomicAdd(&deg[d], 1);
}

// ---- hierarchical scan: part sums -> top scan -> down-sweep ----
__global__ __launch_bounds__(256) void scan_part(const int* __restrict__ deg,
                                                 int* __restrict__ partials, int n) {
  const int tid = threadIdx.x, lane = tid & 63, wid = tid >> 6;
  int i0 = blockIdx.x * 2048 + tid * 8;
  int s = 0;
#pragma unroll
  for (int j = 0; j < 8; j++) { int i = i0 + j; if (i < n) s += deg[i]; }
  s = wave_reduce_sum_i(s);
  __shared__ int wsum[4];
  if (lane == 0) wsum[wid] = s;
  __syncthreads();
  if (tid == 0) partials[blockIdx.x] = wsum[0] + wsum[1] + wsum[2] + wsum[3];
}

__global__ __launch_bounds__(64) void scan_top(const int* __restrict__ partials,
                                               int* __restrict__ top_off,
                                               int* __restrict__ row_ptr, int nb, int n) {
  int l = threadIdx.x;
  int v = (l < nb) ? partials[l] : 0;
  int pre = v;
#pragma unroll
  for (int off = 1; off < 64; off <<= 1) {
    int t = __shfl_up(pre, off);
    if (l >= off) pre += t;
  }
  if (l < nb) top_off[l] = pre - v;
  if (l == 63) row_ptr[n] = pre;
}

__global__ __launch_bounds__(256) void scan_down(const int* __restrict__ deg,
                                                 const int* __restrict__ top_off,
                                                 int* __restrict__ row_ptr,
                                                 int* __restrict__ cursor, int n) {
  const int tid = threadIdx.x, lane = tid & 63, wid = tid >> 6;
  int i0 = blockIdx.x * 2048 + tid * 8;
  int d8[8];
  int s = 0;
#pragma unroll
  for (int j = 0; j < 8; j++) {
    int i = i0 + j;
    d8[j] = (i < n) ? deg[i] : 0;
    s += d8[j];
  }
  int pre = s;
#pragma unroll
  for (int off = 1; off < 64; off <<= 1) {
    int t = __shfl_up(pre, off);
    if (lane >= off) pre += t;
  }
  __shared__ int wtot[4];
  if (lane == 63) wtot[wid] = pre;
  __syncthreads();
  int woff = 0;
  for (int w = 0; w < wid; w++) woff += wtot[w];
  int run = top_off[blockIdx.x] + woff + (pre - s);
#pragma unroll
  for (int j = 0; j < 8; j++) {
    int i = i0 + j;
    if (i < n) { row_ptr[i] = run; cursor[i] = run; }
    run += d8[j];
  }
}

// scatter + layer-1 edge weights fused: record = {src, w0|w1, w2|w3, 0} (w bf16)
__global__ __launch_bounds__(256) void scatter_rec(const int* __restrict__ esrc,
                                                   const int* __restrict__ edst,
                                                   int* __restrict__ cursor,
                                                   const float4* __restrict__ as1,
                                                   const float4* __restrict__ ad1,
                                                   int4* __restrict__ recs,
                                                   int E, int Etot) {
  int e = blockIdx.x * blockDim.x + threadIdx.x;
  if (e >= Etot) return;
  int s = (e < E) ? esrc[e] : (e - E);
  int d = (e < E) ? edst[e] : (e - E);
  int pos = atomicAdd(&cursor[d], 1);
  float4 a = as1[s], b = ad1[d];
  float s0 = a.x + b.x, s1 = a.y + b.y, s2 = a.z + b.z, s3 = a.w + b.w;
  float w0 = exp2f(fmaxf(s0, NEG_SLOPE * s0));
  float w1 = exp2f(fmaxf(s1, NEG_SLOPE * s1));
  float w2 = exp2f(fmaxf(s2, NEG_SLOPE * s2));
  float w3 = exp2f(fmaxf(s3, NEG_SLOPE * s3));
  int4 r;
  r.x = s;
  r.y = (int)((unsigned)f2bf(w0) | ((unsigned)f2bf(w1) << 16));
  r.z = (int)((unsigned)f2bf(w2) | ((unsigned)f2bf(w3) << 16));
  r.w = 0;
  recs[pos] = r;
}

// ---------------- layer-1 aggregate: one wave per dst, record-driven ----------------
__global__ __launch_bounds__(256) void agg1_kernel(const unsigned short* __restrict__ Hb,
                                                   const int4* __restrict__ recs,
                                                   const int* __restrict__ row_ptr,
                                                   const float* __restrict__ b1,
                                                   unsigned short* __restrict__ outb, int n) {
  int d = blockIdx.x * 4 + (threadIdx.x >> 6);
  int l = threadIdx.x & 63;
  int hh = l >> 4;
  int e0 = __builtin_amdgcn_readfirstlane(row_ptr[d]);
  int e1 = __builtin_amdgcn_readfirstlane(row_ptr[d + 1]);
  const int shamt = (hh & 1) ? 0 : 16;
  const bool lowpair = hh < 2;
  float4 acc = {0.f, 0.f, 0.f, 0.f};
  float denom = 0.f;
  int e = e0;
#define WSEL(r) __uint_as_float(((unsigned)((lowpair) ? (r).y : (r).z) << shamt) & 0xffff0000u)
  for (; e + 3 < e1; e += 4) {
    int4 r0 = recs[e], r1 = recs[e + 1], r2 = recs[e + 2], r3 = recs[e + 3];
    float w0 = WSEL(r0), w1 = WSEL(r1), w2 = WSEL(r2), w3 = WSEL(r3);
    uint2 p0 = *(const uint2*)(Hb + (size_t)r0.x * C1 + l * 4);
    uint2 p1 = *(const uint2*)(Hb + (size_t)r1.x * C1 + l * 4);
    uint2 p2 = *(const uint2*)(Hb + (size_t)r2.x * C1 + l * 4);
    uint2 p3 = *(const uint2*)(Hb + (size_t)r3.x * C1 + l * 4);
    denom += (w0 + w1) + (w2 + w3);
    acc.x += w0 * bf_lo(p0.x); acc.y += w0 * bf_hi(p0.x); acc.z += w0 * bf_lo(p0.y); acc.w += w0 * bf_hi(p0.y);
    acc.x += w1 * bf_lo(p1.x); acc.y += w1 * bf_hi(p1.x); acc.z += w1 * bf_lo(p1.y); acc.w += w1 * bf_hi(p1.y);
    acc.x += w2 * bf_lo(p2.x); acc.y += w2 * bf_hi(p2.x); acc.z += w2 * bf_lo(p2.y); acc.w += w2 * bf_hi(p2.y);
    acc.x += w3 * bf_lo(p3.x); acc.y += w3 * bf_hi(p3.x); acc.z += w3 * bf_lo(p3.y); acc.w += w3 * bf_hi(p3.y);
  }
  for (; e < e1; e++) {
    int4 r0 = recs[e];
    float w = WSEL(r0);
    denom += w;
    uint2 p = *(const uint2*)(Hb + (size_t)r0.x * C1 + l * 4);
    acc.x += w * bf_lo(p.x); acc.y += w * bf_hi(p.x); acc.z += w * bf_lo(p.y); acc.w += w * bf_hi(p.y);
  }
#undef WSEL
  float inv = 1.f / (denom + 1e-16f);
  float4 bb = *(const float4*)(b1 + l * 4);
  float4 o;
  o.x = acc.x * inv + bb.x; o.y = acc.y * inv + bb.y;
  o.z = acc.z * inv + bb.z; o.w = acc.w * inv + bb.w;
  o.x = o.x > 0.f ? o.x : (__expf(o.x) - 1.f);
  o.y = o.y > 0.f ? o.y : (__expf(o.y) - 1.f);
  o.z = o.z > 0.f ? o.z : (__expf(o.z) - 1.f);
  o.w = o.w > 0.f ? o.w : (__expf(o.w) - 1.f);
  uint2 pk;
  pk.x = (unsigned int)f2bf(o.x) | ((unsigned int)f2bf(o.y) << 16);
  pk.y = (unsigned int)f2bf(o.z) | ((unsigned int)f2bf(o.w) << 16);
  *(uint2*)(outb + (size_t)d * C1 + l * 4) = pk;
}

// ---------------- layer-2 aggregate + fused mean pool ----------------
__global__ __launch_bounds__(256) void agg2_pool(const unsigned short* __restrict__ Hb,
                                                 const float* __restrict__ as_,
                                                 const float* __restrict__ ad_,
                                                 const int* __restrict__ row_ptr,
                                                 const int4* __restrict__ recs,
                                                 const float* __restrict__ b2,
                                                 float* __restrict__ poolrep, int n) {
  __shared__ float lds[4][64];
  int wid = threadIdx.x >> 6;
  int d = blockIdx.x * 4 + wid;
  int l = threadIdx.x & 63, q = l >> 4, li = l & 15;
  float ad = ad_[d];
  int e0 = row_ptr[d], e1 = row_ptr[d + 1];
  float4 acc = {0.f, 0.f, 0.f, 0.f};
  float denom = 0.f;
  for (int e = e0 + q; e < e1; e += 4) {
    int s = ((const int*)recs)[(size_t)e * 4];
    float sc = as_[s] + ad;
    float w = exp2f(fmaxf(sc, NEG_SLOPE * sc));
    denom += w;
    uint2 p = *(const uint2*)(Hb + (size_t)s * HID + li * 4);
    acc.x += w * bf_lo(p.x); acc.y += w * bf_hi(p.x);
    acc.z += w * bf_lo(p.y); acc.w += w * bf_hi(p.y);
  }
#pragma unroll
  for (int m = 16; m <= 32; m <<= 1) {
    acc.x += __shfl_xor(acc.x, m); acc.y += __shfl_xor(acc.y, m);
    acc.z += __shfl_xor(acc.z, m); acc.w += __shfl_xor(acc.w, m);
    denom += __shfl_xor(denom, m);
  }
  if (q == 0) {
    float inv = 1.f / (denom + 1e-16f);
    float o[4] = {acc.x * inv + b2[li * 4], acc.y * inv + b2[li * 4 + 1],
                  acc.z * inv + b2[li * 4 + 2], acc.w * inv + b2[li * 4 + 3]};
#pragma unroll
    for (int j = 0; j < 4; j++) {
      float v = o[j];
      lds[wid][li * 4 + j] = v > 0.f ? v : (__expf(v) - 1.f);
    }
  }
  __syncthreads();
  if (threadIdx.x < 64) {
    int c = threadIdx.x;
    float v = lds[0][c] + lds[1][c] + lds[2][c] + lds[3][c];
    atomicAdd(&poolrep[(blockIdx.x & 63) * 64 + c], v);
  }
}

__global__ __launch_bounds__(64) void head_kernel(const float* __restrict__ poolrep,
                                                  const float* __restrict__ Wc,
                                                  const float* __restrict__ bc,
                                                  float* __restrict__ out, float inv_n) {
  int l = threadIdx.x;
  float p = 0.f;
  for (int k = 0; k < 64; k++) p += poolrep[k * 64 + l];
  p *= inv_n;
  float o0 = wave_reduce_sum(p * Wc[l * 2 + 0]);
  float o1 = wave_reduce_sum(p * Wc[l * 2 + 1]);
  if (l == 0) { out[0] = o0 + bc[0]; out[1] = o1 + bc[1]; }
}

// ---------------- host ----------------
static inline size_t align256(size_t x) { return (x + 255) & ~(size_t)255; }

extern "C" void kernel_launch(void* const* d_in, const int* in_sizes, int n_in,
                              void* d_out, int out_size, void* d_ws, size_t ws_size,
                              hipStream_t stream) {
  const float* x        = (const float*)d_in[0];
  const int*   ei       = (const int*)d_in[1];
  const float* W1       = (const float*)d_in[2];
  const float* att_src1 = (const float*)d_in[3];
  const float* att_dst1 = (const float*)d_in[4];
  const float* b1       = (const float*)d_in[5];
  const float* W2       = (const float*)d_in[6];
  const float* att_src2 = (const float*)d_in[7];
  const float* att_dst2 = (const float*)d_in[8];
  const float* b2       = (const float*)d_in[9];
  const float* Wc       = (const float*)d_in[10];
  const float* bc       = (const float*)d_in[11];
  float* out = (float*)d_out;

  const int N = in_sizes[0] / F_IN;          // 50000
  const int E = in_sizes[1] / 2;             // 1,600,000
  const int Etot = E + N;                    // + self loops
  const int* ei_src = ei;
  const int* ei_dst = ei + E;

  // workspace layout (~86 MB)
  char* w = (char*)d_ws;
  size_t off = 0;
  unsigned short* h1b    = (unsigned short*)(w + off); off += align256((size_t)N * C1 * 2);
  unsigned short* h1actb = (unsigned short*)(w + off); off += align256((size_t)N * C1 * 2);
  unsigned short* h2b    = (unsigned short*)(w + off); off += align256((size_t)N * HID * 2);
  float* as1   = (float*)(w + off); off += align256((size_t)N * HEADS * 4);
  float* ad1   = (float*)(w + off); off += align256((size_t)N * HEADS * 4);
  float* as2   = (float*)(w + off); off += align256((size_t)N * 4);
  float* ad2   = (float*)(w + off); off += align256((size_t)N * 4);
  int* deg     = (int*)(w + off);   off += align256((size_t)N * 4);
  int* cursor  = (int*)(w + off);   off += align256((size_t)N * 4);
  int* row_ptr = (int*)(w + off);   off += align256((size_t)(N + 1) * 4);
  int* partials= (int*)(w + off);   off += align256(64 * 4);
  int* top_off = (int*)(w + off);   off += align256(64 * 4);
  float* poolrep = (float*)(w + off); off += align256(64 * 64 * 4);
  unsigned short* W1b = (unsigned short*)(w + off); off += align256(32768 * 2);
  unsigned short* W2b = (unsigned short*)(w + off); off += align256(16384 * 2);
  int4* recs   = (int4*)(w + off);  off += align256((size_t)Etot * 16);

  int eb = (Etot + 255) / 256;
  int nb4 = (N + 3) / 4;
  int rowblocks = (N + 63) / 64;
  int nbscan = (N + 2047) / 2048;            // 25

  init_kernel<<<(N + 255) / 256, 256, 0, stream>>>(deg, poolrep, N);
  hist_kernel<<<eb, 256, 0, stream>>>(ei_dst, deg, E, Etot);
  scan_part<<<nbscan, 256, 0, stream>>>(deg, partials, N);
  scan_top<<<1, 64, 0, stream>>>(partials, top_off, row_ptr, nbscan, N);
  scan_down<<<nbscan, 256, 0, stream>>>(deg, top_off, row_ptr, cursor, N);
  pack_w<<<64, 256, 0, stream>>>(W1, W2, W1b, W2b);

  // layer 1 GEMM (all heads per block), then edge-weight scatter, then aggregate
  gemm_mfma<4, false, HEADS><<<rowblocks, 256, 0, stream>>>(x, W1b, h1b, as1, ad1,
                                                            att_src1, att_dst1, N);
  scatter_rec<<<eb, 256, 0, stream>>>(ei_src, ei_dst, cursor,
                                      (const float4*)as1, (const float4*)ad1,
                                      recs, E, Etot);
  agg1_kernel<<<nb4, 256, 0, stream>>>(h1b, recs, row_ptr, b1, h1actb, N);

  // layer 2
  gemm_mfma<8, true, 1><<<rowblocks, 256, 0, stream>>>(h1actb, W2b, h2b, as2, ad2,
                                                       att_src2, att_dst2, N);
  agg2_pool<<<nb4, 256, 0, stream>>>(h2b, as2, ad2, row_ptr, recs, b2, poolrep, N);

  head_kernel<<<1, 64, 0, stream>>>(poolrep, Wc, bc, out, 1.0f / (float)N);
}

// Round 7
// 322.645 us; speedup vs baseline: 2.6014x; 1.1484x over previous
//
#include <hip/hip_runtime.h>
#include <cstdint>
#include <cstddef>

#define NEG_SLOPE 0.2f
#define F_IN 128
#define C1 256      // HEADS*HID layer-1 width
#define HID 64
#define HEADS 4
#define LOG2E 1.4426950408889634f

typedef __attribute__((ext_vector_type(8))) short bf16x8;
typedef __attribute__((ext_vector_type(4))) float f32x4;
typedef __attribute__((ext_vector_type(2))) float f32x2;

__device__ __forceinline__ float wave_reduce_sum(float v) {
#pragma unroll
  for (int off = 32; off > 0; off >>= 1) v += __shfl_down(v, off);
  return v;
}

__device__ __forceinline__ int wave_reduce_sum_i(int v) {
#pragma unroll
  for (int off = 32; off > 0; off >>= 1) v += __shfl_down(v, off);
  return v;
}

__device__ __forceinline__ unsigned short f2bf(float f) {
  union { float f; unsigned int u; } v; v.f = f;
  unsigned int u = v.u;
  unsigned int r = (u + 0x7fffu + ((u >> 16) & 1u)) >> 16;  // RNE
  return (unsigned short)r;
}
__device__ __forceinline__ float bf_lo(unsigned int u) { return __uint_as_float(u << 16); }
__device__ __forceinline__ float bf_hi(unsigned int u) { return __uint_as_float(u & 0xffff0000u); }

__device__ __forceinline__ unsigned char f2fp8(float f) {
  int p = __builtin_amdgcn_cvt_pk_fp8_f32(f, f, 0, false);  // OCP e4m3fn on gfx950
  return (unsigned char)(p & 0xff);
}

// ---------------- weight pre-pack into MFMA fragment order ----------------
__global__ __launch_bounds__(256) void pack_w(const float* __restrict__ W1,
                                              const float* __restrict__ W2,
                                              unsigned short* __restrict__ W1b,
                                              unsigned short* __restrict__ W2b) {
  for (int idx = threadIdx.x + blockIdx.x * 256; idx < 32768 + 16384;
       idx += 256 * gridDim.x) {
    if (idx < 32768) {
      int head = idx >> 13, ks = (idx >> 11) & 3, nt = (idx >> 9) & 3;
      int lane = (idx >> 3) & 63, j = idx & 7;
      int k = ks * 32 + (lane >> 4) * 8 + j;
      int c = head * 64 + nt * 16 + (lane & 15);
      W1b[idx] = f2bf(W1[k * 256 + c]);
    } else {
      int o = idx - 32768;
      int ks = o >> 11, nt = (o >> 9) & 3, lane = (o >> 3) & 63, j = o & 7;
      int k = ks * 32 + (lane >> 4) * 8 + j;
      int c = nt * 16 + (lane & 15);
      W2b[o] = f2bf(W2[k * 64 + c]);
    }
  }
}

// ---------------- MFMA GEMM, all heads per block ----------------
// STORE_FP8: Hb is fp8 e4m3 [M][N]; else bf16 [M][N].
template <int KSTEPS, bool A_BF16, int NH, bool STORE_FP8>
__global__ __launch_bounds__(256) void gemm_mfma(const void* __restrict__ Av,
                                                 const unsigned short* __restrict__ Wb,
                                                 void* __restrict__ Hbv,
                                                 float* __restrict__ as_out,
                                                 float* __restrict__ ad_out,
                                                 const float* __restrict__ att_s,
                                                 const float* __restrict__ att_d,
                                                 int M) {
  constexpr int K = KSTEPS * 32;
  constexpr int N = NH * 64;
  const int lane = threadIdx.x & 63, wid = threadIdx.x >> 6;
  const int rowbase = blockIdx.x * 64 + wid * 16;
  const int g = lane >> 4, li = lane & 15;
  int r_a = rowbase + li;
  if (r_a > M - 1) r_a = M - 1;

  f32x4 acc[NH][4];
#pragma unroll
  for (int h = 0; h < NH; h++)
#pragma unroll
    for (int nt = 0; nt < 4; nt++) {
      acc[h][nt][0] = 0.f; acc[h][nt][1] = 0.f; acc[h][nt][2] = 0.f; acc[h][nt][3] = 0.f;
    }

#pragma unroll
  for (int ks = 0; ks < KSTEPS; ks++) {
    bf16x8 a;
    if constexpr (A_BF16) {
      const unsigned short* Ab = (const unsigned short*)Av;
      a = *(const bf16x8*)(Ab + (size_t)r_a * K + ks * 32 + g * 8);
    } else {
      const float* Af = (const float*)Av;
      const float* p = Af + (size_t)r_a * K + ks * 32 + g * 8;
      float4 v0 = *(const float4*)p, v1 = *(const float4*)(p + 4);
      a[0] = (short)f2bf(v0.x); a[1] = (short)f2bf(v0.y);
      a[2] = (short)f2bf(v0.z); a[3] = (short)f2bf(v0.w);
      a[4] = (short)f2bf(v1.x); a[5] = (short)f2bf(v1.y);
      a[6] = (short)f2bf(v1.z); a[7] = (short)f2bf(v1.w);
    }
#pragma unroll
    for (int h = 0; h < NH; h++)
#pragma unroll
      for (int nt = 0; nt < 4; nt++) {
        bf16x8 b = *(const bf16x8*)(Wb + ((size_t)((h * KSTEPS + ks) * 4 + nt) * 64 + lane) * 8);
        acc[h][nt] = __builtin_amdgcn_mfma_f32_16x16x32_bf16(a, b, acc[h][nt], 0, 0, 0);
      }
  }

#pragma unroll
  for (int h = 0; h < NH; h++) {
    float asum[4] = {0.f, 0.f, 0.f, 0.f}, dsum[4] = {0.f, 0.f, 0.f, 0.f};
#pragma unroll
    for (int nt = 0; nt < 4; nt++) {
      float ws = att_s[h * 64 + nt * 16 + li];
      float wd = att_d[h * 64 + nt * 16 + li];
#pragma unroll
      for (int r = 0; r < 4; r++) { asum[r] += acc[h][nt][r] * ws; dsum[r] += acc[h][nt][r] * wd; }
    }
#pragma unroll
    for (int r = 0; r < 4; r++) {
#pragma unroll
      for (int m = 1; m < 16; m <<= 1) {
        asum[r] += __shfl_xor(asum[r], m);
        dsum[r] += __shfl_xor(dsum[r], m);
      }
    }
#pragma unroll
    for (int r = 0; r < 4; r++) {
      int gr = rowbase + g * 4 + r;
      if (gr < M) {
#pragma unroll
        for (int nt = 0; nt < 4; nt++) {
          if constexpr (STORE_FP8) {
            unsigned char* H8 = (unsigned char*)Hbv;
            H8[(size_t)gr * N + h * 64 + nt * 16 + li] = f2fp8(acc[h][nt][r]);
          } else {
            unsigned short* Hb = (unsigned short*)Hbv;
            Hb[(size_t)gr * N + h * 64 + nt * 16 + li] = f2bf(acc[h][nt][r]);
          }
        }
        if (li == 0) {
          as_out[(size_t)gr * NH + h] = asum[r] * LOG2E;
          ad_out[(size_t)gr * NH + h] = dsum[r] * LOG2E;
        }
      }
    }
  }
}

// ---------------- CSR build ----------------
__global__ __launch_bounds__(256) void init_kernel(int* __restrict__ deg,
                                                   float* __restrict__ poolrep, int n) {
  int i = blockIdx.x * blockDim.x + threadIdx.x;
  if (i < n) deg[i] = 0;
  if (i < 64 * 64) poolrep[i] = 0.f;
}

__global__ __launch_bounds__(256) void hist_kernel(const int* __restrict__ edge_dst,
                                                   int* __restrict__ deg, int E, int Etot) {
  int e = blockIdx.x * blockDim.x + threadIdx.x;
  if (e >= Etot) return;
  int d = (e < E) ? edge_dst[e] : (e - E);
  atomicAdd(&deg[d], 1);
}

// ---- hierarchical scan ----
__global__ __launch_bounds__(256) void scan_part(const int* __restrict__ deg,
                                                 int* __restrict__ partials, int n) {
  const int tid = threadIdx.x, lane = tid & 63, wid = tid >> 6;
  int i0 = blockIdx.x * 2048 + tid * 8;
  int s = 0;
#pragma unroll
  for (int j = 0; j < 8; j++) { int i = i0 + j; if (i < n) s += deg[i]; }
  s = wave_reduce_sum_i(s);
  __shared__ int wsum[4];
  if (lane == 0) wsum[wid] = s;
  __syncthreads();
  if (tid == 0) partials[blockIdx.x] = wsum[0] + wsum[1] + wsum[2] + wsum[3];
}

__global__ __launch_bounds__(64) void scan_top(const int* __restrict__ partials,
                                               int* __restrict__ top_off,
                                               int* __restrict__ row_ptr, int nb, int n) {
  int l = threadIdx.x;
  int v = (l < nb) ? partials[l] : 0;
  int pre = v;
#pragma unroll
  for (int off = 1; off < 64; off <<= 1) {
    int t = __shfl_up(pre, off);
    if (l >= off) pre += t;
  }
  if (l < nb) top_off[l] = pre - v;
  if (l == 63) row_ptr[n] = pre;
}

__global__ __launch_bounds__(256) void scan_down(const int* __restrict__ deg,
                                                 const int* __restrict__ top_off,
                                                 int* __restrict__ row_ptr,
                                                 int* __restrict__ cursor, int n) {
  const int tid = threadIdx.x, lane = tid & 63, wid = tid >> 6;
  int i0 = blockIdx.x * 2048 + tid * 8;
  int d8[8];
  int s = 0;
#pragma unroll
  for (int j = 0; j < 8; j++) {
    int i = i0 + j;
    d8[j] = (i < n) ? deg[i] : 0;
    s += d8[j];
  }
  int pre = s;
#pragma unroll
  for (int off = 1; off < 64; off <<= 1) {
    int t = __shfl_up(pre, off);
    if (lane >= off) pre += t;
  }
  __shared__ int wtot[4];
  if (lane == 63) wtot[wid] = pre;
  __syncthreads();
  int woff = 0;
  for (int w = 0; w < wid; w++) woff += wtot[w];
  int run = top_off[blockIdx.x] + woff + (pre - s);
#pragma unroll
  for (int j = 0; j < 8; j++) {
    int i = i0 + j;
    if (i < n) { row_ptr[i] = run; cursor[i] = run; }
    run += d8[j];
  }
}

// scatter: src32[pos] = src; w4[pos] = 4 bf16 layer-1 edge weights (exp2-domain)
__global__ __launch_bounds__(256) void scatter_rec(const int* __restrict__ esrc,
                                                   const int* __restrict__ edst,
                                                   int* __restrict__ cursor,
                                                   const float4* __restrict__ as1,
                                                   const float4* __restrict__ ad1,
                                                   int* __restrict__ src32,
                                                   uint2* __restrict__ w4,
                                                   int E, int Etot) {
  int e = blockIdx.x * blockDim.x + threadIdx.x;
  if (e >= Etot) return;
  int s = (e < E) ? esrc[e] : (e - E);
  int d = (e < E) ? edst[e] : (e - E);
  int pos = atomicAdd(&cursor[d], 1);
  float4 a = as1[s], b = ad1[d];
  float s0 = a.x + b.x, s1 = a.y + b.y, s2 = a.z + b.z, s3 = a.w + b.w;
  float w0 = exp2f(fmaxf(s0, NEG_SLOPE * s0));
  float w1 = exp2f(fmaxf(s1, NEG_SLOPE * s1));
  float w2 = exp2f(fmaxf(s2, NEG_SLOPE * s2));
  float w3 = exp2f(fmaxf(s3, NEG_SLOPE * s3));
  uint2 r;
  r.x = (unsigned)f2bf(w0) | ((unsigned)f2bf(w1) << 16);
  r.y = (unsigned)f2bf(w2) | ((unsigned)f2bf(w3) << 16);
  src32[pos] = s;
  w4[pos] = r;
}

// ---------------- layer-1 aggregate: one wave per dst, fp8 gather ----------------
// lane l covers channels 4l..4l+3 (head = l>>4); 4B fp8 payload per lane per edge.
__global__ __launch_bounds__(256) void agg1_kernel(const unsigned char* __restrict__ H8,
                                                   const int* __restrict__ src32,
                                                   const uint2* __restrict__ w4,
                                                   const int* __restrict__ row_ptr,
                                                   const float* __restrict__ b1,
                                                   unsigned short* __restrict__ outb, int n) {
  int d = blockIdx.x * 4 + (threadIdx.x >> 6);
  if (d >= n) return;
  int l = threadIdx.x & 63;
  int hh = l >> 4;
  int e0 = __builtin_amdgcn_readfirstlane(row_ptr[d]);
  int e1 = __builtin_amdgcn_readfirstlane(row_ptr[d + 1]);
  const int shamt = (hh & 1) ? 0 : 16;
  const bool lowpair = hh < 2;
  float4 acc = {0.f, 0.f, 0.f, 0.f};
  float denom = 0.f;
  int e = e0;
#define WSEL(r) __uint_as_float(((unsigned)((lowpair) ? (r).x : (r).y) << shamt) & 0xffff0000u)
#define ACCUM(wgt, u8)                                                     \
  {                                                                        \
    f32x2 lo_ = __builtin_amdgcn_cvt_pk_f32_fp8((int)(u8), false);         \
    f32x2 hi_ = __builtin_amdgcn_cvt_pk_f32_fp8((int)(u8), true);          \
    acc.x += (wgt)*lo_[0]; acc.y += (wgt)*lo_[1];                          \
    acc.z += (wgt)*hi_[0]; acc.w += (wgt)*hi_[1];                          \
    denom += (wgt);                                                        \
  }
  for (; e + 3 < e1; e += 4) {
    int s0 = src32[e], s1 = src32[e + 1], s2 = src32[e + 2], s3 = src32[e + 3];
    uint2 r0 = w4[e], r1 = w4[e + 1], r2 = w4[e + 2], r3 = w4[e + 3];
    unsigned u0 = *(const unsigned*)(H8 + (size_t)s0 * C1 + l * 4);
    unsigned u1 = *(const unsigned*)(H8 + (size_t)s1 * C1 + l * 4);
    unsigned u2 = *(const unsigned*)(H8 + (size_t)s2 * C1 + l * 4);
    unsigned u3 = *(const unsigned*)(H8 + (size_t)s3 * C1 + l * 4);
    float w0 = WSEL(r0), w1 = WSEL(r1), w2 = WSEL(r2), w3 = WSEL(r3);
    ACCUM(w0, u0) ACCUM(w1, u1) ACCUM(w2, u2) ACCUM(w3, u3)
  }
  for (; e < e1; e++) {
    int s = src32[e];
    uint2 r0 = w4[e];
    unsigned u = *(const unsigned*)(H8 + (size_t)s * C1 + l * 4);
    float wq = WSEL(r0);
    ACCUM(wq, u)
  }
#undef ACCUM
#undef WSEL
  float inv = 1.f / (denom + 1e-16f);
  float4 bb = *(const float4*)(b1 + l * 4);
  float4 o;
  o.x = acc.x * inv + bb.x; o.y = acc.y * inv + bb.y;
  o.z = acc.z * inv + bb.z; o.w = acc.w * inv + bb.w;
  o.x = o.x > 0.f ? o.x : (__expf(o.x) - 1.f);
  o.y = o.y > 0.f ? o.y : (__expf(o.y) - 1.f);
  o.z = o.z > 0.f ? o.z : (__expf(o.z) - 1.f);
  o.w = o.w > 0.f ? o.w : (__expf(o.w) - 1.f);
  uint2 pk;
  pk.x = (unsigned int)f2bf(o.x) | ((unsigned int)f2bf(o.y) << 16);
  pk.y = (unsigned int)f2bf(o.z) | ((unsigned int)f2bf(o.w) << 16);
  *(uint2*)(outb + (size_t)d * C1 + l * 4) = pk;
}

// ---------------- layer-2 aggregate + fused mean pool ----------------
__global__ __launch_bounds__(256) void agg2_pool(const unsigned short* __restrict__ Hb,
                                                 const float* __restrict__ as_,
                                                 const float* __restrict__ ad_,
                                                 const int* __restrict__ row_ptr,
                                                 const int* __restrict__ src32,
                                                 const float* __restrict__ b2,
                                                 float* __restrict__ poolrep, int n) {
  __shared__ float lds[4][64];
  int wid = threadIdx.x >> 6;
  int d = blockIdx.x * 4 + wid;
  int l = threadIdx.x & 63, q = l >> 4, li = l & 15;
  float ad = ad_[d];
  int e0 = row_ptr[d], e1 = row_ptr[d + 1];
  float4 acc = {0.f, 0.f, 0.f, 0.f};
  float denom = 0.f;
  for (int e = e0 + q; e < e1; e += 4) {
    int s = src32[e];
    float sc = as_[s] + ad;
    float w = exp2f(fmaxf(sc, NEG_SLOPE * sc));
    denom += w;
    uint2 p = *(const uint2*)(Hb + (size_t)s * HID + li * 4);
    acc.x += w * bf_lo(p.x); acc.y += w * bf_hi(p.x);
    acc.z += w * bf_lo(p.y); acc.w += w * bf_hi(p.y);
  }
#pragma unroll
  for (int m = 16; m <= 32; m <<= 1) {
    acc.x += __shfl_xor(acc.x, m); acc.y += __shfl_xor(acc.y, m);
    acc.z += __shfl_xor(acc.z, m); acc.w += __shfl_xor(acc.w, m);
    denom += __shfl_xor(denom, m);
  }
  if (q == 0) {
    float inv = 1.f / (denom + 1e-16f);
    float o[4] = {acc.x * inv + b2[li * 4], acc.y * inv + b2[li * 4 + 1],
                  acc.z * inv + b2[li * 4 + 2], acc.w * inv + b2[li * 4 + 3]};
#pragma unroll
    for (int j = 0; j < 4; j++) {
      float v = o[j];
      lds[wid][li * 4 + j] = v > 0.f ? v : (__expf(v) - 1.f);
    }
  }
  __syncthreads();
  if (threadIdx.x < 64) {
    int c = threadIdx.x;
    float v = lds[0][c] + lds[1][c] + lds[2][c] + lds[3][c];
    atomicAdd(&poolrep[(blockIdx.x & 63) * 64 + c], v);
  }
}

__global__ __launch_bounds__(64) void head_kernel(const float* __restrict__ poolrep,
                                                  const float* __restrict__ Wc,
                                                  const float* __restrict__ bc,
                                                  float* __restrict__ out, float inv_n) {
  int l = threadIdx.x;
  float p = 0.f;
  for (int k = 0; k < 64; k++) p += poolrep[k * 64 + l];
  p *= inv_n;
  float o0 = wave_reduce_sum(p * Wc[l * 2 + 0]);
  float o1 = wave_reduce_sum(p * Wc[l * 2 + 1]);
  if (l == 0) { out[0] = o0 + bc[0]; out[1] = o1 + bc[1]; }
}

// ---------------- host ----------------
static inline size_t align256(size_t x) { return (x + 255) & ~(size_t)255; }

extern "C" void kernel_launch(void* const* d_in, const int* in_sizes, int n_in,
                              void* d_out, int out_size, void* d_ws, size_t ws_size,
                              hipStream_t stream) {
  const float* x        = (const float*)d_in[0];
  const int*   ei       = (const int*)d_in[1];
  const float* W1       = (const float*)d_in[2];
  const float* att_src1 = (const float*)d_in[3];
  const float* att_dst1 = (const float*)d_in[4];
  const float* b1       = (const float*)d_in[5];
  const float* W2       = (const float*)d_in[6];
  const float* att_src2 = (const float*)d_in[7];
  const float* att_dst2 = (const float*)d_in[8];
  const float* b2       = (const float*)d_in[9];
  const float* Wc       = (const float*)d_in[10];
  const float* bc       = (const float*)d_in[11];
  float* out = (float*)d_out;

  const int N = in_sizes[0] / F_IN;          // 50000
  const int E = in_sizes[1] / 2;             // 1,600,000
  const int Etot = E + N;                    // + self loops
  const int* ei_src = ei;
  const int* ei_dst = ei + E;

  // workspace layout (~68 MB)
  char* w = (char*)d_ws;
  size_t off = 0;
  unsigned char*  h1b8   = (unsigned char*)(w + off);  off += align256((size_t)N * C1);      // 12.8MB fp8
  unsigned short* h1actb = (unsigned short*)(w + off); off += align256((size_t)N * C1 * 2);  // 25.6MB bf16
  unsigned short* h2b    = (unsigned short*)(w + off); off += align256((size_t)N * HID * 2); // 6.4MB bf16
  float* as1   = (float*)(w + off); off += align256((size_t)N * HEADS * 4);
  float* ad1   = (float*)(w + off); off += align256((size_t)N * HEADS * 4);
  float* as2   = (float*)(w + off); off += align256((size_t)N * 4);
  float* ad2   = (float*)(w + off); off += align256((size_t)N * 4);
  int* deg     = (int*)(w + off);   off += align256((size_t)N * 4);
  int* cursor  = (int*)(w + off);   off += align256((size_t)N * 4);
  int* row_ptr = (int*)(w + off);   off += align256((size_t)(N + 1) * 4);
  int* partials= (int*)(w + off);   off += align256(64 * 4);
  int* top_off = (int*)(w + off);   off += align256(64 * 4);
  float* poolrep = (float*)(w + off); off += align256(64 * 64 * 4);
  unsigned short* W1b = (unsigned short*)(w + off); off += align256(32768 * 2);
  unsigned short* W2b = (unsigned short*)(w + off); off += align256(16384 * 2);
  int*   src32 = (int*)(w + off);   off += align256((size_t)Etot * 4);
  uint2* w4    = (uint2*)(w + off); off += align256((size_t)Etot * 8);

  int eb = (Etot + 255) / 256;
  int nb4 = (N + 3) / 4;
  int rowblocks = (N + 63) / 64;
  int nbscan = (N + 2047) / 2048;            // 25

  init_kernel<<<(N + 255) / 256, 256, 0, stream>>>(deg, poolrep, N);
  hist_kernel<<<eb, 256, 0, stream>>>(ei_dst, deg, E, Etot);
  scan_part<<<nbscan, 256, 0, stream>>>(deg, partials, N);
  scan_top<<<1, 64, 0, stream>>>(partials, top_off, row_ptr, nbscan, N);
  scan_down<<<nbscan, 256, 0, stream>>>(deg, top_off, row_ptr, cursor, N);
  pack_w<<<64, 256, 0, stream>>>(W1, W2, W1b, W2b);

  // layer 1: GEMM (fp8 h-store) -> edge-weight scatter -> aggregate
  gemm_mfma<4, false, HEADS, true><<<rowblocks, 256, 0, stream>>>(
      x, W1b, h1b8, as1, ad1, att_src1, att_dst1, N);
  scatter_rec<<<eb, 256, 0, stream>>>(ei_src, ei_dst, cursor,
                                      (const float4*)as1, (const float4*)ad1,
                                      src32, w4, E, Etot);
  agg1_kernel<<<nb4, 256, 0, stream>>>(h1b8, src32, w4, row_ptr, b1, h1actb, N);

  // layer 2 (bf16 h-store)
  gemm_mfma<8, true, 1, false><<<rowblocks, 256, 0, stream>>>(
      h1actb, W2b, h2b, as2, ad2, att_src2, att_dst2, N);
  agg2_pool<<<nb4, 256, 0, stream>>>(h2b, as2, ad2, row_ptr, src32, b2, poolrep, N);

  head_kernel<<<1, 64, 0, stream>>>(poolrep, Wc, bc, out, 1.0f / (float)N);
}

// Round 8
// 279.950 us; speedup vs baseline: 2.9982x; 1.1525x over previous
//
#include <hip/hip_runtime.h>
#include <cstdint>
#include <cstddef>

#define NEG_SLOPE 0.2f
#define F_IN 128
#define C1 256      // HEADS*HID layer-1 width
#define HID 64
#define HEADS 4
#define LOG2E 1.4426950408889634f

typedef __attribute__((ext_vector_type(8))) short bf16x8;
typedef __attribute__((ext_vector_type(4))) float f32x4;
typedef __attribute__((ext_vector_type(2))) float f32x2;

__device__ __forceinline__ float wave_reduce_sum(float v) {
#pragma unroll
  for (int off = 32; off > 0; off >>= 1) v += __shfl_down(v, off);
  return v;
}

__device__ __forceinline__ int wave_reduce_sum_i(int v) {
#pragma unroll
  for (int off = 32; off > 0; off >>= 1) v += __shfl_down(v, off);
  return v;
}

__device__ __forceinline__ unsigned short f2bf(float f) {
  union { float f; unsigned int u; } v; v.f = f;
  unsigned int u = v.u;
  unsigned int r = (u + 0x7fffu + ((u >> 16) & 1u)) >> 16;  // RNE
  return (unsigned short)r;
}
__device__ __forceinline__ float bf_lo(unsigned int u) { return __uint_as_float(u << 16); }
__device__ __forceinline__ float bf_hi(unsigned int u) { return __uint_as_float(u & 0xffff0000u); }

__device__ __forceinline__ unsigned char f2fp8(float f) {
  int p = __builtin_amdgcn_cvt_pk_fp8_f32(f, f, 0, false);  // OCP e4m3fn on gfx950
  return (unsigned char)(p & 0xff);
}

// ---------------- weight pre-pack into MFMA fragment order ----------------
__global__ __launch_bounds__(256) void pack_w(const float* __restrict__ W1,
                                              const float* __restrict__ W2,
                                              unsigned short* __restrict__ W1b,
                                              unsigned short* __restrict__ W2b) {
  for (int idx = threadIdx.x + blockIdx.x * 256; idx < 32768 + 16384;
       idx += 256 * gridDim.x) {
    if (idx < 32768) {
      int head = idx >> 13, ks = (idx >> 11) & 3, nt = (idx >> 9) & 3;
      int lane = (idx >> 3) & 63, j = idx & 7;
      int k = ks * 32 + (lane >> 4) * 8 + j;
      int c = head * 64 + nt * 16 + (lane & 15);
      W1b[idx] = f2bf(W1[k * 256 + c]);
    } else {
      int o = idx - 32768;
      int ks = o >> 11, nt = (o >> 9) & 3, lane = (o >> 3) & 63, j = o & 7;
      int k = ks * 32 + (lane >> 4) * 8 + j;
      int c = nt * 16 + (lane & 15);
      W2b[o] = f2bf(W2[k * 64 + c]);
    }
  }
}

// ---------------- MFMA GEMM, all heads per block ----------------
template <int KSTEPS, bool A_BF16, int NH, bool STORE_FP8>
__global__ __launch_bounds__(256) void gemm_mfma(const void* __restrict__ Av,
                                                 const unsigned short* __restrict__ Wb,
                                                 void* __restrict__ Hbv,
                                                 float* __restrict__ as_out,
                                                 float* __restrict__ ad_out,
                                                 const float* __restrict__ att_s,
                                                 const float* __restrict__ att_d,
                                                 int M) {
  constexpr int K = KSTEPS * 32;
  constexpr int N = NH * 64;
  const int lane = threadIdx.x & 63, wid = threadIdx.x >> 6;
  const int rowbase = blockIdx.x * 64 + wid * 16;
  const int g = lane >> 4, li = lane & 15;
  int r_a = rowbase + li;
  if (r_a > M - 1) r_a = M - 1;

  f32x4 acc[NH][4];
#pragma unroll
  for (int h = 0; h < NH; h++)
#pragma unroll
    for (int nt = 0; nt < 4; nt++) {
      acc[h][nt][0] = 0.f; acc[h][nt][1] = 0.f; acc[h][nt][2] = 0.f; acc[h][nt][3] = 0.f;
    }

#pragma unroll
  for (int ks = 0; ks < KSTEPS; ks++) {
    bf16x8 a;
    if constexpr (A_BF16) {
      const unsigned short* Ab = (const unsigned short*)Av;
      a = *(const bf16x8*)(Ab + (size_t)r_a * K + ks * 32 + g * 8);
    } else {
      const float* Af = (const float*)Av;
      const float* p = Af + (size_t)r_a * K + ks * 32 + g * 8;
      float4 v0 = *(const float4*)p, v1 = *(const float4*)(p + 4);
      a[0] = (short)f2bf(v0.x); a[1] = (short)f2bf(v0.y);
      a[2] = (short)f2bf(v0.z); a[3] = (short)f2bf(v0.w);
      a[4] = (short)f2bf(v1.x); a[5] = (short)f2bf(v1.y);
      a[6] = (short)f2bf(v1.z); a[7] = (short)f2bf(v1.w);
    }
#pragma unroll
    for (int h = 0; h < NH; h++)
#pragma unroll
      for (int nt = 0; nt < 4; nt++) {
        bf16x8 b = *(const bf16x8*)(Wb + ((size_t)((h * KSTEPS + ks) * 4 + nt) * 64 + lane) * 8);
        acc[h][nt] = __builtin_amdgcn_mfma_f32_16x16x32_bf16(a, b, acc[h][nt], 0, 0, 0);
      }
  }

#pragma unroll
  for (int h = 0; h < NH; h++) {
    float asum[4] = {0.f, 0.f, 0.f, 0.f}, dsum[4] = {0.f, 0.f, 0.f, 0.f};
#pragma unroll
    for (int nt = 0; nt < 4; nt++) {
      float ws = att_s[h * 64 + nt * 16 + li];
      float wd = att_d[h * 64 + nt * 16 + li];
#pragma unroll
      for (int r = 0; r < 4; r++) { asum[r] += acc[h][nt][r] * ws; dsum[r] += acc[h][nt][r] * wd; }
    }
#pragma unroll
    for (int r = 0; r < 4; r++) {
#pragma unroll
      for (int m = 1; m < 16; m <<= 1) {
        asum[r] += __shfl_xor(asum[r], m);
        dsum[r] += __shfl_xor(dsum[r], m);
      }
    }
#pragma unroll
    for (int r = 0; r < 4; r++) {
      int gr = rowbase + g * 4 + r;
      if (gr < M) {
#pragma unroll
        for (int nt = 0; nt < 4; nt++) {
          if constexpr (STORE_FP8) {
            unsigned char* H8 = (unsigned char*)Hbv;
            H8[(size_t)gr * N + h * 64 + nt * 16 + li] = f2fp8(acc[h][nt][r]);
          } else {
            unsigned short* Hb = (unsigned short*)Hbv;
            Hb[(size_t)gr * N + h * 64 + nt * 16 + li] = f2bf(acc[h][nt][r]);
          }
        }
        if (li == 0) {
          as_out[(size_t)gr * NH + h] = asum[r] * LOG2E;
          ad_out[(size_t)gr * NH + h] = dsum[r] * LOG2E;
        }
      }
    }
  }
}

// ---------------- CSR build ----------------
__global__ __launch_bounds__(256) void init_kernel(int* __restrict__ deg,
                                                   float* __restrict__ poolrep, int n) {
  int i = blockIdx.x * blockDim.x + threadIdx.x;
  if (i < n) deg[i] = 0;
  if (i < 64 * 64) poolrep[i] = 0.f;
}

// hist: count degree AND hand each edge its slot index (coalesced write).
__global__ __launch_bounds__(256) void hist_kernel(const int* __restrict__ edge_dst,
                                                   int* __restrict__ deg,
                                                   int* __restrict__ pos_within,
                                                   int E, int Etot) {
  int e = blockIdx.x * blockDim.x + threadIdx.x;
  if (e >= Etot) return;
  int d = (e < E) ? edge_dst[e] : (e - E);
  pos_within[e] = atomicAdd(&deg[d], 1);
}

// ---- hierarchical scan ----
__global__ __launch_bounds__(256) void scan_part(const int* __restrict__ deg,
                                                 int* __restrict__ partials, int n) {
  const int tid = threadIdx.x, lane = tid & 63, wid = tid >> 6;
  int i0 = blockIdx.x * 2048 + tid * 8;
  int s = 0;
#pragma unroll
  for (int j = 0; j < 8; j++) { int i = i0 + j; if (i < n) s += deg[i]; }
  s = wave_reduce_sum_i(s);
  __shared__ int wsum[4];
  if (lane == 0) wsum[wid] = s;
  __syncthreads();
  if (tid == 0) partials[blockIdx.x] = wsum[0] + wsum[1] + wsum[2] + wsum[3];
}

__global__ __launch_bounds__(64) void scan_top(const int* __restrict__ partials,
                                               int* __restrict__ top_off,
                                               int* __restrict__ row_ptr, int nb, int n) {
  int l = threadIdx.x;
  int v = (l < nb) ? partials[l] : 0;
  int pre = v;
#pragma unroll
  for (int off = 1; off < 64; off <<= 1) {
    int t = __shfl_up(pre, off);
    if (l >= off) pre += t;
  }
  if (l < nb) top_off[l] = pre - v;
  if (l == 63) row_ptr[n] = pre;
}

__global__ __launch_bounds__(256) void scan_down(const int* __restrict__ deg,
                                                 const int* __restrict__ top_off,
                                                 int* __restrict__ row_ptr, int n) {
  const int tid = threadIdx.x, lane = tid & 63, wid = tid >> 6;
  int i0 = blockIdx.x * 2048 + tid * 8;
  int d8[8];
  int s = 0;
#pragma unroll
  for (int j = 0; j < 8; j++) {
    int i = i0 + j;
    d8[j] = (i < n) ? deg[i] : 0;
    s += d8[j];
  }
  int pre = s;
#pragma unroll
  for (int off = 1; off < 64; off <<= 1) {
    int t = __shfl_up(pre, off);
    if (lane >= off) pre += t;
  }
  __shared__ int wtot[4];
  if (lane == 63) wtot[wid] = pre;
  __syncthreads();
  int woff = 0;
  for (int w = 0; w < wid; w++) woff += wtot[w];
  int run = top_off[blockIdx.x] + woff + (pre - s);
#pragma unroll
  for (int j = 0; j < 8; j++) {
    int i = i0 + j;
    if (i < n) row_ptr[i] = run;
    run += d8[j];
  }
}

// scatter: atomic-free; one 16B record per edge {src, w0|w1, w2|w3, 0}
__global__ __launch_bounds__(256) void scatter_rec(const int* __restrict__ esrc,
                                                   const int* __restrict__ edst,
                                                   const int* __restrict__ pos_within,
                                                   const int* __restrict__ row_ptr,
                                                   const float4* __restrict__ as1,
                                                   const float4* __restrict__ ad1,
                                                   int4* __restrict__ recs,
                                                   int E, int Etot) {
  int e = blockIdx.x * blockDim.x + threadIdx.x;
  if (e >= Etot) return;
  int s = (e < E) ? esrc[e] : (e - E);
  int d = (e < E) ? edst[e] : (e - E);
  int pos = row_ptr[d] + pos_within[e];
  float4 a = as1[s], b = ad1[d];
  float s0 = a.x + b.x, s1 = a.y + b.y, s2 = a.z + b.z, s3 = a.w + b.w;
  float w0 = exp2f(fmaxf(s0, NEG_SLOPE * s0));
  float w1 = exp2f(fmaxf(s1, NEG_SLOPE * s1));
  float w2 = exp2f(fmaxf(s2, NEG_SLOPE * s2));
  float w3 = exp2f(fmaxf(s3, NEG_SLOPE * s3));
  int4 r;
  r.x = s;
  r.y = (int)((unsigned)f2bf(w0) | ((unsigned)f2bf(w1) << 16));
  r.z = (int)((unsigned)f2bf(w2) | ((unsigned)f2bf(w3) << 16));
  r.w = 0;
  recs[pos] = r;
}

// ---------------- layer-1 aggregate: one wave per dst, fp8 gather ----------------
__global__ __launch_bounds__(256) void agg1_kernel(const unsigned char* __restrict__ H8,
                                                   const int4* __restrict__ recs,
                                                   const int* __restrict__ row_ptr,
                                                   const float* __restrict__ b1,
                                                   unsigned short* __restrict__ outb, int n) {
  int d = blockIdx.x * 4 + (threadIdx.x >> 6);
  if (d >= n) return;
  int l = threadIdx.x & 63;
  int hh = l >> 4;
  int e0 = __builtin_amdgcn_readfirstlane(row_ptr[d]);
  int e1 = __builtin_amdgcn_readfirstlane(row_ptr[d + 1]);
  const int shamt = (hh & 1) ? 0 : 16;
  const bool lowpair = hh < 2;
  float4 acc = {0.f, 0.f, 0.f, 0.f};
  float denom = 0.f;
  int e = e0;
#define WSEL(r) __uint_as_float(((unsigned)((lowpair) ? (r).y : (r).z) << shamt) & 0xffff0000u)
#define ACCUM(wgt, u8)                                                     \
  {                                                                        \
    f32x2 lo_ = __builtin_amdgcn_cvt_pk_f32_fp8((int)(u8), false);         \
    f32x2 hi_ = __builtin_amdgcn_cvt_pk_f32_fp8((int)(u8), true);          \
    acc.x += (wgt)*lo_[0]; acc.y += (wgt)*lo_[1];                          \
    acc.z += (wgt)*hi_[0]; acc.w += (wgt)*hi_[1];                          \
    denom += (wgt);                                                        \
  }
  for (; e + 3 < e1; e += 4) {
    int4 r0 = recs[e], r1 = recs[e + 1], r2 = recs[e + 2], r3 = recs[e + 3];
    unsigned u0 = *(const unsigned*)(H8 + (size_t)r0.x * C1 + l * 4);
    unsigned u1 = *(const unsigned*)(H8 + (size_t)r1.x * C1 + l * 4);
    unsigned u2 = *(const unsigned*)(H8 + (size_t)r2.x * C1 + l * 4);
    unsigned u3 = *(const unsigned*)(H8 + (size_t)r3.x * C1 + l * 4);
    float w0 = WSEL(r0), w1 = WSEL(r1), w2 = WSEL(r2), w3 = WSEL(r3);
    ACCUM(w0, u0) ACCUM(w1, u1) ACCUM(w2, u2) ACCUM(w3, u3)
  }
  for (; e < e1; e++) {
    int4 r0 = recs[e];
    unsigned u = *(const unsigned*)(H8 + (size_t)r0.x * C1 + l * 4);
    float wq = WSEL(r0);
    ACCUM(wq, u)
  }
#undef ACCUM
#undef WSEL
  float inv = 1.f / (denom + 1e-16f);
  float4 bb = *(const float4*)(b1 + l * 4);
  float4 o;
  o.x = acc.x * inv + bb.x; o.y = acc.y * inv + bb.y;
  o.z = acc.z * inv + bb.z; o.w = acc.w * inv + bb.w;
  o.x = o.x > 0.f ? o.x : (__expf(o.x) - 1.f);
  o.y = o.y > 0.f ? o.y : (__expf(o.y) - 1.f);
  o.z = o.z > 0.f ? o.z : (__expf(o.z) - 1.f);
  o.w = o.w > 0.f ? o.w : (__expf(o.w) - 1.f);
  uint2 pk;
  pk.x = (unsigned int)f2bf(o.x) | ((unsigned int)f2bf(o.y) << 16);
  pk.y = (unsigned int)f2bf(o.z) | ((unsigned int)f2bf(o.w) << 16);
  *(uint2*)(outb + (size_t)d * C1 + l * 4) = pk;
}

// ---------------- layer-2 aggregate + fused mean pool ----------------
__global__ __launch_bounds__(256) void agg2_pool(const unsigned short* __restrict__ Hb,
                                                 const float* __restrict__ as_,
                                                 const float* __restrict__ ad_,
                                                 const int* __restrict__ row_ptr,
                                                 const int4* __restrict__ recs,
                                                 const float* __restrict__ b2,
                                                 float* __restrict__ poolrep, int n) {
  __shared__ float lds[4][64];
  int wid = threadIdx.x >> 6;
  int d = blockIdx.x * 4 + wid;
  int l = threadIdx.x & 63, q = l >> 4, li = l & 15;
  float ad = ad_[d];
  int e0 = row_ptr[d], e1 = row_ptr[d + 1];
  float4 acc = {0.f, 0.f, 0.f, 0.f};
  float denom = 0.f;
  for (int e = e0 + q; e < e1; e += 4) {
    int s = ((const int*)recs)[(size_t)e * 4];
    float sc = as_[s] + ad;
    float w = exp2f(fmaxf(sc, NEG_SLOPE * sc));
    denom += w;
    uint2 p = *(const uint2*)(Hb + (size_t)s * HID + li * 4);
    acc.x += w * bf_lo(p.x); acc.y += w * bf_hi(p.x);
    acc.z += w * bf_lo(p.y); acc.w += w * bf_hi(p.y);
  }
#pragma unroll
  for (int m = 16; m <= 32; m <<= 1) {
    acc.x += __shfl_xor(acc.x, m); acc.y += __shfl_xor(acc.y, m);
    acc.z += __shfl_xor(acc.z, m); acc.w += __shfl_xor(acc.w, m);
    denom += __shfl_xor(denom, m);
  }
  if (q == 0) {
    float inv = 1.f / (denom + 1e-16f);
    float o[4] = {acc.x * inv + b2[li * 4], acc.y * inv + b2[li * 4 + 1],
                  acc.z * inv + b2[li * 4 + 2], acc.w * inv + b2[li * 4 + 3]};
#pragma unroll
    for (int j = 0; j < 4; j++) {
      float v = o[j];
      lds[wid][li * 4 + j] = v > 0.f ? v : (__expf(v) - 1.f);
    }
  }
  __syncthreads();
  if (threadIdx.x < 64) {
    int c = threadIdx.x;
    float v = lds[0][c] + lds[1][c] + lds[2][c] + lds[3][c];
    atomicAdd(&poolrep[(blockIdx.x & 63) * 64 + c], v);
  }
}

__global__ __launch_bounds__(64) void head_kernel(const float* __restrict__ poolrep,
                                                  const float* __restrict__ Wc,
                                                  const float* __restrict__ bc,
                                                  float* __restrict__ out, float inv_n) {
  int l = threadIdx.x;
  float p = 0.f;
  for (int k = 0; k < 64; k++) p += poolrep[k * 64 + l];
  p *= inv_n;
  float o0 = wave_reduce_sum(p * Wc[l * 2 + 0]);
  float o1 = wave_reduce_sum(p * Wc[l * 2 + 1]);
  if (l == 0) { out[0] = o0 + bc[0]; out[1] = o1 + bc[1]; }
}

// ---------------- host ----------------
static inline size_t align256(size_t x) { return (x + 255) & ~(size_t)255; }

extern "C" void kernel_launch(void* const* d_in, const int* in_sizes, int n_in,
                              void* d_out, int out_size, void* d_ws, size_t ws_size,
                              hipStream_t stream) {
  const float* x        = (const float*)d_in[0];
  const int*   ei       = (const int*)d_in[1];
  const float* W1       = (const float*)d_in[2];
  const float* att_src1 = (const float*)d_in[3];
  const float* att_dst1 = (const float*)d_in[4];
  const float* b1       = (const float*)d_in[5];
  const float* W2       = (const float*)d_in[6];
  const float* att_src2 = (const float*)d_in[7];
  const float* att_dst2 = (const float*)d_in[8];
  const float* b2       = (const float*)d_in[9];
  const float* Wc       = (const float*)d_in[10];
  const float* bc       = (const float*)d_in[11];
  float* out = (float*)d_out;

  const int N = in_sizes[0] / F_IN;          // 50000
  const int E = in_sizes[1] / 2;             // 1,600,000
  const int Etot = E + N;                    // + self loops
  const int* ei_src = ei;
  const int* ei_dst = ei + E;

  // workspace layout (~85 MB)
  char* w = (char*)d_ws;
  size_t off = 0;
  unsigned char*  h1b8   = (unsigned char*)(w + off);  off += align256((size_t)N * C1);      // 12.8MB fp8
  unsigned short* h1actb = (unsigned short*)(w + off); off += align256((size_t)N * C1 * 2);  // 25.6MB bf16
  unsigned short* h2b    = (unsigned short*)(w + off); off += align256((size_t)N * HID * 2); // 6.4MB bf16
  float* as1   = (float*)(w + off); off += align256((size_t)N * HEADS * 4);
  float* ad1   = (float*)(w + off); off += align256((size_t)N * HEADS * 4);
  float* as2   = (float*)(w + off); off += align256((size_t)N * 4);
  float* ad2   = (float*)(w + off); off += align256((size_t)N * 4);
  int* deg     = (int*)(w + off);   off += align256((size_t)N * 4);
  int* row_ptr = (int*)(w + off);   off += align256((size_t)(N + 1) * 4);
  int* partials= (int*)(w + off);   off += align256(64 * 4);
  int* top_off = (int*)(w + off);   off += align256(64 * 4);
  float* poolrep = (float*)(w + off); off += align256(64 * 64 * 4);
  unsigned short* W1b = (unsigned short*)(w + off); off += align256(32768 * 2);
  unsigned short* W2b = (unsigned short*)(w + off); off += align256(16384 * 2);
  int* pos_within = (int*)(w + off); off += align256((size_t)Etot * 4);
  int4* recs   = (int4*)(w + off);  off += align256((size_t)Etot * 16);

  int eb = (Etot + 255) / 256;
  int nb4 = (N + 3) / 4;
  int rowblocks = (N + 63) / 64;
  int nbscan = (N + 2047) / 2048;            // 25

  init_kernel<<<(N + 255) / 256, 256, 0, stream>>>(deg, poolrep, N);
  hist_kernel<<<eb, 256, 0, stream>>>(ei_dst, deg, pos_within, E, Etot);
  scan_part<<<nbscan, 256, 0, stream>>>(deg, partials, N);
  scan_top<<<1, 64, 0, stream>>>(partials, top_off, row_ptr, nbscan, N);
  scan_down<<<nbscan, 256, 0, stream>>>(deg, top_off, row_ptr, N);
  pack_w<<<64, 256, 0, stream>>>(W1, W2, W1b, W2b);

  // layer 1: GEMM (fp8 h-store) -> atomic-free record scatter -> aggregate
  gemm_mfma<4, false, HEADS, true><<<rowblocks, 256, 0, stream>>>(
      x, W1b, h1b8, as1, ad1, att_src1, att_dst1, N);
  scatter_rec<<<eb, 256, 0, stream>>>(ei_src, ei_dst, pos_within, row_ptr,
                                      (const float4*)as1, (const float4*)ad1,
                                      recs, E, Etot);
  agg1_kernel<<<nb4, 256, 0, stream>>>(h1b8, recs, row_ptr, b1, h1actb, N);

  // layer 2 (bf16 h-store)
  gemm_mfma<8, true, 1, false><<<rowblocks, 256, 0, stream>>>(
      h1actb, W2b, h2b, as2, ad2, att_src2, att_dst2, N);
  agg2_pool<<<nb4, 256, 0, stream>>>(h2b, as2, ad2, row_ptr, recs, b2, poolrep, N);

  head_kernel<<<1, 64, 0, stream>>>(poolrep, Wc, bc, out, 1.0f / (float)N);
}

// Round 9
// 226.690 us; speedup vs baseline: 3.7026x; 1.2349x over previous
//
#include <hip/hip_runtime.h>
#include <cstdint>
#include <cstddef>

#define NEG_SLOPE 0.2f
#define F_IN 128
#define C1 256      // HEADS*HID layer-1 width
#define HID 64
#define HEADS 4
#define LOG2E 1.4426950408889634f
#define NBUCK 196   // ceil(50000/256)
#define BCAP 10240  // per-bucket region capacity (mean 8448, sigma ~92)

typedef __attribute__((ext_vector_type(8))) short bf16x8;
typedef __attribute__((ext_vector_type(4))) float f32x4;
typedef __attribute__((ext_vector_type(2))) float f32x2;

__device__ __forceinline__ float wave_reduce_sum(float v) {
#pragma unroll
  for (int off = 32; off > 0; off >>= 1) v += __shfl_down(v, off);
  return v;
}

__device__ __forceinline__ unsigned short f2bf(float f) {
  union { float f; unsigned int u; } v; v.f = f;
  unsigned int u = v.u;
  unsigned int r = (u + 0x7fffu + ((u >> 16) & 1u)) >> 16;  // RNE
  return (unsigned short)r;
}
__device__ __forceinline__ float bf_lo(unsigned int u) { return __uint_as_float(u << 16); }
__device__ __forceinline__ float bf_hi(unsigned int u) { return __uint_as_float(u & 0xffff0000u); }

__device__ __forceinline__ unsigned char f2fp8(float f) {
  int p = __builtin_amdgcn_cvt_pk_fp8_f32(f, f, 0, false);  // OCP e4m3fn on gfx950
  return (unsigned char)(p & 0xff);
}

// ---------------- weight pre-pack into MFMA fragment order ----------------
__global__ __launch_bounds__(256) void pack_w(const float* __restrict__ W1,
                                              const float* __restrict__ W2,
                                              unsigned short* __restrict__ W1b,
                                              unsigned short* __restrict__ W2b) {
  for (int idx = threadIdx.x + blockIdx.x * 256; idx < 32768 + 16384;
       idx += 256 * gridDim.x) {
    if (idx < 32768) {
      int head = idx >> 13, ks = (idx >> 11) & 3, nt = (idx >> 9) & 3;
      int lane = (idx >> 3) & 63, j = idx & 7;
      int k = ks * 32 + (lane >> 4) * 8 + j;
      int c = head * 64 + nt * 16 + (lane & 15);
      W1b[idx] = f2bf(W1[k * 256 + c]);
    } else {
      int o = idx - 32768;
      int ks = o >> 11, nt = (o >> 9) & 3, lane = (o >> 3) & 63, j = o & 7;
      int k = ks * 32 + (lane >> 4) * 8 + j;
      int c = nt * 16 + (lane & 15);
      W2b[o] = f2bf(W2[k * 64 + c]);
    }
  }
}

// ---------------- MFMA GEMM, all heads per block ----------------
template <int KSTEPS, bool A_BF16, int NH, bool STORE_FP8>
__global__ __launch_bounds__(256) void gemm_mfma(const void* __restrict__ Av,
                                                 const unsigned short* __restrict__ Wb,
                                                 void* __restrict__ Hbv,
                                                 float* __restrict__ as_out,
                                                 float* __restrict__ ad_out,
                                                 const float* __restrict__ att_s,
                                                 const float* __restrict__ att_d,
                                                 int M) {
  constexpr int K = KSTEPS * 32;
  constexpr int N = NH * 64;
  const int lane = threadIdx.x & 63, wid = threadIdx.x >> 6;
  const int rowbase = blockIdx.x * 64 + wid * 16;
  const int g = lane >> 4, li = lane & 15;
  int r_a = rowbase + li;
  if (r_a > M - 1) r_a = M - 1;

  f32x4 acc[NH][4];
#pragma unroll
  for (int h = 0; h < NH; h++)
#pragma unroll
    for (int nt = 0; nt < 4; nt++) {
      acc[h][nt][0] = 0.f; acc[h][nt][1] = 0.f; acc[h][nt][2] = 0.f; acc[h][nt][3] = 0.f;
    }

#pragma unroll
  for (int ks = 0; ks < KSTEPS; ks++) {
    bf16x8 a;
    if constexpr (A_BF16) {
      const unsigned short* Ab = (const unsigned short*)Av;
      a = *(const bf16x8*)(Ab + (size_t)r_a * K + ks * 32 + g * 8);
    } else {
      const float* Af = (const float*)Av;
      const float* p = Af + (size_t)r_a * K + ks * 32 + g * 8;
      float4 v0 = *(const float4*)p, v1 = *(const float4*)(p + 4);
      a[0] = (short)f2bf(v0.x); a[1] = (short)f2bf(v0.y);
      a[2] = (short)f2bf(v0.z); a[3] = (short)f2bf(v0.w);
      a[4] = (short)f2bf(v1.x); a[5] = (short)f2bf(v1.y);
      a[6] = (short)f2bf(v1.z); a[7] = (short)f2bf(v1.w);
    }
#pragma unroll
    for (int h = 0; h < NH; h++)
#pragma unroll
      for (int nt = 0; nt < 4; nt++) {
        bf16x8 b = *(const bf16x8*)(Wb + ((size_t)((h * KSTEPS + ks) * 4 + nt) * 64 + lane) * 8);
        acc[h][nt] = __builtin_amdgcn_mfma_f32_16x16x32_bf16(a, b, acc[h][nt], 0, 0, 0);
      }
  }

#pragma unroll
  for (int h = 0; h < NH; h++) {
    float asum[4] = {0.f, 0.f, 0.f, 0.f}, dsum[4] = {0.f, 0.f, 0.f, 0.f};
#pragma unroll
    for (int nt = 0; nt < 4; nt++) {
      float ws = att_s[h * 64 + nt * 16 + li];
      float wd = att_d[h * 64 + nt * 16 + li];
#pragma unroll
      for (int r = 0; r < 4; r++) { asum[r] += acc[h][nt][r] * ws; dsum[r] += acc[h][nt][r] * wd; }
    }
#pragma unroll
    for (int r = 0; r < 4; r++) {
#pragma unroll
      for (int m = 1; m < 16; m <<= 1) {
        asum[r] += __shfl_xor(asum[r], m);
        dsum[r] += __shfl_xor(dsum[r], m);
      }
    }
#pragma unroll
    for (int r = 0; r < 4; r++) {
      int gr = rowbase + g * 4 + r;
      if (gr < M) {
#pragma unroll
        for (int nt = 0; nt < 4; nt++) {
          if constexpr (STORE_FP8) {
            unsigned char* H8 = (unsigned char*)Hbv;
            H8[(size_t)gr * N + h * 64 + nt * 16 + li] = f2fp8(acc[h][nt][r]);
          } else {
            unsigned short* Hb = (unsigned short*)Hbv;
            Hb[(size_t)gr * N + h * 64 + nt * 16 + li] = f2bf(acc[h][nt][r]);
          }
        }
        if (li == 0) {
          as_out[(size_t)gr * NH + h] = asum[r] * LOG2E;
          ad_out[(size_t)gr * NH + h] = dsum[r] * LOG2E;
        }
      }
    }
  }
}

// ---------------- CSR build: bucket partition (no per-edge global atomics) ----
__global__ __launch_bounds__(256) void init_kernel(int* __restrict__ gcursor,
                                                   float* __restrict__ poolrep) {
  int i = blockIdx.x * blockDim.x + threadIdx.x;
  if (i < 256) gcursor[i] = 0;
  if (i < 64 * 64) poolrep[i] = 0.f;
}

// pass 1: partition edges into 196 coarse buckets (dst>>8).
// LDS histogram + one global atomic per (block,bucket) run reservation.
__global__ __launch_bounds__(256) void partition_kernel(const int* __restrict__ esrc,
                                                        const int* __restrict__ edst,
                                                        int* __restrict__ gcursor,
                                                        int2* __restrict__ pairs,
                                                        int E, int Etot) {
  __shared__ int hist[256];
  __shared__ int base[256];
  const int tid = threadIdx.x;
  const int e0 = blockIdx.x * 2048;
  hist[tid] = 0;
  __syncthreads();
  int d8[8], rk8[8], bk8[8];
#pragma unroll
  for (int j = 0; j < 8; j++) {
    int e = e0 + tid * 8 + j;
    d8[j] = -1;
    if (e < Etot) {
      int d = (e < E) ? edst[e] : (e - E);
      d8[j] = d;
      bk8[j] = d >> 8;
      rk8[j] = atomicAdd(&hist[bk8[j]], 1);
    }
  }
  __syncthreads();
  if (hist[tid] > 0) base[tid] = atomicAdd(&gcursor[tid], hist[tid]);
  __syncthreads();
#pragma unroll
  for (int j = 0; j < 8; j++) {
    int e = e0 + tid * 8 + j;
    if (e < Etot) {
      int s = (e < E) ? esrc[e] : (e - E);
      int2 pr; pr.x = s; pr.y = d8[j];
      pairs[(size_t)bk8[j] * BCAP + base[bk8[j]] + rk8[j]] = pr;
    }
  }
}

// pass 2: exclusive scan of bucket counts.
__global__ __launch_bounds__(256) void bucket_scan(const int* __restrict__ gcursor,
                                                   int* __restrict__ bucket_base,
                                                   int* __restrict__ row_ptr,
                                                   int n, int etot) {
  __shared__ int tmp[256];
  int tid = threadIdx.x;
  int v = (tid < NBUCK) ? gcursor[tid] : 0;
  tmp[tid] = v;
  __syncthreads();
  for (int off = 1; off < 256; off <<= 1) {
    int t = (tid >= off) ? tmp[tid - off] : 0;
    __syncthreads();
    tmp[tid] += t;
    __syncthreads();
  }
  if (tid < NBUCK) bucket_base[tid] = tmp[tid] - v;
  if (tid == 0) row_ptr[n] = etot;
}

// pass 3 (+fused edge weights): per bucket, 256-bin LDS histogram + scan ->
// final CSR order; writes row_ptr and 16B weight records. No global atomics.
__global__ __launch_bounds__(512) void bucket_csr(const int2* __restrict__ pairs,
                                                  const int* __restrict__ gcursor,
                                                  const int* __restrict__ bucket_base,
                                                  const float4* __restrict__ as1,
                                                  const float4* __restrict__ ad1,
                                                  int4* __restrict__ recs,
                                                  int* __restrict__ row_ptr, int N) {
  __shared__ int hist[256], offs[256], cnt2[256];
  const int b = blockIdx.x;
  const int cnt = gcursor[b];
  const int gbase = bucket_base[b];
  const int2* bp = pairs + (size_t)b * BCAP;
  const int tid = threadIdx.x;
  if (tid < 256) { hist[tid] = 0; cnt2[tid] = 0; }
  __syncthreads();
  for (int i = tid; i < cnt; i += 512) atomicAdd(&hist[bp[i].y & 255], 1);
  __syncthreads();
  if (tid < 256) offs[tid] = hist[tid];
  __syncthreads();
  for (int off = 1; off < 256; off <<= 1) {
    int t = 0;
    if (tid < 256 && tid >= off) t = offs[tid - off];
    __syncthreads();
    if (tid < 256) offs[tid] += t;
    __syncthreads();
  }
  // offs = inclusive scan; exclusive = offs - hist
  if (tid < 256) {
    int node = b * 256 + tid;
    if (node < N) row_ptr[node] = gbase + offs[tid] - hist[tid];
  }
  __syncthreads();
  for (int i = tid; i < cnt; i += 512) {
    int2 pr = bp[i];
    int lo = pr.y & 255;
    int rank = atomicAdd(&cnt2[lo], 1);
    int pos = gbase + offs[lo] - hist[lo] + rank;
    float4 a = as1[pr.x], dd = ad1[pr.y];
    float s0 = a.x + dd.x, s1 = a.y + dd.y, s2 = a.z + dd.z, s3 = a.w + dd.w;
    float w0 = exp2f(fmaxf(s0, NEG_SLOPE * s0));
    float w1 = exp2f(fmaxf(s1, NEG_SLOPE * s1));
    float w2 = exp2f(fmaxf(s2, NEG_SLOPE * s2));
    float w3 = exp2f(fmaxf(s3, NEG_SLOPE * s3));
    int4 r;
    r.x = pr.x;
    r.y = (int)((unsigned)f2bf(w0) | ((unsigned)f2bf(w1) << 16));
    r.z = (int)((unsigned)f2bf(w2) | ((unsigned)f2bf(w3) << 16));
    r.w = 0;
    recs[pos] = r;
  }
}

// ---------------- layer-1 aggregate: one wave per dst, fp8 gather ----------------
__global__ __launch_bounds__(256) void agg1_kernel(const unsigned char* __restrict__ H8,
                                                   const int4* __restrict__ recs,
                                                   const int* __restrict__ row_ptr,
                                                   const float* __restrict__ b1,
                                                   unsigned short* __restrict__ outb, int n) {
  int d = blockIdx.x * 4 + (threadIdx.x >> 6);
  if (d >= n) return;
  int l = threadIdx.x & 63;
  int hh = l >> 4;
  int e0 = __builtin_amdgcn_readfirstlane(row_ptr[d]);
  int e1 = __builtin_amdgcn_readfirstlane(row_ptr[d + 1]);
  const int shamt = (hh & 1) ? 0 : 16;
  const bool lowpair = hh < 2;
  float4 acc = {0.f, 0.f, 0.f, 0.f};
  float denom = 0.f;
  int e = e0;
#define WSEL(r) __uint_as_float(((unsigned)((lowpair) ? (r).y : (r).z) << shamt) & 0xffff0000u)
#define ACCUM(wgt, u8)                                                     \
  {                                                                        \
    f32x2 lo_ = __builtin_amdgcn_cvt_pk_f32_fp8((int)(u8), false);         \
    f32x2 hi_ = __builtin_amdgcn_cvt_pk_f32_fp8((int)(u8), true);          \
    acc.x += (wgt)*lo_[0]; acc.y += (wgt)*lo_[1];                          \
    acc.z += (wgt)*hi_[0]; acc.w += (wgt)*hi_[1];                          \
    denom += (wgt);                                                        \
  }
  for (; e + 3 < e1; e += 4) {
    int4 r0 = recs[e], r1 = recs[e + 1], r2 = recs[e + 2], r3 = recs[e + 3];
    unsigned u0 = *(const unsigned*)(H8 + (size_t)r0.x * C1 + l * 4);
    unsigned u1 = *(const unsigned*)(H8 + (size_t)r1.x * C1 + l * 4);
    unsigned u2 = *(const unsigned*)(H8 + (size_t)r2.x * C1 + l * 4);
    unsigned u3 = *(const unsigned*)(H8 + (size_t)r3.x * C1 + l * 4);
    float w0 = WSEL(r0), w1 = WSEL(r1), w2 = WSEL(r2), w3 = WSEL(r3);
    ACCUM(w0, u0) ACCUM(w1, u1) ACCUM(w2, u2) ACCUM(w3, u3)
  }
  for (; e < e1; e++) {
    int4 r0 = recs[e];
    unsigned u = *(const unsigned*)(H8 + (size_t)r0.x * C1 + l * 4);
    float wq = WSEL(r0);
    ACCUM(wq, u)
  }
#undef ACCUM
#undef WSEL
  float inv = 1.f / (denom + 1e-16f);
  float4 bb = *(const float4*)(b1 + l * 4);
  float4 o;
  o.x = acc.x * inv + bb.x; o.y = acc.y * inv + bb.y;
  o.z = acc.z * inv + bb.z; o.w = acc.w * inv + bb.w;
  o.x = o.x > 0.f ? o.x : (__expf(o.x) - 1.f);
  o.y = o.y > 0.f ? o.y : (__expf(o.y) - 1.f);
  o.z = o.z > 0.f ? o.z : (__expf(o.z) - 1.f);
  o.w = o.w > 0.f ? o.w : (__expf(o.w) - 1.f);
  uint2 pk;
  pk.x = (unsigned int)f2bf(o.x) | ((unsigned int)f2bf(o.y) << 16);
  pk.y = (unsigned int)f2bf(o.z) | ((unsigned int)f2bf(o.w) << 16);
  *(uint2*)(outb + (size_t)d * C1 + l * 4) = pk;
}

// ---------------- layer-2 aggregate + fused mean pool ----------------
__global__ __launch_bounds__(256) void agg2_pool(const unsigned short* __restrict__ Hb,
                                                 const float* __restrict__ as_,
                                                 const float* __restrict__ ad_,
                                                 const int* __restrict__ row_ptr,
                                                 const int4* __restrict__ recs,
                                                 const float* __restrict__ b2,
                                                 float* __restrict__ poolrep, int n) {
  __shared__ float lds[4][64];
  int wid = threadIdx.x >> 6;
  int d = blockIdx.x * 4 + wid;
  int l = threadIdx.x & 63, q = l >> 4, li = l & 15;
  float ad = ad_[d];
  int e0 = row_ptr[d], e1 = row_ptr[d + 1];
  float4 acc = {0.f, 0.f, 0.f, 0.f};
  float denom = 0.f;
  for (int e = e0 + q; e < e1; e += 4) {
    int s = ((const int*)recs)[(size_t)e * 4];
    float sc = as_[s] + ad;
    float w = exp2f(fmaxf(sc, NEG_SLOPE * sc));
    denom += w;
    uint2 p = *(const uint2*)(Hb + (size_t)s * HID + li * 4);
    acc.x += w * bf_lo(p.x); acc.y += w * bf_hi(p.x);
    acc.z += w * bf_lo(p.y); acc.w += w * bf_hi(p.y);
  }
#pragma unroll
  for (int m = 16; m <= 32; m <<= 1) {
    acc.x += __shfl_xor(acc.x, m); acc.y += __shfl_xor(acc.y, m);
    acc.z += __shfl_xor(acc.z, m); acc.w += __shfl_xor(acc.w, m);
    denom += __shfl_xor(denom, m);
  }
  if (q == 0) {
    float inv = 1.f / (denom + 1e-16f);
    float o[4] = {acc.x * inv + b2[li * 4], acc.y * inv + b2[li * 4 + 1],
                  acc.z * inv + b2[li * 4 + 2], acc.w * inv + b2[li * 4 + 3]};
#pragma unroll
    for (int j = 0; j < 4; j++) {
      float v = o[j];
      lds[wid][li * 4 + j] = v > 0.f ? v : (__expf(v) - 1.f);
    }
  }
  __syncthreads();
  if (threadIdx.x < 64) {
    int c = threadIdx.x;
    float v = lds[0][c] + lds[1][c] + lds[2][c] + lds[3][c];
    atomicAdd(&poolrep[(blockIdx.x & 63) * 64 + c], v);
  }
}

__global__ __launch_bounds__(64) void head_kernel(const float* __restrict__ poolrep,
                                                  const float* __restrict__ Wc,
                                                  const float* __restrict__ bc,
                                                  float* __restrict__ out, float inv_n) {
  int l = threadIdx.x;
  float p = 0.f;
  for (int k = 0; k < 64; k++) p += poolrep[k * 64 + l];
  p *= inv_n;
  float o0 = wave_reduce_sum(p * Wc[l * 2 + 0]);
  float o1 = wave_reduce_sum(p * Wc[l * 2 + 1]);
  if (l == 0) { out[0] = o0 + bc[0]; out[1] = o1 + bc[1]; }
}

// ---------------- host ----------------
static inline size_t align256(size_t x) { return (x + 255) & ~(size_t)255; }

extern "C" void kernel_launch(void* const* d_in, const int* in_sizes, int n_in,
                              void* d_out, int out_size, void* d_ws, size_t ws_size,
                              hipStream_t stream) {
  const float* x        = (const float*)d_in[0];
  const int*   ei       = (const int*)d_in[1];
  const float* W1       = (const float*)d_in[2];
  const float* att_src1 = (const float*)d_in[3];
  const float* att_dst1 = (const float*)d_in[4];
  const float* b1       = (const float*)d_in[5];
  const float* W2       = (const float*)d_in[6];
  const float* att_src2 = (const float*)d_in[7];
  const float* att_dst2 = (const float*)d_in[8];
  const float* b2       = (const float*)d_in[9];
  const float* Wc       = (const float*)d_in[10];
  const float* bc       = (const float*)d_in[11];
  float* out = (float*)d_out;

  const int N = in_sizes[0] / F_IN;          // 50000
  const int E = in_sizes[1] / 2;             // 1,600,000
  const int Etot = E + N;                    // + self loops
  const int* ei_src = ei;
  const int* ei_dst = ei + E;

  // workspace layout (~90 MB)
  char* w = (char*)d_ws;
  size_t off = 0;
  unsigned char*  h1b8   = (unsigned char*)(w + off);  off += align256((size_t)N * C1);      // 12.8MB fp8
  unsigned short* h1actb = (unsigned short*)(w + off); off += align256((size_t)N * C1 * 2);  // 25.6MB bf16
  unsigned short* h2b    = (unsigned short*)(w + off); off += align256((size_t)N * HID * 2); // 6.4MB bf16
  float* as1   = (float*)(w + off); off += align256((size_t)N * HEADS * 4);
  float* ad1   = (float*)(w + off); off += align256((size_t)N * HEADS * 4);
  float* as2   = (float*)(w + off); off += align256((size_t)N * 4);
  float* ad2   = (float*)(w + off); off += align256((size_t)N * 4);
  int* row_ptr = (int*)(w + off);   off += align256((size_t)(N + 1) * 4);
  int* gcursor = (int*)(w + off);   off += align256(256 * 4);
  int* bucket_base = (int*)(w + off); off += align256(256 * 4);
  float* poolrep = (float*)(w + off); off += align256(64 * 64 * 4);
  unsigned short* W1b = (unsigned short*)(w + off); off += align256(32768 * 2);
  unsigned short* W2b = (unsigned short*)(w + off); off += align256(16384 * 2);
  int2* pairs  = (int2*)(w + off);  off += align256((size_t)NBUCK * BCAP * 8);  // 16.1MB
  int4* recs   = (int4*)(w + off);  off += align256((size_t)Etot * 16);         // 26.4MB

  int nb4 = (N + 3) / 4;
  int rowblocks = (N + 63) / 64;
  int pblocks = (Etot + 2047) / 2048;

  init_kernel<<<16, 256, 0, stream>>>(gcursor, poolrep);
  partition_kernel<<<pblocks, 256, 0, stream>>>(ei_src, ei_dst, gcursor, pairs, E, Etot);
  bucket_scan<<<1, 256, 0, stream>>>(gcursor, bucket_base, row_ptr, N, Etot);
  pack_w<<<64, 256, 0, stream>>>(W1, W2, W1b, W2b);

  // layer 1: GEMM (fp8 h-store) -> CSR+weights (bucket_csr) -> aggregate
  gemm_mfma<4, false, HEADS, true><<<rowblocks, 256, 0, stream>>>(
      x, W1b, h1b8, as1, ad1, att_src1, att_dst1, N);
  bucket_csr<<<NBUCK, 512, 0, stream>>>(pairs, gcursor, bucket_base,
                                        (const float4*)as1, (const float4*)ad1,
                                        recs, row_ptr, N);
  agg1_kernel<<<nb4, 256, 0, stream>>>(h1b8, recs, row_ptr, b1, h1actb, N);

  // layer 2 (bf16 h-store)
  gemm_mfma<8, true, 1, false><<<rowblocks, 256, 0, stream>>>(
      h1actb, W2b, h2b, as2, ad2, att_src2, att_dst2, N);
  agg2_pool<<<nb4, 256, 0, stream>>>(h2b, as2, ad2, row_ptr, recs, b2, poolrep, N);

  head_kernel<<<1, 64, 0, stream>>>(poolrep, Wc, bc, out, 1.0f / (float)N);
}

// Round 10
// 220.801 us; speedup vs baseline: 3.8013x; 1.0267x over previous
//
#include <hip/hip_runtime.h>
#include <cstdint>
#include <cstddef>

#define NEG_SLOPE 0.2f
#define F_IN 128
#define C1 256      // HEADS*HID layer-1 width
#define HID 64
#define HEADS 4
#define LOG2E 1.4426950408889634f
#define NBUCK 196   // ceil(50000/256)
#define BCAP 10240  // per-bucket region capacity

typedef __attribute__((ext_vector_type(8))) short bf16x8;
typedef __attribute__((ext_vector_type(4))) float f32x4;
typedef __attribute__((ext_vector_type(2))) float f32x2;

__device__ __forceinline__ float wave_reduce_sum(float v) {
#pragma unroll
  for (int off = 32; off > 0; off >>= 1) v += __shfl_down(v, off);
  return v;
}

__device__ __forceinline__ unsigned short f2bf(float f) {
  union { float f; unsigned int u; } v; v.f = f;
  unsigned int u = v.u;
  unsigned int r = (u + 0x7fffu + ((u >> 16) & 1u)) >> 16;  // RNE
  return (unsigned short)r;
}
__device__ __forceinline__ float bf_lo(unsigned int u) { return __uint_as_float(u << 16); }
__device__ __forceinline__ float bf_hi(unsigned int u) { return __uint_as_float(u & 0xffff0000u); }

__device__ __forceinline__ unsigned char f2fp8(float f) {
  int p = __builtin_amdgcn_cvt_pk_fp8_f32(f, f, 0, false);  // OCP e4m3fn
  return (unsigned char)(p & 0xff);
}

// ---------------- weight pre-pack into MFMA fragment order ----------------
__global__ __launch_bounds__(256) void pack_w(const float* __restrict__ W1,
                                              const float* __restrict__ W2,
                                              unsigned short* __restrict__ W1b,
                                              unsigned short* __restrict__ W2b) {
  for (int idx = threadIdx.x + blockIdx.x * 256; idx < 32768 + 16384;
       idx += 256 * gridDim.x) {
    if (idx < 32768) {
      int head = idx >> 13, ks = (idx >> 11) & 3, nt = (idx >> 9) & 3;
      int lane = (idx >> 3) & 63, j = idx & 7;
      int k = ks * 32 + (lane >> 4) * 8 + j;
      int c = head * 64 + nt * 16 + (lane & 15);
      W1b[idx] = f2bf(W1[k * 256 + c]);
    } else {
      int o = idx - 32768;
      int ks = o >> 11, nt = (o >> 9) & 3, lane = (o >> 3) & 63, j = o & 7;
      int k = ks * 32 + (lane >> 4) * 8 + j;
      int c = nt * 16 + (lane & 15);
      W2b[o] = f2bf(W2[k * 64 + c]);
    }
  }
}

// ---------------- MFMA GEMM1 (fp32 A, fp8 h-store, all heads per block) ----------------
__global__ __launch_bounds__(256) void gemm1_mfma(const float* __restrict__ Af,
                                                  const unsigned short* __restrict__ Wb,
                                                  unsigned char* __restrict__ H8,
                                                  float* __restrict__ as_out,
                                                  float* __restrict__ ad_out,
                                                  const float* __restrict__ att_s,
                                                  const float* __restrict__ att_d,
                                                  int M) {
  constexpr int KSTEPS = 4, NH = HEADS, K = 128, N = 256;
  const int lane = threadIdx.x & 63, wid = threadIdx.x >> 6;
  const int rowbase = blockIdx.x * 64 + wid * 16;
  const int g = lane >> 4, li = lane & 15;
  int r_a = rowbase + li;
  if (r_a > M - 1) r_a = M - 1;

  f32x4 acc[NH][4];
#pragma unroll
  for (int h = 0; h < NH; h++)
#pragma unroll
    for (int nt = 0; nt < 4; nt++) {
      acc[h][nt][0] = 0.f; acc[h][nt][1] = 0.f; acc[h][nt][2] = 0.f; acc[h][nt][3] = 0.f;
    }

#pragma unroll
  for (int ks = 0; ks < KSTEPS; ks++) {
    bf16x8 a;
    const float* p = Af + (size_t)r_a * K + ks * 32 + g * 8;
    float4 v0 = *(const float4*)p, v1 = *(const float4*)(p + 4);
    a[0] = (short)f2bf(v0.x); a[1] = (short)f2bf(v0.y);
    a[2] = (short)f2bf(v0.z); a[3] = (short)f2bf(v0.w);
    a[4] = (short)f2bf(v1.x); a[5] = (short)f2bf(v1.y);
    a[6] = (short)f2bf(v1.z); a[7] = (short)f2bf(v1.w);
#pragma unroll
    for (int h = 0; h < NH; h++)
#pragma unroll
      for (int nt = 0; nt < 4; nt++) {
        bf16x8 b = *(const bf16x8*)(Wb + ((size_t)((h * KSTEPS + ks) * 4 + nt) * 64 + lane) * 8);
        acc[h][nt] = __builtin_amdgcn_mfma_f32_16x16x32_bf16(a, b, acc[h][nt], 0, 0, 0);
      }
  }

#pragma unroll
  for (int h = 0; h < NH; h++) {
    float asum[4] = {0.f, 0.f, 0.f, 0.f}, dsum[4] = {0.f, 0.f, 0.f, 0.f};
#pragma unroll
    for (int nt = 0; nt < 4; nt++) {
      float ws = att_s[h * 64 + nt * 16 + li];
      float wd = att_d[h * 64 + nt * 16 + li];
#pragma unroll
      for (int r = 0; r < 4; r++) { asum[r] += acc[h][nt][r] * ws; dsum[r] += acc[h][nt][r] * wd; }
    }
#pragma unroll
    for (int r = 0; r < 4; r++) {
#pragma unroll
      for (int m = 1; m < 16; m <<= 1) {
        asum[r] += __shfl_xor(asum[r], m);
        dsum[r] += __shfl_xor(dsum[r], m);
      }
    }
#pragma unroll
    for (int r = 0; r < 4; r++) {
      int gr = rowbase + g * 4 + r;
      if (gr < M) {
#pragma unroll
        for (int nt = 0; nt < 4; nt++)
          H8[(size_t)gr * N + h * 64 + nt * 16 + li] = f2fp8(acc[h][nt][r]);
        if (li == 0) {
          as_out[(size_t)gr * NH + h] = asum[r] * LOG2E;
          ad_out[(size_t)gr * NH + h] = dsum[r] * LOG2E;
        }
      }
    }
  }
}

// ---------------- CSR build: bucket partition ----------------
__global__ __launch_bounds__(256) void init_kernel(int* __restrict__ gcursor,
                                                   float* __restrict__ poolrep) {
  int i = blockIdx.x * blockDim.x + threadIdx.x;
  if (i < 256) gcursor[i] = 0;
  if (i < 64 * 64) poolrep[i] = 0.f;
}

__global__ __launch_bounds__(256) void partition_kernel(const int* __restrict__ esrc,
                                                        const int* __restrict__ edst,
                                                        int* __restrict__ gcursor,
                                                        int2* __restrict__ pairs,
                                                        int E, int Etot) {
  __shared__ int hist[256];
  __shared__ int base[256];
  const int tid = threadIdx.x;
  const int e0 = blockIdx.x * 2048;
  hist[tid] = 0;
  __syncthreads();
  int d8[8], rk8[8], bk8[8];
#pragma unroll
  for (int j = 0; j < 8; j++) {
    int e = e0 + tid * 8 + j;
    d8[j] = -1;
    if (e < Etot) {
      int d = (e < E) ? edst[e] : (e - E);
      d8[j] = d;
      bk8[j] = d >> 8;
      rk8[j] = atomicAdd(&hist[bk8[j]], 1);
    }
  }
  __syncthreads();
  if (hist[tid] > 0) base[tid] = atomicAdd(&gcursor[tid], hist[tid]);
  __syncthreads();
#pragma unroll
  for (int j = 0; j < 8; j++) {
    int e = e0 + tid * 8 + j;
    if (e < Etot) {
      int s = (e < E) ? esrc[e] : (e - E);
      int2 pr; pr.x = s; pr.y = d8[j];
      pairs[(size_t)bk8[j] * BCAP + base[bk8[j]] + rk8[j]] = pr;
    }
  }
}

__global__ __launch_bounds__(256) void bucket_scan(const int* __restrict__ gcursor,
                                                   int* __restrict__ bucket_base,
                                                   int* __restrict__ row_ptr,
                                                   int n, int etot) {
  __shared__ int tmp[256];
  int tid = threadIdx.x;
  int v = (tid < NBUCK) ? gcursor[tid] : 0;
  tmp[tid] = v;
  __syncthreads();
  for (int off = 1; off < 256; off <<= 1) {
    int t = (tid >= off) ? tmp[tid - off] : 0;
    __syncthreads();
    tmp[tid] += t;
    __syncthreads();
  }
  if (tid < NBUCK) bucket_base[tid] = tmp[tid] - v;
  if (tid == 0) row_ptr[n] = etot;
}

__global__ __launch_bounds__(512) void bucket_csr(const int2* __restrict__ pairs,
                                                  const int* __restrict__ gcursor,
                                                  const int* __restrict__ bucket_base,
                                                  const float4* __restrict__ as1,
                                                  const float4* __restrict__ ad1,
                                                  int4* __restrict__ recs,
                                                  int* __restrict__ row_ptr, int N) {
  __shared__ int hist[256], offs[256], cnt2[256];
  const int b = blockIdx.x;
  const int cnt = gcursor[b];
  const int gbase = bucket_base[b];
  const int2* bp = pairs + (size_t)b * BCAP;
  const int tid = threadIdx.x;
  if (tid < 256) { hist[tid] = 0; cnt2[tid] = 0; }
  __syncthreads();
  for (int i = tid; i < cnt; i += 512) atomicAdd(&hist[bp[i].y & 255], 1);
  __syncthreads();
  if (tid < 256) offs[tid] = hist[tid];
  __syncthreads();
  for (int off = 1; off < 256; off <<= 1) {
    int t = 0;
    if (tid < 256 && tid >= off) t = offs[tid - off];
    __syncthreads();
    if (tid < 256) offs[tid] += t;
    __syncthreads();
  }
  if (tid < 256) {
    int node = b * 256 + tid;
    if (node < N) row_ptr[node] = gbase + offs[tid] - hist[tid];
  }
  __syncthreads();
  for (int i = tid; i < cnt; i += 512) {
    int2 pr = bp[i];
    int lo = pr.y & 255;
    int rank = atomicAdd(&cnt2[lo], 1);
    int pos = gbase + offs[lo] - hist[lo] + rank;
    float4 a = as1[pr.x], dd = ad1[pr.y];
    float s0 = a.x + dd.x, s1 = a.y + dd.y, s2 = a.z + dd.z, s3 = a.w + dd.w;
    float w0 = exp2f(fmaxf(s0, NEG_SLOPE * s0));
    float w1 = exp2f(fmaxf(s1, NEG_SLOPE * s1));
    float w2 = exp2f(fmaxf(s2, NEG_SLOPE * s2));
    float w3 = exp2f(fmaxf(s3, NEG_SLOPE * s3));
    int4 r;
    r.x = pr.x;
    r.y = (int)((unsigned)f2bf(w0) | ((unsigned)f2bf(w1) << 16));
    r.z = (int)((unsigned)f2bf(w2) | ((unsigned)f2bf(w3) << 16));
    r.w = 0;
    recs[pos] = r;
  }
}

// ---------------- fused: layer-1 aggregate + GEMM2 + alpha2 dots ----------------
// block = 16 dsts (4 waves x 4 dsts). h1act staged in XOR-swizzled LDS bf16,
// then 16x64 GEMM over K=256 via MFMA; h2 stored fp8; as2/ad2 from fp32 accs.
__global__ __launch_bounds__(256) void agg1_gemm2(const unsigned char* __restrict__ H8,
                                                  const int4* __restrict__ recs,
                                                  const int* __restrict__ row_ptr,
                                                  const float* __restrict__ b1,
                                                  const unsigned short* __restrict__ W2b,
                                                  const float* __restrict__ att_s2,
                                                  const float* __restrict__ att_d2,
                                                  unsigned char* __restrict__ H2,
                                                  float* __restrict__ as2,
                                                  float* __restrict__ ad2, int n) {
  __shared__ unsigned char lds_h[16 * 512];   // 16 rows x 256 bf16, swizzled
  __shared__ float pA[4][16], pD[4][16];
  const int tid = threadIdx.x;
  const int l = tid & 63, w = tid >> 6;
  const int dbase = blockIdx.x * 16;
  const int hh = l >> 4;
  const int shamt = (hh & 1) ? 0 : 16;
  const bool lowpair = hh < 2;
  const float4 bb = *(const float4*)(b1 + l * 4);

  // ---- phase 1: aggregate 4 dsts per wave into LDS ----
#define WSEL(r) __uint_as_float(((unsigned)((lowpair) ? (r).y : (r).z) << shamt) & 0xffff0000u)
#define ACCUM(wgt, u8)                                                     \
  {                                                                        \
    f32x2 lo_ = __builtin_amdgcn_cvt_pk_f32_fp8((int)(u8), false);         \
    f32x2 hi_ = __builtin_amdgcn_cvt_pk_f32_fp8((int)(u8), true);          \
    acc.x += (wgt)*lo_[0]; acc.y += (wgt)*lo_[1];                          \
    acc.z += (wgt)*hi_[0]; acc.w += (wgt)*hi_[1];                          \
    denom += (wgt);                                                        \
  }
  for (int i = 0; i < 4; i++) {
    int dloc = w * 4 + i;
    int d = dbase + dloc;
    bool active = d < n;
    float4 acc = {0.f, 0.f, 0.f, 0.f};
    float denom = 0.f;
    if (active) {
      int e0 = __builtin_amdgcn_readfirstlane(row_ptr[d]);
      int e1 = __builtin_amdgcn_readfirstlane(row_ptr[d + 1]);
      int e = e0;
      for (; e + 3 < e1; e += 4) {
        int4 r0 = recs[e], r1 = recs[e + 1], r2 = recs[e + 2], r3 = recs[e + 3];
        unsigned u0 = *(const unsigned*)(H8 + (size_t)r0.x * C1 + l * 4);
        unsigned u1 = *(const unsigned*)(H8 + (size_t)r1.x * C1 + l * 4);
        unsigned u2 = *(const unsigned*)(H8 + (size_t)r2.x * C1 + l * 4);
        unsigned u3 = *(const unsigned*)(H8 + (size_t)r3.x * C1 + l * 4);
        float w0 = WSEL(r0), w1 = WSEL(r1), w2 = WSEL(r2), w3 = WSEL(r3);
        ACCUM(w0, u0) ACCUM(w1, u1) ACCUM(w2, u2) ACCUM(w3, u3)
      }
      for (; e < e1; e++) {
        int4 r0 = recs[e];
        unsigned u = *(const unsigned*)(H8 + (size_t)r0.x * C1 + l * 4);
        float wq = WSEL(r0);
        ACCUM(wq, u)
      }
    }
    float inv = 1.f / (denom + 1e-16f);
    float4 o;
    o.x = acc.x * inv + bb.x; o.y = acc.y * inv + bb.y;
    o.z = acc.z * inv + bb.z; o.w = acc.w * inv + bb.w;
    o.x = o.x > 0.f ? o.x : (__expf(o.x) - 1.f);
    o.y = o.y > 0.f ? o.y : (__expf(o.y) - 1.f);
    o.z = o.z > 0.f ? o.z : (__expf(o.z) - 1.f);
    o.w = o.w > 0.f ? o.w : (__expf(o.w) - 1.f);
    if (!active) { o.x = 0.f; o.y = 0.f; o.z = 0.f; o.w = 0.f; }
    uint2 pk;
    pk.x = (unsigned int)f2bf(o.x) | ((unsigned int)f2bf(o.y) << 16);
    pk.y = (unsigned int)f2bf(o.z) | ((unsigned int)f2bf(o.w) << 16);
    unsigned byte = (unsigned)(l * 8) ^ ((unsigned)(dloc & 7) << 4);
    *(uint2*)(lds_h + dloc * 512 + byte) = pk;
  }
#undef ACCUM
#undef WSEL
  __syncthreads();

  // ---- phase 2: GEMM2 16x64, K=256; wave w owns cols w*16..w*16+15 ----
  const int li2 = l & 15, g2 = l >> 4;
  f32x4 acc2;
  acc2[0] = 0.f; acc2[1] = 0.f; acc2[2] = 0.f; acc2[3] = 0.f;
#pragma unroll
  for (int ks = 0; ks < 8; ks++) {
    unsigned byte = (unsigned)((ks * 32 + g2 * 8) * 2) ^ ((unsigned)(li2 & 7) << 4);
    bf16x8 a = *(const bf16x8*)(lds_h + li2 * 512 + byte);
    bf16x8 b = *(const bf16x8*)(W2b + ((size_t)(ks * 4 + w) * 64 + l) * 8);
    acc2 = __builtin_amdgcn_mfma_f32_16x16x32_bf16(a, b, acc2, 0, 0, 0);
  }

  // alpha2 dots (fp32) + fp8 h2 store
  float ws = att_s2[w * 16 + li2], wd = att_d2[w * 16 + li2];
  float asum[4], dsum[4];
#pragma unroll
  for (int r = 0; r < 4; r++) { asum[r] = acc2[r] * ws; dsum[r] = acc2[r] * wd; }
#pragma unroll
  for (int r = 0; r < 4; r++) {
#pragma unroll
    for (int m = 1; m < 16; m <<= 1) {
      asum[r] += __shfl_xor(asum[r], m);
      dsum[r] += __shfl_xor(dsum[r], m);
    }
  }
#pragma unroll
  for (int r = 0; r < 4; r++) {
    int row = g2 * 4 + r;
    int d2 = dbase + row;
    if (d2 < n) H2[(size_t)d2 * HID + w * 16 + li2] = f2fp8(acc2[r]);
    if (li2 == 0) { pA[w][row] = asum[r]; pD[w][row] = dsum[r]; }
  }
  __syncthreads();
  if (tid < 16) {
    int d2 = dbase + tid;
    if (d2 < n) as2[d2] = (pA[0][tid] + pA[1][tid] + pA[2][tid] + pA[3][tid]) * LOG2E;
  } else if (tid < 32) {
    int row = tid - 16;
    int d2 = dbase + row;
    if (d2 < n) ad2[d2] = (pD[0][row] + pD[1][row] + pD[2][row] + pD[3][row]) * LOG2E;
  }
}

// ---------------- layer-2 aggregate (fp8 gather) + fused mean pool ----------------
__global__ __launch_bounds__(256) void agg2_pool(const unsigned char* __restrict__ H2,
                                                 const float* __restrict__ as_,
                                                 const float* __restrict__ ad_,
                                                 const int* __restrict__ row_ptr,
                                                 const int4* __restrict__ recs,
                                                 const float* __restrict__ b2,
                                                 float* __restrict__ poolrep, int n) {
  __shared__ float lds[4][64];
  int wid = threadIdx.x >> 6;
  int d = blockIdx.x * 4 + wid;
  int l = threadIdx.x & 63, q = l >> 4, li = l & 15;
  float ad = ad_[d];
  int e0 = row_ptr[d], e1 = row_ptr[d + 1];
  float4 acc = {0.f, 0.f, 0.f, 0.f};
  float denom = 0.f;
  for (int e = e0 + q; e < e1; e += 4) {
    int s = ((const int*)recs)[(size_t)e * 4];
    float sc = as_[s] + ad;
    float w = exp2f(fmaxf(sc, NEG_SLOPE * sc));
    denom += w;
    unsigned u = *(const unsigned*)(H2 + (size_t)s * HID + li * 4);
    f32x2 lo_ = __builtin_amdgcn_cvt_pk_f32_fp8((int)u, false);
    f32x2 hi_ = __builtin_amdgcn_cvt_pk_f32_fp8((int)u, true);
    acc.x += w * lo_[0]; acc.y += w * lo_[1];
    acc.z += w * hi_[0]; acc.w += w * hi_[1];
  }
#pragma unroll
  for (int m = 16; m <= 32; m <<= 1) {
    acc.x += __shfl_xor(acc.x, m); acc.y += __shfl_xor(acc.y, m);
    acc.z += __shfl_xor(acc.z, m); acc.w += __shfl_xor(acc.w, m);
    denom += __shfl_xor(denom, m);
  }
  if (q == 0) {
    float inv = 1.f / (denom + 1e-16f);
    float o[4] = {acc.x * inv + b2[li * 4], acc.y * inv + b2[li * 4 + 1],
                  acc.z * inv + b2[li * 4 + 2], acc.w * inv + b2[li * 4 + 3]};
#pragma unroll
    for (int j = 0; j < 4; j++) {
      float v = o[j];
      lds[wid][li * 4 + j] = v > 0.f ? v : (__expf(v) - 1.f);
    }
  }
  __syncthreads();
  if (threadIdx.x < 64) {
    int c = threadIdx.x;
    float v = lds[0][c] + lds[1][c] + lds[2][c] + lds[3][c];
    atomicAdd(&poolrep[(blockIdx.x & 63) * 64 + c], v);
  }
}

__global__ __launch_bounds__(64) void head_kernel(const float* __restrict__ poolrep,
                                                  const float* __restrict__ Wc,
                                                  const float* __restrict__ bc,
                                                  float* __restrict__ out, float inv_n) {
  int l = threadIdx.x;
  float p = 0.f;
  for (int k = 0; k < 64; k++) p += poolrep[k * 64 + l];
  p *= inv_n;
  float o0 = wave_reduce_sum(p * Wc[l * 2 + 0]);
  float o1 = wave_reduce_sum(p * Wc[l * 2 + 1]);
  if (l == 0) { out[0] = o0 + bc[0]; out[1] = o1 + bc[1]; }
}

// ---------------- host ----------------
static inline size_t align256(size_t x) { return (x + 255) & ~(size_t)255; }

extern "C" void kernel_launch(void* const* d_in, const int* in_sizes, int n_in,
                              void* d_out, int out_size, void* d_ws, size_t ws_size,
                              hipStream_t stream) {
  const float* x        = (const float*)d_in[0];
  const int*   ei       = (const int*)d_in[1];
  const float* W1       = (const float*)d_in[2];
  const float* att_src1 = (const float*)d_in[3];
  const float* att_dst1 = (const float*)d_in[4];
  const float* b1       = (const float*)d_in[5];
  const float* W2       = (const float*)d_in[6];
  const float* att_src2 = (const float*)d_in[7];
  const float* att_dst2 = (const float*)d_in[8];
  const float* b2       = (const float*)d_in[9];
  const float* Wc       = (const float*)d_in[10];
  const float* bc       = (const float*)d_in[11];
  float* out = (float*)d_out;

  const int N = in_sizes[0] / F_IN;          // 50000
  const int E = in_sizes[1] / 2;             // 1,600,000
  const int Etot = E + N;                    // + self loops
  const int* ei_src = ei;
  const int* ei_dst = ei + E;

  // workspace layout (~63 MB)
  char* w = (char*)d_ws;
  size_t off = 0;
  unsigned char* h1b8 = (unsigned char*)(w + off); off += align256((size_t)N * C1);   // 12.8MB fp8
  unsigned char* h2b8 = (unsigned char*)(w + off); off += align256((size_t)N * HID);  // 3.2MB fp8
  float* as1   = (float*)(w + off); off += align256((size_t)N * HEADS * 4);
  float* ad1   = (float*)(w + off); off += align256((size_t)N * HEADS * 4);
  float* as2   = (float*)(w + off); off += align256((size_t)N * 4);
  float* ad2   = (float*)(w + off); off += align256((size_t)N * 4);
  int* row_ptr = (int*)(w + off);   off += align256((size_t)(N + 1) * 4);
  int* gcursor = (int*)(w + off);   off += align256(256 * 4);
  int* bucket_base = (int*)(w + off); off += align256(256 * 4);
  float* poolrep = (float*)(w + off); off += align256(64 * 64 * 4);
  unsigned short* W1b = (unsigned short*)(w + off); off += align256(32768 * 2);
  unsigned short* W2b = (unsigned short*)(w + off); off += align256(16384 * 2);
  int2* pairs  = (int2*)(w + off);  off += align256((size_t)NBUCK * BCAP * 8);  // 16.1MB
  int4* recs   = (int4*)(w + off);  off += align256((size_t)Etot * 16);         // 26.4MB

  int nb4 = (N + 3) / 4;
  int rowblocks = (N + 63) / 64;
  int pblocks = (Etot + 2047) / 2048;
  int fblocks = (N + 15) / 16;               // 3125

  init_kernel<<<16, 256, 0, stream>>>(gcursor, poolrep);
  partition_kernel<<<pblocks, 256, 0, stream>>>(ei_src, ei_dst, gcursor, pairs, E, Etot);
  bucket_scan<<<1, 256, 0, stream>>>(gcursor, bucket_base, row_ptr, N, Etot);
  pack_w<<<64, 256, 0, stream>>>(W1, W2, W1b, W2b);

  // layer 1: GEMM1 (fp8 h-store) -> CSR+weights -> fused aggregate+GEMM2
  gemm1_mfma<<<rowblocks, 256, 0, stream>>>(x, W1b, h1b8, as1, ad1,
                                            att_src1, att_dst1, N);
  bucket_csr<<<NBUCK, 512, 0, stream>>>(pairs, gcursor, bucket_base,
                                        (const float4*)as1, (const float4*)ad1,
                                        recs, row_ptr, N);
  agg1_gemm2<<<fblocks, 256, 0, stream>>>(h1b8, recs, row_ptr, b1, W2b,
                                          att_src2, att_dst2, h2b8, as2, ad2, N);

  // layer 2 aggregate + pool
  agg2_pool<<<nb4, 256, 0, stream>>>(h2b8, as2, ad2, row_ptr, recs, b2, poolrep, N);

  head_kernel<<<1, 64, 0, stream>>>(poolrep, Wc, bc, out, 1.0f / (float)N);
}

// Round 11
// 213.729 us; speedup vs baseline: 3.9271x; 1.0331x over previous
//
#include <hip/hip_runtime.h>
#include <cstdint>
#include <cstddef>

#define NEG_SLOPE 0.2f
#define F_IN 128
#define C1 256      // HEADS*HID layer-1 width
#define HID 64
#define HEADS 4
#define LOG2E 1.4426950408889634f
#define NBUCK 196   // ceil(50000/256)
#define BCAP 10240  // per-bucket region capacity

typedef __attribute__((ext_vector_type(8))) short bf16x8;
typedef __attribute__((ext_vector_type(4))) float f32x4;
typedef __attribute__((ext_vector_type(2))) float f32x2;

__device__ __forceinline__ float wave_reduce_sum(float v) {
#pragma unroll
  for (int off = 32; off > 0; off >>= 1) v += __shfl_down(v, off);
  return v;
}

__device__ __forceinline__ unsigned short f2bf(float f) {
  union { float f; unsigned int u; } v; v.f = f;
  unsigned int u = v.u;
  unsigned int r = (u + 0x7fffu + ((u >> 16) & 1u)) >> 16;  // RNE
  return (unsigned short)r;
}
__device__ __forceinline__ float bf_lo(unsigned int u) { return __uint_as_float(u << 16); }
__device__ __forceinline__ float bf_hi(unsigned int u) { return __uint_as_float(u & 0xffff0000u); }

__device__ __forceinline__ unsigned char f2fp8(float f) {
  int p = __builtin_amdgcn_cvt_pk_fp8_f32(f, f, 0, false);  // OCP e4m3fn
  return (unsigned char)(p & 0xff);
}

// ---------------- setup: zero gcursor/poolrep + weight pre-pack (merged) --------
__global__ __launch_bounds__(256) void setup_kernel(const float* __restrict__ W1,
                                                    const float* __restrict__ W2,
                                                    unsigned short* __restrict__ W1b,
                                                    unsigned short* __restrict__ W2b,
                                                    int* __restrict__ gcursor,
                                                    float* __restrict__ poolrep) {
  const int TOT = 256 + 4096 + 32768 + 16384;
  for (int idx = threadIdx.x + blockIdx.x * 256; idx < TOT; idx += 256 * gridDim.x) {
    if (idx < 256) {
      gcursor[idx] = 0;
    } else if (idx < 256 + 4096) {
      poolrep[idx - 256] = 0.f;
    } else if (idx < 256 + 4096 + 32768) {
      int o = idx - (256 + 4096);
      int head = o >> 13, ks = (o >> 11) & 3, nt = (o >> 9) & 3;
      int lane = (o >> 3) & 63, j = o & 7;
      int k = ks * 32 + (lane >> 4) * 8 + j;
      int c = head * 64 + nt * 16 + (lane & 15);
      W1b[o] = f2bf(W1[k * 256 + c]);
    } else {
      int o = idx - (256 + 4096 + 32768);
      int ks = o >> 11, nt = (o >> 9) & 3, lane = (o >> 3) & 63, j = o & 7;
      int k = ks * 32 + (lane >> 4) * 8 + j;
      int c = nt * 16 + (lane & 15);
      W2b[o] = f2bf(W2[k * 64 + c]);
    }
  }
}

// ---------------- MFMA GEMM1 (fp32 A, fp8 h-store, all heads per block) ----------------
__global__ __launch_bounds__(256) void gemm1_mfma(const float* __restrict__ Af,
                                                  const unsigned short* __restrict__ Wb,
                                                  unsigned char* __restrict__ H8,
                                                  float* __restrict__ as_out,
                                                  float* __restrict__ ad_out,
                                                  const float* __restrict__ att_s,
                                                  const float* __restrict__ att_d,
                                                  int M) {
  constexpr int KSTEPS = 4, NH = HEADS, K = 128, N = 256;
  const int lane = threadIdx.x & 63, wid = threadIdx.x >> 6;
  const int rowbase = blockIdx.x * 64 + wid * 16;
  const int g = lane >> 4, li = lane & 15;
  int r_a = rowbase + li;
  if (r_a > M - 1) r_a = M - 1;

  f32x4 acc[NH][4];
#pragma unroll
  for (int h = 0; h < NH; h++)
#pragma unroll
    for (int nt = 0; nt < 4; nt++) {
      acc[h][nt][0] = 0.f; acc[h][nt][1] = 0.f; acc[h][nt][2] = 0.f; acc[h][nt][3] = 0.f;
    }

#pragma unroll
  for (int ks = 0; ks < KSTEPS; ks++) {
    bf16x8 a;
    const float* p = Af + (size_t)r_a * K + ks * 32 + g * 8;
    float4 v0 = *(const float4*)p, v1 = *(const float4*)(p + 4);
    a[0] = (short)f2bf(v0.x); a[1] = (short)f2bf(v0.y);
    a[2] = (short)f2bf(v0.z); a[3] = (short)f2bf(v0.w);
    a[4] = (short)f2bf(v1.x); a[5] = (short)f2bf(v1.y);
    a[6] = (short)f2bf(v1.z); a[7] = (short)f2bf(v1.w);
#pragma unroll
    for (int h = 0; h < NH; h++)
#pragma unroll
      for (int nt = 0; nt < 4; nt++) {
        bf16x8 b = *(const bf16x8*)(Wb + ((size_t)((h * KSTEPS + ks) * 4 + nt) * 64 + lane) * 8);
        acc[h][nt] = __builtin_amdgcn_mfma_f32_16x16x32_bf16(a, b, acc[h][nt], 0, 0, 0);
      }
  }

#pragma unroll
  for (int h = 0; h < NH; h++) {
    float asum[4] = {0.f, 0.f, 0.f, 0.f}, dsum[4] = {0.f, 0.f, 0.f, 0.f};
#pragma unroll
    for (int nt = 0; nt < 4; nt++) {
      float ws = att_s[h * 64 + nt * 16 + li];
      float wd = att_d[h * 64 + nt * 16 + li];
#pragma unroll
      for (int r = 0; r < 4; r++) { asum[r] += acc[h][nt][r] * ws; dsum[r] += acc[h][nt][r] * wd; }
    }
#pragma unroll
    for (int r = 0; r < 4; r++) {
#pragma unroll
      for (int m = 1; m < 16; m <<= 1) {
        asum[r] += __shfl_xor(asum[r], m);
        dsum[r] += __shfl_xor(dsum[r], m);
      }
    }
#pragma unroll
    for (int r = 0; r < 4; r++) {
      int gr = rowbase + g * 4 + r;
      if (gr < M) {
#pragma unroll
        for (int nt = 0; nt < 4; nt++)
          H8[(size_t)gr * N + h * 64 + nt * 16 + li] = f2fp8(acc[h][nt][r]);
        if (li == 0) {
          as_out[(size_t)gr * NH + h] = asum[r] * LOG2E;
          ad_out[(size_t)gr * NH + h] = dsum[r] * LOG2E;
        }
      }
    }
  }
}

// ---------------- CSR build: bucket partition ----------------
__global__ __launch_bounds__(256) void partition_kernel(const int* __restrict__ esrc,
                                                        const int* __restrict__ edst,
                                                        int* __restrict__ gcursor,
                                                        int2* __restrict__ pairs,
                                                        int E, int Etot) {
  __shared__ int hist[256];
  __shared__ int base[256];
  const int tid = threadIdx.x;
  const int e0 = blockIdx.x * 2048;
  hist[tid] = 0;
  __syncthreads();
  int d8[8], rk8[8], bk8[8];
#pragma unroll
  for (int j = 0; j < 8; j++) {
    int e = e0 + tid * 8 + j;
    d8[j] = -1;
    if (e < Etot) {
      int d = (e < E) ? edst[e] : (e - E);
      d8[j] = d;
      bk8[j] = d >> 8;
      rk8[j] = atomicAdd(&hist[bk8[j]], 1);
    }
  }
  __syncthreads();
  if (hist[tid] > 0) base[tid] = atomicAdd(&gcursor[tid], hist[tid]);
  __syncthreads();
#pragma unroll
  for (int j = 0; j < 8; j++) {
    int e = e0 + tid * 8 + j;
    if (e < Etot) {
      int s = (e < E) ? esrc[e] : (e - E);
      int2 pr; pr.x = s; pr.y = d8[j];
      pairs[(size_t)bk8[j] * BCAP + base[bk8[j]] + rk8[j]] = pr;
    }
  }
}

// per-bucket CSR + fused edge weights; computes its own bucket prefix.
__global__ __launch_bounds__(512) void bucket_csr(const int2* __restrict__ pairs,
                                                  const int* __restrict__ gcursor,
                                                  const float4* __restrict__ as1,
                                                  const float4* __restrict__ ad1,
                                                  int4* __restrict__ recs,
                                                  int* __restrict__ row_ptr,
                                                  int N, int Etot) {
  __shared__ int hist[256], offs[256], cnt2[256], gpre[256];
  const int b = blockIdx.x;
  const int tid = threadIdx.x;
  if (tid < 256) {
    hist[tid] = 0; cnt2[tid] = 0;
    gpre[tid] = (tid < NBUCK) ? gcursor[tid] : 0;
  }
  __syncthreads();
  // inclusive scan of bucket counts (for this block's base)
  for (int off = 1; off < 256; off <<= 1) {
    int t = 0;
    if (tid < 256 && tid >= off) t = gpre[tid - off];
    __syncthreads();
    if (tid < 256) gpre[tid] += t;
    __syncthreads();
  }
  const int cnt = gcursor[b];
  const int gbase = (b == 0) ? 0 : gpre[b - 1];
  const int2* bp = pairs + (size_t)b * BCAP;
  if (b == 0 && tid == 0) row_ptr[N] = Etot;

  for (int i = tid; i < cnt; i += 512) atomicAdd(&hist[bp[i].y & 255], 1);
  __syncthreads();
  if (tid < 256) offs[tid] = hist[tid];
  __syncthreads();
  for (int off = 1; off < 256; off <<= 1) {
    int t = 0;
    if (tid < 256 && tid >= off) t = offs[tid - off];
    __syncthreads();
    if (tid < 256) offs[tid] += t;
    __syncthreads();
  }
  if (tid < 256) {
    int node = b * 256 + tid;
    if (node < N) row_ptr[node] = gbase + offs[tid] - hist[tid];
  }
  __syncthreads();
  for (int i = tid; i < cnt; i += 512) {
    int2 pr = bp[i];
    int lo = pr.y & 255;
    int rank = atomicAdd(&cnt2[lo], 1);
    int pos = gbase + offs[lo] - hist[lo] + rank;
    float4 a = as1[pr.x], dd = ad1[pr.y];
    float s0 = a.x + dd.x, s1 = a.y + dd.y, s2 = a.z + dd.z, s3 = a.w + dd.w;
    float w0 = exp2f(fmaxf(s0, NEG_SLOPE * s0));
    float w1 = exp2f(fmaxf(s1, NEG_SLOPE * s1));
    float w2 = exp2f(fmaxf(s2, NEG_SLOPE * s2));
    float w3 = exp2f(fmaxf(s3, NEG_SLOPE * s3));
    int4 r;
    r.x = pr.x;
    r.y = (int)((unsigned)f2bf(w0) | ((unsigned)f2bf(w1) << 16));
    r.z = (int)((unsigned)f2bf(w2) | ((unsigned)f2bf(w3) << 16));
    r.w = 0;
    recs[pos] = r;
  }
}

// ---------------- fused: layer-1 aggregate + GEMM2 + alpha2 dots ----------------
__global__ __launch_bounds__(256) void agg1_gemm2(const unsigned char* __restrict__ H8,
                                                  const int4* __restrict__ recs,
                                                  const int* __restrict__ row_ptr,
                                                  const float* __restrict__ b1,
                                                  const unsigned short* __restrict__ W2b,
                                                  const float* __restrict__ att_s2,
                                                  const float* __restrict__ att_d2,
                                                  unsigned char* __restrict__ H2,
                                                  float* __restrict__ as2,
                                                  float* __restrict__ ad2, int n) {
  __shared__ unsigned char lds_h[16 * 512];   // 16 rows x 256 bf16, swizzled
  __shared__ float pA[4][16], pD[4][16];
  const int tid = threadIdx.x;
  const int l = tid & 63, w = tid >> 6;
  const int dbase = blockIdx.x * 16;
  const int hh = l >> 4;
  const int shamt = (hh & 1) ? 0 : 16;
  const bool lowpair = hh < 2;
  const float4 bb = *(const float4*)(b1 + l * 4);

  // ---- phase 1: aggregate 4 dsts per wave into LDS (packed f32x2 math) ----
#define WSEL(r) __uint_as_float(((unsigned)((lowpair) ? (r).y : (r).z) << shamt) & 0xffff0000u)
#define ACCUM(wgt, u8)                                                     \
  {                                                                        \
    f32x2 lo_ = __builtin_amdgcn_cvt_pk_f32_fp8((int)(u8), false);         \
    f32x2 hi_ = __builtin_amdgcn_cvt_pk_f32_fp8((int)(u8), true);          \
    accA += lo_ * (wgt); accB += hi_ * (wgt);                              \
    denom += (wgt);                                                        \
  }
  for (int i = 0; i < 4; i++) {
    int dloc = w * 4 + i;
    int d = dbase + dloc;
    bool active = d < n;
    f32x2 accA = {0.f, 0.f}, accB = {0.f, 0.f};
    float denom = 0.f;
    if (active) {
      int e0 = __builtin_amdgcn_readfirstlane(row_ptr[d]);
      int e1 = __builtin_amdgcn_readfirstlane(row_ptr[d + 1]);
      int e = e0;
      for (; e + 3 < e1; e += 4) {
        int4 r0 = recs[e], r1 = recs[e + 1], r2 = recs[e + 2], r3 = recs[e + 3];
        unsigned u0 = *(const unsigned*)(H8 + (size_t)r0.x * C1 + l * 4);
        unsigned u1 = *(const unsigned*)(H8 + (size_t)r1.x * C1 + l * 4);
        unsigned u2 = *(const unsigned*)(H8 + (size_t)r2.x * C1 + l * 4);
        unsigned u3 = *(const unsigned*)(H8 + (size_t)r3.x * C1 + l * 4);
        float w0 = WSEL(r0), w1 = WSEL(r1), w2 = WSEL(r2), w3 = WSEL(r3);
        ACCUM(w0, u0) ACCUM(w1, u1) ACCUM(w2, u2) ACCUM(w3, u3)
      }
      for (; e < e1; e++) {
        int4 r0 = recs[e];
        unsigned u = *(const unsigned*)(H8 + (size_t)r0.x * C1 + l * 4);
        float wq = WSEL(r0);
        ACCUM(wq, u)
      }
    }
    float inv = 1.f / (denom + 1e-16f);
    float4 o;
    o.x = accA[0] * inv + bb.x; o.y = accA[1] * inv + bb.y;
    o.z = accB[0] * inv + bb.z; o.w = accB[1] * inv + bb.w;
    o.x = o.x > 0.f ? o.x : (__expf(o.x) - 1.f);
    o.y = o.y > 0.f ? o.y : (__expf(o.y) - 1.f);
    o.z = o.z > 0.f ? o.z : (__expf(o.z) - 1.f);
    o.w = o.w > 0.f ? o.w : (__expf(o.w) - 1.f);
    if (!active) { o.x = 0.f; o.y = 0.f; o.z = 0.f; o.w = 0.f; }
    uint2 pk;
    pk.x = (unsigned int)f2bf(o.x) | ((unsigned int)f2bf(o.y) << 16);
    pk.y = (unsigned int)f2bf(o.z) | ((unsigned int)f2bf(o.w) << 16);
    unsigned byte = (unsigned)(l * 8) ^ ((unsigned)(dloc & 7) << 4);
    *(uint2*)(lds_h + dloc * 512 + byte) = pk;
  }
#undef ACCUM
#undef WSEL
  __syncthreads();

  // ---- phase 2: GEMM2 16x64, K=256; wave w owns cols w*16..w*16+15 ----
  const int li2 = l & 15, g2 = l >> 4;
  f32x4 acc2;
  acc2[0] = 0.f; acc2[1] = 0.f; acc2[2] = 0.f; acc2[3] = 0.f;
#pragma unroll
  for (int ks = 0; ks < 8; ks++) {
    unsigned byte = (unsigned)((ks * 32 + g2 * 8) * 2) ^ ((unsigned)(li2 & 7) << 4);
    bf16x8 a = *(const bf16x8*)(lds_h + li2 * 512 + byte);
    bf16x8 b = *(const bf16x8*)(W2b + ((size_t)(ks * 4 + w) * 64 + l) * 8);
    acc2 = __builtin_amdgcn_mfma_f32_16x16x32_bf16(a, b, acc2, 0, 0, 0);
  }

  // alpha2 dots (fp32) + fp8 h2 store
  float ws = att_s2[w * 16 + li2], wd = att_d2[w * 16 + li2];
  float asum[4], dsum[4];
#pragma unroll
  for (int r = 0; r < 4; r++) { asum[r] = acc2[r] * ws; dsum[r] = acc2[r] * wd; }
#pragma unroll
  for (int r = 0; r < 4; r++) {
#pragma unroll
    for (int m = 1; m < 16; m <<= 1) {
      asum[r] += __shfl_xor(asum[r], m);
      dsum[r] += __shfl_xor(dsum[r], m);
    }
  }
#pragma unroll
  for (int r = 0; r < 4; r++) {
    int row = g2 * 4 + r;
    int d2 = dbase + row;
    if (d2 < n) H2[(size_t)d2 * HID + w * 16 + li2] = f2fp8(acc2[r]);
    if (li2 == 0) { pA[w][row] = asum[r]; pD[w][row] = dsum[r]; }
  }
  __syncthreads();
  if (tid < 16) {
    int d2 = dbase + tid;
    if (d2 < n) as2[d2] = (pA[0][tid] + pA[1][tid] + pA[2][tid] + pA[3][tid]) * LOG2E;
  } else if (tid < 32) {
    int row = tid - 16;
    int d2 = dbase + row;
    if (d2 < n) ad2[d2] = (pD[0][row] + pD[1][row] + pD[2][row] + pD[3][row]) * LOG2E;
  }
}

// ---------------- layer-2 aggregate (fp8 gather, packed math) + mean pool ----------------
__global__ __launch_bounds__(256) void agg2_pool(const unsigned char* __restrict__ H2,
                                                 const float* __restrict__ as_,
                                                 const float* __restrict__ ad_,
                                                 const int* __restrict__ row_ptr,
                                                 const int4* __restrict__ recs,
                                                 const float* __restrict__ b2,
                                                 float* __restrict__ poolrep, int n) {
  __shared__ float lds[4][64];
  int wid = threadIdx.x >> 6;
  int d = blockIdx.x * 4 + wid;
  int l = threadIdx.x & 63, q = l >> 4, li = l & 15;
  float ad = ad_[d];
  int e0 = row_ptr[d], e1 = row_ptr[d + 1];
  f32x2 accA = {0.f, 0.f}, accB = {0.f, 0.f};
  float denom = 0.f;
  for (int e = e0 + q; e < e1; e += 4) {
    int s = ((const int*)recs)[(size_t)e * 4];
    float sc = as_[s] + ad;
    float w = exp2f(fmaxf(sc, NEG_SLOPE * sc));
    denom += w;
    unsigned u = *(const unsigned*)(H2 + (size_t)s * HID + li * 4);
    f32x2 lo_ = __builtin_amdgcn_cvt_pk_f32_fp8((int)u, false);
    f32x2 hi_ = __builtin_amdgcn_cvt_pk_f32_fp8((int)u, true);
    accA += lo_ * w; accB += hi_ * w;
  }
#pragma unroll
  for (int m = 16; m <= 32; m <<= 1) {
    accA[0] += __shfl_xor(accA[0], m); accA[1] += __shfl_xor(accA[1], m);
    accB[0] += __shfl_xor(accB[0], m); accB[1] += __shfl_xor(accB[1], m);
    denom += __shfl_xor(denom, m);
  }
  if (q == 0) {
    float inv = 1.f / (denom + 1e-16f);
    float o[4] = {accA[0] * inv + b2[li * 4], accA[1] * inv + b2[li * 4 + 1],
                  accB[0] * inv + b2[li * 4 + 2], accB[1] * inv + b2[li * 4 + 3]};
#pragma unroll
    for (int j = 0; j < 4; j++) {
      float v = o[j];
      lds[wid][li * 4 + j] = v > 0.f ? v : (__expf(v) - 1.f);
    }
  }
  __syncthreads();
  if (threadIdx.x < 64) {
    int c = threadIdx.x;
    float v = lds[0][c] + lds[1][c] + lds[2][c] + lds[3][c];
    atomicAdd(&poolrep[(blockIdx.x & 63) * 64 + c], v);
  }
}

__global__ __launch_bounds__(64) void head_kernel(const float* __restrict__ poolrep,
                                                  const float* __restrict__ Wc,
                                                  const float* __restrict__ bc,
                                                  float* __restrict__ out, float inv_n) {
  int l = threadIdx.x;
  float p = 0.f;
  for (int k = 0; k < 64; k++) p += poolrep[k * 64 + l];
  p *= inv_n;
  float o0 = wave_reduce_sum(p * Wc[l * 2 + 0]);
  float o1 = wave_reduce_sum(p * Wc[l * 2 + 1]);
  if (l == 0) { out[0] = o0 + bc[0]; out[1] = o1 + bc[1]; }
}

// ---------------- host ----------------
static inline size_t align256(size_t x) { return (x + 255) & ~(size_t)255; }

extern "C" void kernel_launch(void* const* d_in, const int* in_sizes, int n_in,
                              void* d_out, int out_size, void* d_ws, size_t ws_size,
                              hipStream_t stream) {
  const float* x        = (const float*)d_in[0];
  const int*   ei       = (const int*)d_in[1];
  const float* W1       = (const float*)d_in[2];
  const float* att_src1 = (const float*)d_in[3];
  const float* att_dst1 = (const float*)d_in[4];
  const float* b1       = (const float*)d_in[5];
  const float* W2       = (const float*)d_in[6];
  const float* att_src2 = (const float*)d_in[7];
  const float* att_dst2 = (const float*)d_in[8];
  const float* b2       = (const float*)d_in[9];
  const float* Wc       = (const float*)d_in[10];
  const float* bc       = (const float*)d_in[11];
  float* out = (float*)d_out;

  const int N = in_sizes[0] / F_IN;          // 50000
  const int E = in_sizes[1] / 2;             // 1,600,000
  const int Etot = E + N;                    // + self loops
  const int* ei_src = ei;
  const int* ei_dst = ei + E;

  // workspace layout (~63 MB)
  char* w = (char*)d_ws;
  size_t off = 0;
  unsigned char* h1b8 = (unsigned char*)(w + off); off += align256((size_t)N * C1);   // 12.8MB fp8
  unsigned char* h2b8 = (unsigned char*)(w + off); off += align256((size_t)N * HID);  // 3.2MB fp8
  float* as1   = (float*)(w + off); off += align256((size_t)N * HEADS * 4);
  float* ad1   = (float*)(w + off); off += align256((size_t)N * HEADS * 4);
  float* as2   = (float*)(w + off); off += align256((size_t)N * 4);
  float* ad2   = (float*)(w + off); off += align256((size_t)N * 4);
  int* row_ptr = (int*)(w + off);   off += align256((size_t)(N + 1) * 4);
  int* gcursor = (int*)(w + off);   off += align256(256 * 4);
  float* poolrep = (float*)(w + off); off += align256(64 * 64 * 4);
  unsigned short* W1b = (unsigned short*)(w + off); off += align256(32768 * 2);
  unsigned short* W2b = (unsigned short*)(w + off); off += align256(16384 * 2);
  int2* pairs  = (int2*)(w + off);  off += align256((size_t)NBUCK * BCAP * 8);  // 16.1MB
  int4* recs   = (int4*)(w + off);  off += align256((size_t)Etot * 16);         // 26.4MB

  int nb4 = (N + 3) / 4;
  int rowblocks = (N + 63) / 64;
  int pblocks = (Etot + 2047) / 2048;
  int fblocks = (N + 15) / 16;               // 3125

  setup_kernel<<<104, 256, 0, stream>>>(W1, W2, W1b, W2b, gcursor, poolrep);
  partition_kernel<<<pblocks, 256, 0, stream>>>(ei_src, ei_dst, gcursor, pairs, E, Etot);
  gemm1_mfma<<<rowblocks, 256, 0, stream>>>(x, W1b, h1b8, as1, ad1,
                                            att_src1, att_dst1, N);
  bucket_csr<<<NBUCK, 512, 0, stream>>>(pairs, gcursor,
                                        (const float4*)as1, (const float4*)ad1,
                                        recs, row_ptr, N, Etot);
  agg1_gemm2<<<fblocks, 256, 0, stream>>>(h1b8, recs, row_ptr, b1, W2b,
                                          att_src2, att_dst2, h2b8, as2, ad2, N);
  agg2_pool<<<nb4, 256, 0, stream>>>(h2b8, as2, ad2, row_ptr, recs, b2, poolrep, N);
  head_kernel<<<1, 64, 0, stream>>>(poolrep, Wc, bc, out, 1.0f / (float)N);
}